// Round 1
// baseline (4249.086 us; speedup 1.0000x reference)
//
#include <hip/hip_runtime.h>
#include <cstdint>
#include <cstddef>

// ---------------- problem constants ----------------
#define B_  4
#define L_  4096
#define D_  256
#define DI_ 512
#define H_  8
#define P_  64
#define N_  16
#define M_  (B_ * L_)            // 16384 rows
#define PROJ_ (DI_ + 2 * H_ * N_)  // 768

// ---------------- GEMM: C = A(M,K) * W(N,K)^T + bias, with epilogues --------
// EPI 0: plain store to out0 (ldc = N)
// EPI 1: in_proj split: col<DI -> silu -> out0 (xi, ld=DI); col>=DI -> out1 (z, ld=DI)
// EPI 2: x_proj: col<DI -> softplus(v + aux[col]) ; store all to out0 (ld=768)
// EPI 3: plain but row-flipped along L (for backward out_proj -> d_out)
#define BM 64
#define BN 64
#define BK 16

template <int EPI>
__launch_bounds__(256)
__global__ void gemm_nt(const float* __restrict__ A, const float* __restrict__ W,
                        const float* __restrict__ bias, int Mv, int Nv, int Kv,
                        float* __restrict__ out0, float* __restrict__ out1,
                        const float* __restrict__ aux) {
    __shared__ float As[BK][BM + 1];
    __shared__ float Ws[BK][BN + 1];
    const int bm = blockIdx.x * BM;
    const int bn = blockIdx.y * BN;
    const int tid = threadIdx.x;
    const int tx = tid & 15;
    const int ty = tid >> 4;

    float acc[4][4];
#pragma unroll
    for (int i = 0; i < 4; ++i)
#pragma unroll
        for (int j = 0; j < 4; ++j) acc[i][j] = 0.f;

    const int lm = tid >> 2;          // 0..63 row within tile
    const int lk = (tid & 3) << 2;    // 0,4,8,12 k within tile

    for (int k0 = 0; k0 < Kv; k0 += BK) {
        const float4 a4 = *reinterpret_cast<const float4*>(
            &A[(size_t)(bm + lm) * Kv + k0 + lk]);
        const float4 w4 = *reinterpret_cast<const float4*>(
            &W[(size_t)(bn + lm) * Kv + k0 + lk]);
        As[lk + 0][lm] = a4.x; As[lk + 1][lm] = a4.y;
        As[lk + 2][lm] = a4.z; As[lk + 3][lm] = a4.w;
        Ws[lk + 0][lm] = w4.x; Ws[lk + 1][lm] = w4.y;
        Ws[lk + 2][lm] = w4.z; Ws[lk + 3][lm] = w4.w;
        __syncthreads();
#pragma unroll
        for (int kk = 0; kk < BK; ++kk) {
            float av[4], wv[4];
#pragma unroll
            for (int i = 0; i < 4; ++i) av[i] = As[kk][ty * 4 + i];
#pragma unroll
            for (int j = 0; j < 4; ++j) wv[j] = Ws[kk][tx * 4 + j];
#pragma unroll
            for (int i = 0; i < 4; ++i)
#pragma unroll
                for (int j = 0; j < 4; ++j) acc[i][j] = fmaf(av[i], wv[j], acc[i][j]);
        }
        __syncthreads();
    }

    const int cbase = bn + tx * 4;
#pragma unroll
    for (int i = 0; i < 4; ++i) {
        const int r = bm + ty * 4 + i;
        float v[4];
#pragma unroll
        for (int j = 0; j < 4; ++j) v[j] = acc[i][j] + bias[cbase + j];

        if (EPI == 0) {
            float4 o = {v[0], v[1], v[2], v[3]};
            *reinterpret_cast<float4*>(&out0[(size_t)r * Nv + cbase]) = o;
        } else if (EPI == 1) {
            if (cbase < DI_) {
#pragma unroll
                for (int j = 0; j < 4; ++j) v[j] = v[j] / (1.f + __expf(-v[j]));
                float4 o = {v[0], v[1], v[2], v[3]};
                *reinterpret_cast<float4*>(&out0[(size_t)r * DI_ + cbase]) = o;
            } else {
                float4 o = {v[0], v[1], v[2], v[3]};
                *reinterpret_cast<float4*>(&out1[(size_t)r * DI_ + cbase - DI_]) = o;
            }
        } else if (EPI == 2) {
            if (cbase < DI_) {
#pragma unroll
                for (int j = 0; j < 4; ++j) {
                    float x = v[j] + aux[cbase + j];
                    v[j] = (x > 20.f) ? x : log1pf(__expf(x));
                }
            }
            float4 o = {v[0], v[1], v[2], v[3]};
            *reinterpret_cast<float4*>(&out0[(size_t)r * PROJ_ + cbase]) = o;
        } else {  // EPI 3: flipped rows
            const int bb = r >> 12;          // / L_
            const int l = r & (L_ - 1);
            const int rr = (bb << 12) + (L_ - 1 - l);
            float4 o = {v[0], v[1], v[2], v[3]};
            *reinterpret_cast<float4*>(&out0[(size_t)rr * Nv + cbase]) = o;
        }
    }
}

// ---------------- selective scan -------------------------------------------
// grid: (B_*H_, P_/16), block: 256 threads = 16 p x 16 n
__launch_bounds__(256)
__global__ void ssm_scan(const float* __restrict__ xi, const float* __restrict__ z,
                         const float* __restrict__ proj, const float* __restrict__ A_log,
                         const float* __restrict__ D_skip, float* __restrict__ yg) {
    const int bh = blockIdx.x;
    const int b = bh >> 3;
    const int h = bh & 7;
    const int tid = threadIdx.x;
    const int pl = tid >> 4;          // 0..15
    const int n = tid & 15;
    const int c = h * P_ + blockIdx.y * 16 + pl;   // channel 0..511

    const float Aval = -__expf(A_log[c * N_ + n]);
    const float Dv = D_skip[c];

    const size_t rowP = (size_t)b * L_ * PROJ_;
    const size_t rowX = (size_t)b * L_ * DI_;
    const float* pdt = proj + rowP + c;
    const float* pB = proj + rowP + DI_ + h * N_ + n;
    const float* pC = proj + rowP + DI_ + H_ * N_ + h * N_ + n;
    const float* px = xi + rowX + c;
    const float* pz = z + rowX + c;
    float* py = yg + rowX + c;

    float dt_v = *pdt, Bv = *pB, Cv = *pC, xv = *px, zv = *pz;
    float hs = 0.f;

    for (int t = 0; t < L_; ++t) {
        float dt_n = 0.f, B_n = 0.f, C_n = 0.f, x_n = 0.f, z_n = 0.f;
        if (t + 1 < L_) {
            dt_n = pdt[PROJ_]; B_n = pB[PROJ_]; C_n = pC[PROJ_];
            x_n = px[DI_]; z_n = pz[DI_];
        }
        const float dA = __expf(dt_v * Aval);
        hs = fmaf(hs, dA, dt_v * Bv * xv);
        float part = hs * Cv;
        part += __shfl_xor(part, 1);
        part += __shfl_xor(part, 2);
        part += __shfl_xor(part, 4);
        part += __shfl_xor(part, 8);
        if (n == 0) {
            const float g = zv / (1.f + __expf(-zv));
            py[0] = (part + Dv * xv) * g;
        }
        pdt += PROJ_; pB += PROJ_; pC += PROJ_; px += DI_; pz += DI_; py += DI_;
        dt_v = dt_n; Bv = B_n; Cv = C_n; xv = x_n; zv = z_n;
    }
}

// ---------------- layernorm + flip -----------------------------------------
__launch_bounds__(256)
__global__ void ln_flip(const float* __restrict__ x, const float* __restrict__ w,
                        const float* __restrict__ bvec, float* __restrict__ y) {
    const int row = blockIdx.x;       // b*L + l
    const int d = threadIdx.x;        // 0..255
    const float v = x[(size_t)row * D_ + d];
    float s = v, s2 = v * v;
#pragma unroll
    for (int m = 32; m; m >>= 1) {
        s += __shfl_xor(s, m);
        s2 += __shfl_xor(s2, m);
    }
    __shared__ float sh[8];
    const int wave = d >> 6;
    if ((d & 63) == 0) { sh[wave] = s; sh[4 + wave] = s2; }
    __syncthreads();
    const float ts = sh[0] + sh[1] + sh[2] + sh[3];
    const float ts2 = sh[4] + sh[5] + sh[6] + sh[7];
    const float mean = ts * (1.f / D_);
    const float var = ts2 * (1.f / D_) - mean * mean;
    const float inv = rsqrtf(var + 1e-5f);
    const int b = row >> 12;
    const int l = row & (L_ - 1);
    const int drow = (b << 12) + (L_ - 1 - l);
    y[(size_t)drow * D_ + d] = (v - mean) * inv * w[d] + bvec[d];
}

// ---------------- depthwise conv(k=3) + exact GELU, added in-place ----------
__launch_bounds__(256)
__global__ void conv_gelu_add(const float* __restrict__ x, const float* __restrict__ cw,
                              const float* __restrict__ cb, float* __restrict__ out) {
    const int idx = blockIdx.x * 256 + threadIdx.x;   // over B*L*D
    const int d = idx & (D_ - 1);
    const int l = (idx >> 8) & (L_ - 1);
    const int b = idx >> (8 + 12);
    float acc = cb[d];
    const float w0 = cw[d * 3 + 0], w1 = cw[d * 3 + 1], w2 = cw[d * 3 + 2];
    const size_t base = ((size_t)b * L_ + l) * D_ + d;
    if (l > 0) acc = fmaf(x[base - D_], w0, acc);
    acc = fmaf(x[base], w1, acc);
    if (l + 1 < L_) acc = fmaf(x[base + D_], w2, acc);
    const float g = 0.5f * acc * (1.f + erff(acc * 0.70710678118654752f));
    out[idx] += g;
}

// ---------------- host launcher --------------------------------------------
extern "C" void kernel_launch(void* const* d_in, const int* in_sizes, int n_in,
                              void* d_out, int out_size, void* d_ws, size_t ws_size,
                              hipStream_t stream) {
    const float* inputs = (const float*)d_in[0];
    // f_: 1..9, b_: 10..18
    const float* f_in_w = (const float*)d_in[1];
    const float* f_in_b = (const float*)d_in[2];
    const float* f_xp_w = (const float*)d_in[3];
    const float* f_xp_b = (const float*)d_in[4];
    const float* f_dt_b = (const float*)d_in[5];
    const float* f_A = (const float*)d_in[6];
    const float* f_D = (const float*)d_in[7];
    const float* f_out_w = (const float*)d_in[8];
    const float* f_out_b = (const float*)d_in[9];
    const float* b_in_w = (const float*)d_in[10];
    const float* b_in_b = (const float*)d_in[11];
    const float* b_xp_w = (const float*)d_in[12];
    const float* b_xp_b = (const float*)d_in[13];
    const float* b_dt_b = (const float*)d_in[14];
    const float* b_A = (const float*)d_in[15];
    const float* b_D = (const float*)d_in[16];
    const float* b_out_w = (const float*)d_in[17];
    const float* b_out_b = (const float*)d_in[18];
    const float* norm_w = (const float*)d_in[19];
    const float* norm_b = (const float*)d_in[20];
    const float* conv_w = (const float*)d_in[21];
    const float* conv_b = (const float*)d_in[22];
    float* out = (float*)d_out;

    // workspace layout (floats)
    float* ws = (float*)d_ws;
    float* xi   = ws;                               // 8,388,608
    float* zbuf = xi + (size_t)M_ * DI_;            // 8,388,608
    float* proj = zbuf + (size_t)M_ * DI_;          // 12,582,912
    float* yg   = proj + (size_t)M_ * PROJ_;        // 8,388,608
    float* y1n  = yg + (size_t)M_ * DI_;            // 4,194,304
    float* y1   = proj;                             // alias: proj dead after scan

    const dim3 blk(256);
    const dim3 g_in(M_ / BM, (2 * DI_) / BN);   // (256,16)
    const dim3 g_xp(M_ / BM, PROJ_ / BN);       // (256,12)
    const dim3 g_out(M_ / BM, D_ / BN);         // (256,4)
    const dim3 g_scan(B_ * H_, P_ / 16);        // (32,4)

    // ---- forward pass ----
    gemm_nt<1><<<g_in, blk, 0, stream>>>(inputs, f_in_w, f_in_b, M_, 2 * DI_, D_,
                                         xi, zbuf, nullptr);
    gemm_nt<2><<<g_xp, blk, 0, stream>>>(xi, f_xp_w, f_xp_b, M_, PROJ_, DI_,
                                         proj, nullptr, f_dt_b);
    ssm_scan<<<g_scan, blk, 0, stream>>>(xi, zbuf, proj, f_A, f_D, yg);
    gemm_nt<0><<<g_out, blk, 0, stream>>>(yg, f_out_w, f_out_b, M_, D_, DI_,
                                          y1, nullptr, nullptr);
    ln_flip<<<dim3(M_), blk, 0, stream>>>(y1, norm_w, norm_b, y1n);

    // ---- backward pass ----
    gemm_nt<1><<<g_in, blk, 0, stream>>>(y1n, b_in_w, b_in_b, M_, 2 * DI_, D_,
                                         xi, zbuf, nullptr);
    gemm_nt<2><<<g_xp, blk, 0, stream>>>(xi, b_xp_w, b_xp_b, M_, PROJ_, DI_,
                                         proj, nullptr, b_dt_b);
    ssm_scan<<<g_scan, blk, 0, stream>>>(xi, zbuf, proj, b_A, b_D, yg);
    gemm_nt<3><<<g_out, blk, 0, stream>>>(yg, b_out_w, b_out_b, M_, D_, DI_,
                                          out, nullptr, nullptr);

    // ---- locality branch ----
    conv_gelu_add<<<dim3(M_ * D_ / 256), blk, 0, stream>>>(inputs, conv_w, conv_b, out);
}

// Round 2
// 1671.820 us; speedup vs baseline: 2.5416x; 2.5416x over previous
//
#include <hip/hip_runtime.h>
#include <cstdint>
#include <cstddef>

// ---------------- problem constants ----------------
#define B_  4
#define L_  4096
#define D_  256
#define DI_ 512
#define H_  8
#define P_  64
#define N_  16
#define M_  (B_ * L_)            // 16384 rows
#define PROJ_ (DI_ + 2 * H_ * N_)  // 768

// chunked scan parameters
#define NC_ 32                   // number of chunks along L
#define CL_ (L_ / NC_)           // 128 chunk length
#define NSEQ_ (B_ * H_ * P_ * N_)  // 32768 scalar sequences

// ---------------- GEMM: C = A(M,K) * W(N,K)^T + bias, with epilogues --------
// EPI 0: plain store to out0 (ldc = N)
// EPI 1: in_proj split: col<DI -> silu -> out0 (xi, ld=DI); col>=DI -> out1 (z, ld=DI)
// EPI 2: x_proj: col<DI -> softplus(v + aux[col]) ; store all to out0 (ld=768)
// EPI 3: plain but row-flipped along L (for backward out_proj -> d_out)
#define BM 64
#define BN 64
#define BK 16

template <int EPI>
__launch_bounds__(256)
__global__ void gemm_nt(const float* __restrict__ A, const float* __restrict__ W,
                        const float* __restrict__ bias, int Mv, int Nv, int Kv,
                        float* __restrict__ out0, float* __restrict__ out1,
                        const float* __restrict__ aux) {
    __shared__ float As[BK][BM + 1];
    __shared__ float Ws[BK][BN + 1];
    const int bm = blockIdx.x * BM;
    const int bn = blockIdx.y * BN;
    const int tid = threadIdx.x;
    const int tx = tid & 15;
    const int ty = tid >> 4;

    float acc[4][4];
#pragma unroll
    for (int i = 0; i < 4; ++i)
#pragma unroll
        for (int j = 0; j < 4; ++j) acc[i][j] = 0.f;

    const int lm = tid >> 2;          // 0..63 row within tile
    const int lk = (tid & 3) << 2;    // 0,4,8,12 k within tile

    for (int k0 = 0; k0 < Kv; k0 += BK) {
        const float4 a4 = *reinterpret_cast<const float4*>(
            &A[(size_t)(bm + lm) * Kv + k0 + lk]);
        const float4 w4 = *reinterpret_cast<const float4*>(
            &W[(size_t)(bn + lm) * Kv + k0 + lk]);
        As[lk + 0][lm] = a4.x; As[lk + 1][lm] = a4.y;
        As[lk + 2][lm] = a4.z; As[lk + 3][lm] = a4.w;
        Ws[lk + 0][lm] = w4.x; Ws[lk + 1][lm] = w4.y;
        Ws[lk + 2][lm] = w4.z; Ws[lk + 3][lm] = w4.w;
        __syncthreads();
#pragma unroll
        for (int kk = 0; kk < BK; ++kk) {
            float av[4], wv[4];
#pragma unroll
            for (int i = 0; i < 4; ++i) av[i] = As[kk][ty * 4 + i];
#pragma unroll
            for (int j = 0; j < 4; ++j) wv[j] = Ws[kk][tx * 4 + j];
#pragma unroll
            for (int i = 0; i < 4; ++i)
#pragma unroll
                for (int j = 0; j < 4; ++j) acc[i][j] = fmaf(av[i], wv[j], acc[i][j]);
        }
        __syncthreads();
    }

    const int cbase = bn + tx * 4;
#pragma unroll
    for (int i = 0; i < 4; ++i) {
        const int r = bm + ty * 4 + i;
        float v[4];
#pragma unroll
        for (int j = 0; j < 4; ++j) v[j] = acc[i][j] + bias[cbase + j];

        if (EPI == 0) {
            float4 o = {v[0], v[1], v[2], v[3]};
            *reinterpret_cast<float4*>(&out0[(size_t)r * Nv + cbase]) = o;
        } else if (EPI == 1) {
            if (cbase < DI_) {
#pragma unroll
                for (int j = 0; j < 4; ++j) v[j] = v[j] / (1.f + __expf(-v[j]));
                float4 o = {v[0], v[1], v[2], v[3]};
                *reinterpret_cast<float4*>(&out0[(size_t)r * DI_ + cbase]) = o;
            } else {
                float4 o = {v[0], v[1], v[2], v[3]};
                *reinterpret_cast<float4*>(&out1[(size_t)r * DI_ + cbase - DI_]) = o;
            }
        } else if (EPI == 2) {
            if (cbase < DI_) {
#pragma unroll
                for (int j = 0; j < 4; ++j) {
                    float x = v[j] + aux[cbase + j];
                    v[j] = (x > 20.f) ? x : log1pf(__expf(x));
                }
            }
            float4 o = {v[0], v[1], v[2], v[3]};
            *reinterpret_cast<float4*>(&out0[(size_t)r * PROJ_ + cbase]) = o;
        } else {  // EPI 3: flipped rows
            const int bb = r >> 12;          // / L_
            const int l = r & (L_ - 1);
            const int rr = (bb << 12) + (L_ - 1 - l);
            float4 o = {v[0], v[1], v[2], v[3]};
            *reinterpret_cast<float4*>(&out0[(size_t)rr * Nv + cbase]) = o;
        }
    }
}

// ---------------- chunked selective scan ------------------------------------
// Pass 1: per-(seq,chunk) local scan from h=0; emit decay product + end state.
// grid: (B_*H_, P_/16, NC_), block 256 = 16 p x 16 n
__launch_bounds__(256)
__global__ void scan_chunk_state(const float* __restrict__ xi,
                                 const float* __restrict__ proj,
                                 const float* __restrict__ A_log,
                                 float* __restrict__ st_prod,
                                 float* __restrict__ st_hend) {
    const int bh = blockIdx.x;
    const int b = bh >> 3;
    const int h = bh & 7;
    const int tid = threadIdx.x;
    const int pl = tid >> 4;
    const int n = tid & 15;
    const int c = h * P_ + blockIdx.y * 16 + pl;
    const int t0 = blockIdx.z * CL_;

    const float Aval = -__expf(A_log[c * N_ + n]);

    const size_t rowP = ((size_t)b * L_ + t0) * PROJ_;
    const size_t rowX = ((size_t)b * L_ + t0) * DI_;
    const float* pdt = proj + rowP + c;
    const float* pB = proj + rowP + DI_ + h * N_ + n;
    const float* px = xi + rowX + c;

    float prod = 1.f, hs = 0.f;
#pragma unroll 4
    for (int t = 0; t < CL_; ++t) {
        const float dt_v = pdt[0];
        const float Bv = pB[0];
        const float xv = px[0];
        const float dA = __expf(dt_v * Aval);
        hs = fmaf(hs, dA, dt_v * Bv * xv);
        prod *= dA;
        pdt += PROJ_; pB += PROJ_; px += DI_;
    }
    // seq index: consecutive with tid
    const int sidx = (bh * P_ + blockIdx.y * 16 + pl) * N_ + n;
    st_prod[(size_t)blockIdx.z * NSEQ_ + sidx] = prod;
    st_hend[(size_t)blockIdx.z * NSEQ_ + sidx] = hs;
}

// Pass 2: sequential combine across chunks; emit each chunk's incoming state.
__launch_bounds__(256)
__global__ void scan_combine(const float* __restrict__ st_prod,
                             const float* __restrict__ st_hend,
                             float* __restrict__ st_hin) {
    const int s = blockIdx.x * 256 + threadIdx.x;   // 0..NSEQ_-1
    float H = 0.f;
#pragma unroll
    for (int k = 0; k < NC_; ++k) {
        const size_t o = (size_t)k * NSEQ_ + s;
        st_hin[o] = H;
        H = fmaf(st_prod[o], H, st_hend[o]);
    }
}

// Pass 3: re-scan each chunk seeded with true incoming state; emit gated y.
__launch_bounds__(256)
__global__ void scan_chunk_out(const float* __restrict__ xi,
                               const float* __restrict__ z,
                               const float* __restrict__ proj,
                               const float* __restrict__ A_log,
                               const float* __restrict__ D_skip,
                               const float* __restrict__ st_hin,
                               float* __restrict__ yg) {
    const int bh = blockIdx.x;
    const int b = bh >> 3;
    const int h = bh & 7;
    const int tid = threadIdx.x;
    const int pl = tid >> 4;
    const int n = tid & 15;
    const int c = h * P_ + blockIdx.y * 16 + pl;
    const int t0 = blockIdx.z * CL_;

    const float Aval = -__expf(A_log[c * N_ + n]);
    const float Dv = D_skip[c];

    const size_t rowP = ((size_t)b * L_ + t0) * PROJ_;
    const size_t rowX = ((size_t)b * L_ + t0) * DI_;
    const float* pdt = proj + rowP + c;
    const float* pB = proj + rowP + DI_ + h * N_ + n;
    const float* pC = proj + rowP + DI_ + H_ * N_ + h * N_ + n;
    const float* px = xi + rowX + c;
    const float* pz = z + rowX + c;
    float* py = yg + rowX + c;

    const int sidx = (bh * P_ + blockIdx.y * 16 + pl) * N_ + n;
    float hs = st_hin[(size_t)blockIdx.z * NSEQ_ + sidx];

    for (int t = 0; t < CL_; ++t) {
        const float dt_v = pdt[0];
        const float Bv = pB[0];
        const float Cv = pC[0];
        const float xv = px[0];
        const float dA = __expf(dt_v * Aval);
        hs = fmaf(hs, dA, dt_v * Bv * xv);
        float part = hs * Cv;
        part += __shfl_xor(part, 1);
        part += __shfl_xor(part, 2);
        part += __shfl_xor(part, 4);
        part += __shfl_xor(part, 8);
        if (n == 0) {
            const float zv = pz[0];
            const float g = zv / (1.f + __expf(-zv));
            py[0] = (part + Dv * xv) * g;
        }
        pdt += PROJ_; pB += PROJ_; pC += PROJ_; px += DI_; pz += DI_; py += DI_;
    }
}

// ---------------- layernorm + flip -----------------------------------------
__launch_bounds__(256)
__global__ void ln_flip(const float* __restrict__ x, const float* __restrict__ w,
                        const float* __restrict__ bvec, float* __restrict__ y) {
    const int row = blockIdx.x;       // b*L + l
    const int d = threadIdx.x;        // 0..255
    const float v = x[(size_t)row * D_ + d];
    float s = v, s2 = v * v;
#pragma unroll
    for (int m = 32; m; m >>= 1) {
        s += __shfl_xor(s, m);
        s2 += __shfl_xor(s2, m);
    }
    __shared__ float sh[8];
    const int wave = d >> 6;
    if ((d & 63) == 0) { sh[wave] = s; sh[4 + wave] = s2; }
    __syncthreads();
    const float ts = sh[0] + sh[1] + sh[2] + sh[3];
    const float ts2 = sh[4] + sh[5] + sh[6] + sh[7];
    const float mean = ts * (1.f / D_);
    const float var = ts2 * (1.f / D_) - mean * mean;
    const float inv = rsqrtf(var + 1e-5f);
    const int b = row >> 12;
    const int l = row & (L_ - 1);
    const int drow = (b << 12) + (L_ - 1 - l);
    y[(size_t)drow * D_ + d] = (v - mean) * inv * w[d] + bvec[d];
}

// ---------------- depthwise conv(k=3) + exact GELU, added in-place ----------
__launch_bounds__(256)
__global__ void conv_gelu_add(const float* __restrict__ x, const float* __restrict__ cw,
                              const float* __restrict__ cb, float* __restrict__ out) {
    const int idx = blockIdx.x * 256 + threadIdx.x;   // over B*L*D
    const int d = idx & (D_ - 1);
    const int l = (idx >> 8) & (L_ - 1);
    const int b = idx >> (8 + 12);
    float acc = cb[d];
    const float w0 = cw[d * 3 + 0], w1 = cw[d * 3 + 1], w2 = cw[d * 3 + 2];
    const size_t base = ((size_t)b * L_ + l) * D_ + d;
    if (l > 0) acc = fmaf(x[base - D_], w0, acc);
    acc = fmaf(x[base], w1, acc);
    if (l + 1 < L_) acc = fmaf(x[base + D_], w2, acc);
    const float g = 0.5f * acc * (1.f + erff(acc * 0.70710678118654752f));
    out[idx] += g;
}

// ---------------- host launcher --------------------------------------------
extern "C" void kernel_launch(void* const* d_in, const int* in_sizes, int n_in,
                              void* d_out, int out_size, void* d_ws, size_t ws_size,
                              hipStream_t stream) {
    const float* inputs = (const float*)d_in[0];
    const float* f_in_w = (const float*)d_in[1];
    const float* f_in_b = (const float*)d_in[2];
    const float* f_xp_w = (const float*)d_in[3];
    const float* f_xp_b = (const float*)d_in[4];
    const float* f_dt_b = (const float*)d_in[5];
    const float* f_A = (const float*)d_in[6];
    const float* f_D = (const float*)d_in[7];
    const float* f_out_w = (const float*)d_in[8];
    const float* f_out_b = (const float*)d_in[9];
    const float* b_in_w = (const float*)d_in[10];
    const float* b_in_b = (const float*)d_in[11];
    const float* b_xp_w = (const float*)d_in[12];
    const float* b_xp_b = (const float*)d_in[13];
    const float* b_dt_b = (const float*)d_in[14];
    const float* b_A = (const float*)d_in[15];
    const float* b_D = (const float*)d_in[16];
    const float* b_out_w = (const float*)d_in[17];
    const float* b_out_b = (const float*)d_in[18];
    const float* norm_w = (const float*)d_in[19];
    const float* norm_b = (const float*)d_in[20];
    const float* conv_w = (const float*)d_in[21];
    const float* conv_b = (const float*)d_in[22];
    float* out = (float*)d_out;

    // workspace layout (floats)
    float* ws = (float*)d_ws;
    float* xi   = ws;                               // 8,388,608
    float* zbuf = xi + (size_t)M_ * DI_;            // 8,388,608
    float* proj = zbuf + (size_t)M_ * DI_;          // 12,582,912
    float* yg   = proj + (size_t)M_ * PROJ_;        // 8,388,608
    float* y1n  = yg + (size_t)M_ * DI_;            // 4,194,304 floats
    float* y1   = proj;                             // alias: proj dead after scan

    // scan state buffers aliased into y1n's slot (dead during both scans):
    // 3 x NSEQ_*NC_ = 3 x 1,048,576 floats = 12.6 MB <= y1n's 16.8 MB
    float* st_prod = y1n;
    float* st_hend = st_prod + (size_t)NSEQ_ * NC_;
    float* st_hin  = st_hend + (size_t)NSEQ_ * NC_;

    const dim3 blk(256);
    const dim3 g_in(M_ / BM, (2 * DI_) / BN);   // (256,16)
    const dim3 g_xp(M_ / BM, PROJ_ / BN);       // (256,12)
    const dim3 g_out(M_ / BM, D_ / BN);         // (256,4)
    const dim3 g_chunk(B_ * H_, P_ / 16, NC_);  // (32,4,32) = 4096 blocks
    const dim3 g_comb(NSEQ_ / 256);             // 128 blocks

    // ---- forward pass ----
    gemm_nt<1><<<g_in, blk, 0, stream>>>(inputs, f_in_w, f_in_b, M_, 2 * DI_, D_,
                                         xi, zbuf, nullptr);
    gemm_nt<2><<<g_xp, blk, 0, stream>>>(xi, f_xp_w, f_xp_b, M_, PROJ_, DI_,
                                         proj, nullptr, f_dt_b);
    scan_chunk_state<<<g_chunk, blk, 0, stream>>>(xi, proj, f_A, st_prod, st_hend);
    scan_combine<<<g_comb, blk, 0, stream>>>(st_prod, st_hend, st_hin);
    scan_chunk_out<<<g_chunk, blk, 0, stream>>>(xi, zbuf, proj, f_A, f_D, st_hin, yg);
    gemm_nt<0><<<g_out, blk, 0, stream>>>(yg, f_out_w, f_out_b, M_, D_, DI_,
                                          y1, nullptr, nullptr);
    ln_flip<<<dim3(M_), blk, 0, stream>>>(y1, norm_w, norm_b, y1n);

    // ---- backward pass ----
    gemm_nt<1><<<g_in, blk, 0, stream>>>(y1n, b_in_w, b_in_b, M_, 2 * DI_, D_,
                                         xi, zbuf, nullptr);
    gemm_nt<2><<<g_xp, blk, 0, stream>>>(xi, b_xp_w, b_xp_b, M_, PROJ_, DI_,
                                         proj, nullptr, b_dt_b);
    scan_chunk_state<<<g_chunk, blk, 0, stream>>>(xi, proj, b_A, st_prod, st_hend);
    scan_combine<<<g_comb, blk, 0, stream>>>(st_prod, st_hend, st_hin);
    scan_chunk_out<<<g_chunk, blk, 0, stream>>>(xi, zbuf, proj, b_A, b_D, st_hin, yg);
    gemm_nt<3><<<g_out, blk, 0, stream>>>(yg, b_out_w, b_out_b, M_, D_, DI_,
                                          out, nullptr, nullptr);

    // ---- locality branch ----
    conv_gelu_add<<<dim3(M_ * D_ / 256), blk, 0, stream>>>(inputs, conv_w, conv_b, out);
}

// Round 3
// 897.153 us; speedup vs baseline: 4.7362x; 1.8635x over previous
//
#include <hip/hip_runtime.h>
#include <hip/hip_bf16.h>
#include <cstdint>
#include <cstddef>

// ---------------- problem constants ----------------
#define B_  4
#define L_  4096
#define D_  256
#define DI_ 512
#define H_  8
#define P_  64
#define N_  16
#define M_  (B_ * L_)              // 16384 rows
#define PROJ_ (DI_ + 2 * H_ * N_)  // 768

// chunked scan parameters
#define NC_ 32                     // chunks along L
#define CL_ (L_ / NC_)             // 128
#define NSEQ_ (B_ * H_ * P_ * N_)  // 32768 scalar sequences

typedef __bf16 bf16x8 __attribute__((ext_vector_type(8)));
typedef float f32x4 __attribute__((ext_vector_type(4)));

__device__ __forceinline__ void cp16_lds(const __hip_bfloat16* g, short* lds) {
    __builtin_amdgcn_global_load_lds(
        (const __attribute__((address_space(1))) void*)g,
        (__attribute__((address_space(3))) void*)lds, 16, 0, 0);
}

// ---------------- fp32 -> bf16 conversion -----------------------------------
__global__ void f2b(const float* __restrict__ in, __hip_bfloat16* __restrict__ out, int n) {
    for (int i = blockIdx.x * 256 + threadIdx.x; i < n; i += gridDim.x * 256)
        out[i] = __float2bfloat16(in[i]);
}

// ---------------- MFMA bf16 GEMM: C = A(M,K) * W(N,K)^T + bias --------------
// 128x128 tile, BK=32, 4 waves in 2x2, each wave 4x4 mfma_f32_16x16x32_bf16.
// EPI 0: fp32 store, ld=256 (y1)
// EPI 1: in_proj: col<DI -> silu -> out0 fp32 (ld 512) + obf bf16; else out1 (z)
// EPI 2: x_proj: col<DI -> softplus(v+aux); fp32 store ld=768
// EPI 3: fp32 store row-flipped along L, ld=256 (d_out)
template <int EPI>
__launch_bounds__(256)
__global__ void gemm_mfma(const __hip_bfloat16* __restrict__ A,
                          const __hip_bfloat16* __restrict__ W,
                          const float* __restrict__ bias, int Kv,
                          float* __restrict__ out0, float* __restrict__ out1,
                          __hip_bfloat16* __restrict__ obf,
                          const float* __restrict__ aux) {
    __shared__ short As[128 * 32];
    __shared__ short Bs[128 * 32];
    const int tid = threadIdx.x;
    const int lane = tid & 63;
    const int wave = tid >> 6;
    const int bm = blockIdx.x * 128;
    const int bn = blockIdx.y * 128;
    const int wm = (wave >> 1) * 64;
    const int wn = (wave & 1) * 64;

    f32x4 acc[4][4];
#pragma unroll
    for (int i = 0; i < 4; ++i)
#pragma unroll
        for (int j = 0; j < 4; ++j) acc[i][j] = (f32x4)0.f;

    // staging: each wave stages 32 rows of A-tile and B-tile (2 insts each).
    // one inst: 64 lanes x 16B = 16 rows x 64B; lane -> row lane>>2, kgrp lane&3.
    const int srow = lane >> 2;
    const int sk = (lane & 3) * 8;
    const __hip_bfloat16* gA0 = A + (size_t)(bm + wave * 32 + srow) * Kv + sk;
    const __hip_bfloat16* gA1 = gA0 + (size_t)16 * Kv;
    const __hip_bfloat16* gB0 = W + (size_t)(bn + wave * 32 + srow) * Kv + sk;
    const __hip_bfloat16* gB1 = gB0 + (size_t)16 * Kv;
    short* lA0 = As + (wave * 32) * 32;
    short* lA1 = As + (wave * 32 + 16) * 32;
    short* lB0 = Bs + (wave * 32) * 32;
    short* lB1 = Bs + (wave * 32 + 16) * 32;

    const int fr = lane & 15;          // fragment row (m or n)
    const int fk = (lane >> 4) * 8;    // fragment k offset

    for (int k0 = 0; k0 < Kv; k0 += 32) {
        cp16_lds(gA0 + k0, lA0);
        cp16_lds(gA1 + k0, lA1);
        cp16_lds(gB0 + k0, lB0);
        cp16_lds(gB1 + k0, lB1);
        __syncthreads();
        bf16x8 af[4], bv[4];
#pragma unroll
        for (int i = 0; i < 4; ++i)
            af[i] = *reinterpret_cast<const bf16x8*>(&As[(wm + i * 16 + fr) * 32 + fk]);
#pragma unroll
        for (int j = 0; j < 4; ++j)
            bv[j] = *reinterpret_cast<const bf16x8*>(&Bs[(wn + j * 16 + fr) * 32 + fk]);
#pragma unroll
        for (int i = 0; i < 4; ++i)
#pragma unroll
            for (int j = 0; j < 4; ++j)
                acc[i][j] = __builtin_amdgcn_mfma_f32_16x16x32_bf16(
                    af[i], bv[j], acc[i][j], 0, 0, 0);
        __syncthreads();
    }

    // epilogue: C/D layout col = lane&15, row = (lane>>4)*4 + v (m89/m91)
    const int n16 = lane & 15;
    const int r4 = (lane >> 4) * 4;
#pragma unroll
    for (int i = 0; i < 4; ++i) {
#pragma unroll
        for (int j = 0; j < 4; ++j) {
            const int cg = bn + wn + j * 16 + n16;
            const float bb = bias[cg];
#pragma unroll
            for (int v = 0; v < 4; ++v) {
                const int r = bm + wm + i * 16 + r4 + v;
                float val = acc[i][j][v] + bb;
                if (EPI == 0) {
                    out0[(size_t)r * 256 + cg] = val;
                } else if (EPI == 1) {
                    if (cg < DI_) {
                        val = val / (1.f + __expf(-val));
                        out0[(size_t)r * DI_ + cg] = val;
                        obf[(size_t)r * DI_ + cg] = __float2bfloat16(val);
                    } else {
                        out1[(size_t)r * DI_ + cg - DI_] = val;
                    }
                } else if (EPI == 2) {
                    if (cg < DI_) {
                        float x = val + aux[cg];
                        val = (x > 20.f) ? x : log1pf(__expf(x));
                    }
                    out0[(size_t)r * PROJ_ + cg] = val;
                } else {
                    const int b = r >> 12;
                    const int l = r & (L_ - 1);
                    out0[(size_t)((b << 12) + (L_ - 1 - l)) * 256 + cg] = val;
                }
            }
        }
    }
}

// ---------------- chunked selective scan ------------------------------------
__launch_bounds__(256)
__global__ void scan_chunk_state(const float* __restrict__ xi,
                                 const float* __restrict__ proj,
                                 const float* __restrict__ A_log,
                                 float* __restrict__ st_prod,
                                 float* __restrict__ st_hend) {
    const int bh = blockIdx.x;
    const int b = bh >> 3;
    const int h = bh & 7;
    const int tid = threadIdx.x;
    const int pl = tid >> 4;
    const int n = tid & 15;
    const int c = h * P_ + blockIdx.y * 16 + pl;
    const int t0 = blockIdx.z * CL_;

    const float Aval = -__expf(A_log[c * N_ + n]);

    const size_t rowP = ((size_t)b * L_ + t0) * PROJ_;
    const size_t rowX = ((size_t)b * L_ + t0) * DI_;
    const float* pdt = proj + rowP + c;
    const float* pB = proj + rowP + DI_ + h * N_ + n;
    const float* px = xi + rowX + c;

    float prod = 1.f, hs = 0.f;
#pragma unroll 4
    for (int t = 0; t < CL_; ++t) {
        const float dt_v = pdt[0];
        const float Bv = pB[0];
        const float xv = px[0];
        const float dA = __expf(dt_v * Aval);
        hs = fmaf(hs, dA, dt_v * Bv * xv);
        prod *= dA;
        pdt += PROJ_; pB += PROJ_; px += DI_;
    }
    const int sidx = (bh * P_ + blockIdx.y * 16 + pl) * N_ + n;
    st_prod[(size_t)blockIdx.z * NSEQ_ + sidx] = prod;
    st_hend[(size_t)blockIdx.z * NSEQ_ + sidx] = hs;
}

__launch_bounds__(256)
__global__ void scan_combine(const float* __restrict__ st_prod,
                             const float* __restrict__ st_hend,
                             float* __restrict__ st_hin) {
    const int s = blockIdx.x * 256 + threadIdx.x;
    float H = 0.f;
#pragma unroll
    for (int k = 0; k < NC_; ++k) {
        const size_t o = (size_t)k * NSEQ_ + s;
        st_hin[o] = H;
        H = fmaf(st_prod[o], H, st_hend[o]);
    }
}

__launch_bounds__(256)
__global__ void scan_chunk_out(const float* __restrict__ xi,
                               const float* __restrict__ z,
                               const float* __restrict__ proj,
                               const float* __restrict__ A_log,
                               const float* __restrict__ D_skip,
                               const float* __restrict__ st_hin,
                               __hip_bfloat16* __restrict__ yg) {
    const int bh = blockIdx.x;
    const int b = bh >> 3;
    const int h = bh & 7;
    const int tid = threadIdx.x;
    const int pl = tid >> 4;
    const int n = tid & 15;
    const int c = h * P_ + blockIdx.y * 16 + pl;
    const int t0 = blockIdx.z * CL_;

    const float Aval = -__expf(A_log[c * N_ + n]);
    const float Dv = D_skip[c];

    const size_t rowP = ((size_t)b * L_ + t0) * PROJ_;
    const size_t rowX = ((size_t)b * L_ + t0) * DI_;
    const float* pdt = proj + rowP + c;
    const float* pB = proj + rowP + DI_ + h * N_ + n;
    const float* pC = proj + rowP + DI_ + H_ * N_ + h * N_ + n;
    const float* px = xi + rowX + c;
    const float* pz = z + rowX + c;
    __hip_bfloat16* py = yg + rowX + c;

    const int sidx = (bh * P_ + blockIdx.y * 16 + pl) * N_ + n;
    float hs = st_hin[(size_t)blockIdx.z * NSEQ_ + sidx];

    for (int t = 0; t < CL_; ++t) {
        const float dt_v = pdt[0];
        const float Bv = pB[0];
        const float Cv = pC[0];
        const float xv = px[0];
        const float dA = __expf(dt_v * Aval);
        hs = fmaf(hs, dA, dt_v * Bv * xv);
        float part = hs * Cv;
        part += __shfl_xor(part, 1);
        part += __shfl_xor(part, 2);
        part += __shfl_xor(part, 4);
        part += __shfl_xor(part, 8);
        if (n == 0) {
            const float zv = pz[0];
            const float g = zv / (1.f + __expf(-zv));
            py[0] = __float2bfloat16((part + Dv * xv) * g);
        }
        pdt += PROJ_; pB += PROJ_; pC += PROJ_; px += DI_; pz += DI_; py += DI_;
    }
}

// ---------------- layernorm + flip (bf16 out) --------------------------------
__launch_bounds__(256)
__global__ void ln_flip(const float* __restrict__ x, const float* __restrict__ w,
                        const float* __restrict__ bvec, __hip_bfloat16* __restrict__ y) {
    const int row = blockIdx.x;
    const int d = threadIdx.x;
    const float v = x[(size_t)row * D_ + d];
    float s = v, s2 = v * v;
#pragma unroll
    for (int m = 32; m; m >>= 1) {
        s += __shfl_xor(s, m);
        s2 += __shfl_xor(s2, m);
    }
    __shared__ float sh[8];
    const int wave = d >> 6;
    if ((d & 63) == 0) { sh[wave] = s; sh[4 + wave] = s2; }
    __syncthreads();
    const float ts = sh[0] + sh[1] + sh[2] + sh[3];
    const float ts2 = sh[4] + sh[5] + sh[6] + sh[7];
    const float mean = ts * (1.f / D_);
    const float var = ts2 * (1.f / D_) - mean * mean;
    const float inv = rsqrtf(var + 1e-5f);
    const int b = row >> 12;
    const int l = row & (L_ - 1);
    const int drow = (b << 12) + (L_ - 1 - l);
    y[(size_t)drow * D_ + d] = __float2bfloat16((v - mean) * inv * w[d] + bvec[d]);
}

// ---------------- depthwise conv(k=3) + exact GELU, added in-place ----------
__launch_bounds__(256)
__global__ void conv_gelu_add(const float* __restrict__ x, const float* __restrict__ cw,
                              const float* __restrict__ cb, float* __restrict__ out) {
    const int idx = blockIdx.x * 256 + threadIdx.x;
    const int d = idx & (D_ - 1);
    const int l = (idx >> 8) & (L_ - 1);
    const int b = idx >> (8 + 12);
    float acc = cb[d];
    const float w0 = cw[d * 3 + 0], w1 = cw[d * 3 + 1], w2 = cw[d * 3 + 2];
    const size_t base = ((size_t)b * L_ + l) * D_ + d;
    if (l > 0) acc = fmaf(x[base - D_], w0, acc);
    acc = fmaf(x[base], w1, acc);
    if (l + 1 < L_) acc = fmaf(x[base + D_], w2, acc);
    const float g = 0.5f * acc * (1.f + erff(acc * 0.70710678118654752f));
    out[idx] += g;
}

// ---------------- host launcher --------------------------------------------
extern "C" void kernel_launch(void* const* d_in, const int* in_sizes, int n_in,
                              void* d_out, int out_size, void* d_ws, size_t ws_size,
                              hipStream_t stream) {
    const float* inputs = (const float*)d_in[0];
    const float* f_in_w = (const float*)d_in[1];
    const float* f_in_b = (const float*)d_in[2];
    const float* f_xp_w = (const float*)d_in[3];
    const float* f_xp_b = (const float*)d_in[4];
    const float* f_dt_b = (const float*)d_in[5];
    const float* f_A = (const float*)d_in[6];
    const float* f_D = (const float*)d_in[7];
    const float* f_out_w = (const float*)d_in[8];
    const float* f_out_b = (const float*)d_in[9];
    const float* b_in_w = (const float*)d_in[10];
    const float* b_in_b = (const float*)d_in[11];
    const float* b_xp_w = (const float*)d_in[12];
    const float* b_xp_b = (const float*)d_in[13];
    const float* b_dt_b = (const float*)d_in[14];
    const float* b_A = (const float*)d_in[15];
    const float* b_D = (const float*)d_in[16];
    const float* b_out_w = (const float*)d_in[17];
    const float* b_out_b = (const float*)d_in[18];
    const float* norm_w = (const float*)d_in[19];
    const float* norm_b = (const float*)d_in[20];
    const float* conv_w = (const float*)d_in[21];
    const float* conv_b = (const float*)d_in[22];
    float* out = (float*)d_out;

    // workspace layout (float-sized slots)
    float* ws = (float*)d_ws;
    float* xi_f32 = ws;                                   // 8,388,608 f
    float* zbuf   = xi_f32 + (size_t)M_ * DI_;            // 8,388,608 f
    float* proj   = zbuf + (size_t)M_ * DI_;              // 12,582,912 f
    float* y1     = proj + (size_t)M_ * PROJ_;            // 4,194,304 f
    __hip_bfloat16* xi_bf = (__hip_bfloat16*)(y1 + (size_t)M_ * D_);       // 8,388,608 bf16
    __hip_bfloat16* yg_bf = xi_bf + (size_t)M_ * DI_;                      // 8,388,608 bf16
    __hip_bfloat16* a_bf  = yg_bf + (size_t)M_ * DI_;                      // 4,194,304 bf16 (inputs_bf16 / y1n)
    __hip_bfloat16* wpool = a_bf + (size_t)M_ * D_;                        // 1,572,864 bf16
    __hip_bfloat16* f_in_wb  = wpool;
    __hip_bfloat16* f_xp_wb  = f_in_wb + 2 * DI_ * D_;     // +262144
    __hip_bfloat16* f_out_wb = f_xp_wb + PROJ_ * DI_;      // +393216
    __hip_bfloat16* b_in_wb  = f_out_wb + D_ * DI_;        // +131072
    __hip_bfloat16* b_xp_wb  = b_in_wb + 2 * DI_ * D_;
    __hip_bfloat16* b_out_wb = b_xp_wb + PROJ_ * DI_;

    // scan state buffers aliased into y1's slot (y1 dead during both scans):
    // 3 x 1,048,576 floats = 12.58 MB <= y1's 16.78 MB
    float* st_prod = y1;
    float* st_hend = st_prod + (size_t)NSEQ_ * NC_;
    float* st_hin  = st_hend + (size_t)NSEQ_ * NC_;

    const dim3 blk(256);
    const dim3 g_in(M_ / 128, (2 * DI_) / 128);   // (128,8)
    const dim3 g_xp(M_ / 128, PROJ_ / 128);       // (128,6)
    const dim3 g_out(M_ / 128, 2);                // (128,2)
    const dim3 g_chunk(B_ * H_, P_ / 16, NC_);    // 4096 blocks
    const dim3 g_comb(NSEQ_ / 256);

    // ---- fp32 -> bf16 conversions (weights + inputs) ----
    f2b<<<dim3(1024), blk, 0, stream>>>(inputs, a_bf, M_ * D_);
    f2b<<<dim3(256), blk, 0, stream>>>(f_in_w, f_in_wb, 2 * DI_ * D_);
    f2b<<<dim3(256), blk, 0, stream>>>(f_xp_w, f_xp_wb, PROJ_ * DI_);
    f2b<<<dim3(256), blk, 0, stream>>>(f_out_w, f_out_wb, D_ * DI_);
    f2b<<<dim3(256), blk, 0, stream>>>(b_in_w, b_in_wb, 2 * DI_ * D_);
    f2b<<<dim3(256), blk, 0, stream>>>(b_xp_w, b_xp_wb, PROJ_ * DI_);
    f2b<<<dim3(256), blk, 0, stream>>>(b_out_w, b_out_wb, D_ * DI_);

    // ---- forward pass ----
    gemm_mfma<1><<<g_in, blk, 0, stream>>>(a_bf, f_in_wb, f_in_b, D_,
                                           xi_f32, zbuf, xi_bf, nullptr);
    gemm_mfma<2><<<g_xp, blk, 0, stream>>>(xi_bf, f_xp_wb, f_xp_b, DI_,
                                           proj, nullptr, nullptr, f_dt_b);
    scan_chunk_state<<<g_chunk, blk, 0, stream>>>(xi_f32, proj, f_A, st_prod, st_hend);
    scan_combine<<<g_comb, blk, 0, stream>>>(st_prod, st_hend, st_hin);
    scan_chunk_out<<<g_chunk, blk, 0, stream>>>(xi_f32, zbuf, proj, f_A, f_D, st_hin, yg_bf);
    gemm_mfma<0><<<g_out, blk, 0, stream>>>(yg_bf, f_out_wb, f_out_b, DI_,
                                            y1, nullptr, nullptr, nullptr);
    ln_flip<<<dim3(M_), blk, 0, stream>>>(y1, norm_w, norm_b, a_bf);

    // ---- backward pass ----
    gemm_mfma<1><<<g_in, blk, 0, stream>>>(a_bf, b_in_wb, b_in_b, D_,
                                           xi_f32, zbuf, xi_bf, nullptr);
    gemm_mfma<2><<<g_xp, blk, 0, stream>>>(xi_bf, b_xp_wb, b_xp_b, DI_,
                                           proj, nullptr, nullptr, b_dt_b);
    scan_chunk_state<<<g_chunk, blk, 0, stream>>>(xi_f32, proj, b_A, st_prod, st_hend);
    scan_combine<<<g_comb, blk, 0, stream>>>(st_prod, st_hend, st_hin);
    scan_chunk_out<<<g_chunk, blk, 0, stream>>>(xi_f32, zbuf, proj, b_A, b_D, st_hin, yg_bf);
    gemm_mfma<3><<<g_out, blk, 0, stream>>>(yg_bf, b_out_wb, b_out_b, DI_,
                                            out, nullptr, nullptr, nullptr);

    // ---- locality branch ----
    conv_gelu_add<<<dim3(M_ * D_ / 256), blk, 0, stream>>>(inputs, conv_w, conv_b, out);
}

// Round 4
// 589.132 us; speedup vs baseline: 7.2124x; 1.5228x over previous
//
#include <hip/hip_runtime.h>
#include <hip/hip_bf16.h>
#include <cstdint>
#include <cstddef>

// ---------------- problem constants ----------------
#define B_  4
#define L_  4096
#define D_  256
#define DI_ 512
#define H_  8
#define P_  64
#define N_  16
#define M_  (B_ * L_)              // 16384 rows
#define PROJ_ (DI_ + 2 * H_ * N_)  // 768

// chunked scan parameters (N held in registers; 1 thread = 1 (b,h,p) channel)
#define NC_ 128                    // chunks along L
#define CL_ (L_ / NC_)             // 32
#define NSEQ_ (B_ * H_ * P_ * N_)  // 32768 scalar sequences
#define LOG2E_ 1.4426950408889634f

typedef __bf16 bf16x8 __attribute__((ext_vector_type(8)));
typedef float f32x4 __attribute__((ext_vector_type(4)));

__device__ __forceinline__ void cp16_lds(const __hip_bfloat16* g, short* lds) {
    __builtin_amdgcn_global_load_lds(
        (const __attribute__((address_space(1))) void*)g,
        (__attribute__((address_space(3))) void*)lds, 16, 0, 0);
}

// ---------------- fp32 -> bf16 conversion -----------------------------------
__global__ void f2b(const float* __restrict__ in, __hip_bfloat16* __restrict__ out, int n) {
    for (int i = blockIdx.x * 256 + threadIdx.x; i < n; i += gridDim.x * 256)
        out[i] = __float2bfloat16(in[i]);
}

// ---------------- MFMA bf16 GEMM: C = A(M,K) * W(N,K)^T + bias --------------
// 128x128 tile, BK=32, 4 waves in 2x2, each wave 4x4 mfma_f32_16x16x32_bf16.
// EPI 0: fp32 store, ld=256 (y1)
// EPI 1: in_proj: col<DI -> silu -> obf bf16 (xi); else out1 fp32 (z)
// EPI 2: x_proj: col<DI -> softplus(v+aux); fp32 store ld=768
// EPI 3: fp32 store row-flipped along L, ld=256 (d_out)
template <int EPI>
__launch_bounds__(256)
__global__ void gemm_mfma(const __hip_bfloat16* __restrict__ A,
                          const __hip_bfloat16* __restrict__ W,
                          const float* __restrict__ bias, int Kv,
                          float* __restrict__ out0, float* __restrict__ out1,
                          __hip_bfloat16* __restrict__ obf,
                          const float* __restrict__ aux) {
    __shared__ short As[128 * 32];
    __shared__ short Bs[128 * 32];
    const int tid = threadIdx.x;
    const int lane = tid & 63;
    const int wave = tid >> 6;
    const int bm = blockIdx.x * 128;
    const int bn = blockIdx.y * 128;
    const int wm = (wave >> 1) * 64;
    const int wn = (wave & 1) * 64;

    f32x4 acc[4][4];
#pragma unroll
    for (int i = 0; i < 4; ++i)
#pragma unroll
        for (int j = 0; j < 4; ++j) acc[i][j] = (f32x4)0.f;

    const int srow = lane >> 2;
    const int sk = (lane & 3) * 8;
    const __hip_bfloat16* gA0 = A + (size_t)(bm + wave * 32 + srow) * Kv + sk;
    const __hip_bfloat16* gA1 = gA0 + (size_t)16 * Kv;
    const __hip_bfloat16* gB0 = W + (size_t)(bn + wave * 32 + srow) * Kv + sk;
    const __hip_bfloat16* gB1 = gB0 + (size_t)16 * Kv;
    short* lA0 = As + (wave * 32) * 32;
    short* lA1 = As + (wave * 32 + 16) * 32;
    short* lB0 = Bs + (wave * 32) * 32;
    short* lB1 = Bs + (wave * 32 + 16) * 32;

    const int fr = lane & 15;
    const int fk = (lane >> 4) * 8;

    for (int k0 = 0; k0 < Kv; k0 += 32) {
        cp16_lds(gA0 + k0, lA0);
        cp16_lds(gA1 + k0, lA1);
        cp16_lds(gB0 + k0, lB0);
        cp16_lds(gB1 + k0, lB1);
        __syncthreads();
        bf16x8 af[4], bv[4];
#pragma unroll
        for (int i = 0; i < 4; ++i)
            af[i] = *reinterpret_cast<const bf16x8*>(&As[(wm + i * 16 + fr) * 32 + fk]);
#pragma unroll
        for (int j = 0; j < 4; ++j)
            bv[j] = *reinterpret_cast<const bf16x8*>(&Bs[(wn + j * 16 + fr) * 32 + fk]);
#pragma unroll
        for (int i = 0; i < 4; ++i)
#pragma unroll
            for (int j = 0; j < 4; ++j)
                acc[i][j] = __builtin_amdgcn_mfma_f32_16x16x32_bf16(
                    af[i], bv[j], acc[i][j], 0, 0, 0);
        __syncthreads();
    }

    const int n16 = lane & 15;
    const int r4 = (lane >> 4) * 4;
#pragma unroll
    for (int i = 0; i < 4; ++i) {
#pragma unroll
        for (int j = 0; j < 4; ++j) {
            const int cg = bn + wn + j * 16 + n16;
            const float bb = bias[cg];
#pragma unroll
            for (int v = 0; v < 4; ++v) {
                const int r = bm + wm + i * 16 + r4 + v;
                float val = acc[i][j][v] + bb;
                if (EPI == 0) {
                    out0[(size_t)r * 256 + cg] = val;
                } else if (EPI == 1) {
                    if (cg < DI_) {
                        val = val / (1.f + __expf(-val));
                        obf[(size_t)r * DI_ + cg] = __float2bfloat16(val);
                    } else {
                        out1[(size_t)r * DI_ + cg - DI_] = val;
                    }
                } else if (EPI == 2) {
                    if (cg < DI_) {
                        float x = val + aux[cg];
                        val = (x > 20.f) ? x : log1pf(__expf(x));
                    }
                    out0[(size_t)r * PROJ_ + cg] = val;
                } else {
                    const int b = r >> 12;
                    const int l = r & (L_ - 1);
                    out0[(size_t)((b << 12) + (L_ - 1 - l)) * 256 + cg] = val;
                }
            }
        }
    }
}

// ---------------- chunked selective scan, N in registers ---------------------
// grid: (B_*H_, NC_/4), block 256; wave w handles chunk blockIdx.y*4+w,
// lane = p. One thread owns h[16] for channel c = h*64+p.

__launch_bounds__(256)
__global__ void scan_chunk_state(const __hip_bfloat16* __restrict__ xi,
                                 const float* __restrict__ proj,
                                 const float* __restrict__ A_log,
                                 float* __restrict__ st_prod,
                                 float* __restrict__ st_hend) {
    const int bh = blockIdx.x;
    const int b = bh >> 3;
    const int h = bh & 7;
    const int lane = threadIdx.x & 63;
    const int wave = threadIdx.x >> 6;
    const int chunk = blockIdx.y * 4 + wave;
    const int t0 = chunk * CL_;
    const int c = h * P_ + lane;

    float A2[N_], hs[N_], pr[N_];
#pragma unroll
    for (int n = 0; n < N_; ++n) {
        A2[n] = -__expf(A_log[c * N_ + n]) * LOG2E_;
        hs[n] = 0.f;
        pr[n] = 1.f;
    }

    const float* pP = proj + ((size_t)b * L_ + t0) * PROJ_;
    const __hip_bfloat16* px = xi + ((size_t)b * L_ + t0) * DI_ + c;
    const int bOff = DI_ + h * N_;

#pragma unroll 4
    for (int t = 0; t < CL_; ++t) {
        const float dt_v = pP[c];
        const float xv = __bfloat162float(px[0]);
        const float4 B0 = *reinterpret_cast<const float4*>(pP + bOff);
        const float4 B1 = *reinterpret_cast<const float4*>(pP + bOff + 4);
        const float4 B2 = *reinterpret_cast<const float4*>(pP + bOff + 8);
        const float4 B3 = *reinterpret_cast<const float4*>(pP + bOff + 12);
        const float Bv[N_] = {B0.x, B0.y, B0.z, B0.w, B1.x, B1.y, B1.z, B1.w,
                              B2.x, B2.y, B2.z, B2.w, B3.x, B3.y, B3.z, B3.w};
        const float dtx = dt_v * xv;
#pragma unroll
        for (int n = 0; n < N_; ++n) {
            const float dA = exp2f(dt_v * A2[n]);
            hs[n] = fmaf(hs[n], dA, dtx * Bv[n]);
            pr[n] *= dA;
        }
        pP += PROJ_; px += DI_;
    }

    const size_t s0 = (size_t)chunk * NSEQ_ + ((size_t)(bh * P_ + lane)) * N_;
#pragma unroll
    for (int n = 0; n < N_; n += 4) {
        *reinterpret_cast<float4*>(st_prod + s0 + n) =
            make_float4(pr[n], pr[n + 1], pr[n + 2], pr[n + 3]);
        *reinterpret_cast<float4*>(st_hend + s0 + n) =
            make_float4(hs[n], hs[n + 1], hs[n + 2], hs[n + 3]);
    }
}

// Pass 2: sequential combine; writes each chunk's incoming state IN PLACE over
// st_prod (st_prod becomes st_hin).
__launch_bounds__(256)
__global__ void scan_combine(float* __restrict__ st_prod,
                             const float* __restrict__ st_hend) {
    const int s = blockIdx.x * 256 + threadIdx.x;
    float H = 0.f;
#pragma unroll 8
    for (int k = 0; k < NC_; ++k) {
        const size_t o = (size_t)k * NSEQ_ + s;
        const float Pv = st_prod[o];
        const float Ev = st_hend[o];
        st_prod[o] = H;
        H = fmaf(Pv, H, Ev);
    }
}

__launch_bounds__(256)
__global__ void scan_chunk_out(const __hip_bfloat16* __restrict__ xi,
                               const float* __restrict__ z,
                               const float* __restrict__ proj,
                               const float* __restrict__ A_log,
                               const float* __restrict__ D_skip,
                               const float* __restrict__ st_hin,
                               __hip_bfloat16* __restrict__ yg) {
    const int bh = blockIdx.x;
    const int b = bh >> 3;
    const int h = bh & 7;
    const int lane = threadIdx.x & 63;
    const int wave = threadIdx.x >> 6;
    const int chunk = blockIdx.y * 4 + wave;
    const int t0 = chunk * CL_;
    const int c = h * P_ + lane;

    float A2[N_], hs[N_];
    const size_t s0 = (size_t)chunk * NSEQ_ + ((size_t)(bh * P_ + lane)) * N_;
#pragma unroll
    for (int n = 0; n < N_; n += 4) {
        const float4 h4 = *reinterpret_cast<const float4*>(st_hin + s0 + n);
        hs[n] = h4.x; hs[n + 1] = h4.y; hs[n + 2] = h4.z; hs[n + 3] = h4.w;
    }
#pragma unroll
    for (int n = 0; n < N_; ++n)
        A2[n] = -__expf(A_log[c * N_ + n]) * LOG2E_;
    const float Dv = D_skip[c];

    const float* pP = proj + ((size_t)b * L_ + t0) * PROJ_;
    const __hip_bfloat16* px = xi + ((size_t)b * L_ + t0) * DI_ + c;
    const float* pz = z + ((size_t)b * L_ + t0) * DI_ + c;
    __hip_bfloat16* py = yg + ((size_t)b * L_ + t0) * DI_ + c;
    const int bOff = DI_ + h * N_;
    const int cOff = DI_ + H_ * N_ + h * N_;

#pragma unroll 4
    for (int t = 0; t < CL_; ++t) {
        const float dt_v = pP[c];
        const float xv = __bfloat162float(px[0]);
        const float zv = pz[0];
        const float4 B0 = *reinterpret_cast<const float4*>(pP + bOff);
        const float4 B1 = *reinterpret_cast<const float4*>(pP + bOff + 4);
        const float4 B2 = *reinterpret_cast<const float4*>(pP + bOff + 8);
        const float4 B3 = *reinterpret_cast<const float4*>(pP + bOff + 12);
        const float4 C0 = *reinterpret_cast<const float4*>(pP + cOff);
        const float4 C1 = *reinterpret_cast<const float4*>(pP + cOff + 4);
        const float4 C2 = *reinterpret_cast<const float4*>(pP + cOff + 8);
        const float4 C3 = *reinterpret_cast<const float4*>(pP + cOff + 12);
        const float Bv[N_] = {B0.x, B0.y, B0.z, B0.w, B1.x, B1.y, B1.z, B1.w,
                              B2.x, B2.y, B2.z, B2.w, B3.x, B3.y, B3.z, B3.w};
        const float Cv[N_] = {C0.x, C0.y, C0.z, C0.w, C1.x, C1.y, C1.z, C1.w,
                              C2.x, C2.y, C2.z, C2.w, C3.x, C3.y, C3.z, C3.w};
        const float dtx = dt_v * xv;
        float y = 0.f;
#pragma unroll
        for (int n = 0; n < N_; ++n) {
            const float dA = exp2f(dt_v * A2[n]);
            hs[n] = fmaf(hs[n], dA, dtx * Bv[n]);
            y = fmaf(hs[n], Cv[n], y);
        }
        const float g = zv / (1.f + __expf(-zv));
        py[0] = __float2bfloat16((y + Dv * xv) * g);
        pP += PROJ_; px += DI_; pz += DI_; py += DI_;
    }
}

// ---------------- layernorm + flip (bf16 out) --------------------------------
__launch_bounds__(256)
__global__ void ln_flip(const float* __restrict__ x, const float* __restrict__ w,
                        const float* __restrict__ bvec, __hip_bfloat16* __restrict__ y) {
    const int row = blockIdx.x;
    const int d = threadIdx.x;
    const float v = x[(size_t)row * D_ + d];
    float s = v, s2 = v * v;
#pragma unroll
    for (int m = 32; m; m >>= 1) {
        s += __shfl_xor(s, m);
        s2 += __shfl_xor(s2, m);
    }
    __shared__ float sh[8];
    const int wave = d >> 6;
    if ((d & 63) == 0) { sh[wave] = s; sh[4 + wave] = s2; }
    __syncthreads();
    const float ts = sh[0] + sh[1] + sh[2] + sh[3];
    const float ts2 = sh[4] + sh[5] + sh[6] + sh[7];
    const float mean = ts * (1.f / D_);
    const float var = ts2 * (1.f / D_) - mean * mean;
    const float inv = rsqrtf(var + 1e-5f);
    const int b = row >> 12;
    const int l = row & (L_ - 1);
    const int drow = (b << 12) + (L_ - 1 - l);
    y[(size_t)drow * D_ + d] = __float2bfloat16((v - mean) * inv * w[d] + bvec[d]);
}

// ---------------- depthwise conv(k=3) + exact GELU, added in-place ----------
__launch_bounds__(256)
__global__ void conv_gelu_add(const float* __restrict__ x, const float* __restrict__ cw,
                              const float* __restrict__ cb, float* __restrict__ out) {
    const int idx = blockIdx.x * 256 + threadIdx.x;
    const int d = idx & (D_ - 1);
    const int l = (idx >> 8) & (L_ - 1);
    const int b = idx >> (8 + 12);
    float acc = cb[d];
    const float w0 = cw[d * 3 + 0], w1 = cw[d * 3 + 1], w2 = cw[d * 3 + 2];
    const size_t base = ((size_t)b * L_ + l) * D_ + d;
    if (l > 0) acc = fmaf(x[base - D_], w0, acc);
    acc = fmaf(x[base], w1, acc);
    if (l + 1 < L_) acc = fmaf(x[base + D_], w2, acc);
    const float g = 0.5f * acc * (1.f + erff(acc * 0.70710678118654752f));
    out[idx] += g;
}

// ---------------- host launcher --------------------------------------------
extern "C" void kernel_launch(void* const* d_in, const int* in_sizes, int n_in,
                              void* d_out, int out_size, void* d_ws, size_t ws_size,
                              hipStream_t stream) {
    const float* inputs = (const float*)d_in[0];
    const float* f_in_w = (const float*)d_in[1];
    const float* f_in_b = (const float*)d_in[2];
    const float* f_xp_w = (const float*)d_in[3];
    const float* f_xp_b = (const float*)d_in[4];
    const float* f_dt_b = (const float*)d_in[5];
    const float* f_A = (const float*)d_in[6];
    const float* f_D = (const float*)d_in[7];
    const float* f_out_w = (const float*)d_in[8];
    const float* f_out_b = (const float*)d_in[9];
    const float* b_in_w = (const float*)d_in[10];
    const float* b_in_b = (const float*)d_in[11];
    const float* b_xp_w = (const float*)d_in[12];
    const float* b_xp_b = (const float*)d_in[13];
    const float* b_dt_b = (const float*)d_in[14];
    const float* b_A = (const float*)d_in[15];
    const float* b_D = (const float*)d_in[16];
    const float* b_out_w = (const float*)d_in[17];
    const float* b_out_b = (const float*)d_in[18];
    const float* norm_w = (const float*)d_in[19];
    const float* norm_b = (const float*)d_in[20];
    const float* conv_w = (const float*)d_in[21];
    const float* conv_b = (const float*)d_in[22];
    float* out = (float*)d_out;

    // workspace layout (same total footprint as R3; xi_f32 slot -> scan states)
    float* ws = (float*)d_ws;
    float* st_prod = ws;                                  // NSEQ_*NC_ = 4,194,304 f
    float* st_hend = st_prod + (size_t)NSEQ_ * NC_;       // 4,194,304 f
    float* zbuf    = st_hend + (size_t)NSEQ_ * NC_;       // 8,388,608 f
    float* proj    = zbuf + (size_t)M_ * DI_;             // 12,582,912 f
    float* y1      = proj + (size_t)M_ * PROJ_;           // 4,194,304 f
    __hip_bfloat16* xi_bf = (__hip_bfloat16*)(y1 + (size_t)M_ * D_);   // 8,388,608 bf16
    __hip_bfloat16* yg_bf = xi_bf + (size_t)M_ * DI_;                  // 8,388,608 bf16
    __hip_bfloat16* a_bf  = yg_bf + (size_t)M_ * DI_;                  // 4,194,304 bf16
    __hip_bfloat16* wpool = a_bf + (size_t)M_ * D_;
    __hip_bfloat16* f_in_wb  = wpool;
    __hip_bfloat16* f_xp_wb  = f_in_wb + 2 * DI_ * D_;
    __hip_bfloat16* f_out_wb = f_xp_wb + PROJ_ * DI_;
    __hip_bfloat16* b_in_wb  = f_out_wb + D_ * DI_;
    __hip_bfloat16* b_xp_wb  = b_in_wb + 2 * DI_ * D_;
    __hip_bfloat16* b_out_wb = b_xp_wb + PROJ_ * DI_;

    const dim3 blk(256);
    const dim3 g_in(M_ / 128, (2 * DI_) / 128);   // (128,8)
    const dim3 g_xp(M_ / 128, PROJ_ / 128);       // (128,6)
    const dim3 g_out(M_ / 128, 2);                // (128,2)
    const dim3 g_chunk(B_ * H_, NC_ / 4);         // (32,32) = 1024 blocks, 4096 waves
    const dim3 g_comb(NSEQ_ / 256);               // 128 blocks

    // ---- fp32 -> bf16 conversions (weights + inputs) ----
    f2b<<<dim3(1024), blk, 0, stream>>>(inputs, a_bf, M_ * D_);
    f2b<<<dim3(256), blk, 0, stream>>>(f_in_w, f_in_wb, 2 * DI_ * D_);
    f2b<<<dim3(256), blk, 0, stream>>>(f_xp_w, f_xp_wb, PROJ_ * DI_);
    f2b<<<dim3(256), blk, 0, stream>>>(f_out_w, f_out_wb, D_ * DI_);
    f2b<<<dim3(256), blk, 0, stream>>>(b_in_w, b_in_wb, 2 * DI_ * D_);
    f2b<<<dim3(256), blk, 0, stream>>>(b_xp_w, b_xp_wb, PROJ_ * DI_);
    f2b<<<dim3(256), blk, 0, stream>>>(b_out_w, b_out_wb, D_ * DI_);

    // ---- forward pass ----
    gemm_mfma<1><<<g_in, blk, 0, stream>>>(a_bf, f_in_wb, f_in_b, D_,
                                           nullptr, zbuf, xi_bf, nullptr);
    gemm_mfma<2><<<g_xp, blk, 0, stream>>>(xi_bf, f_xp_wb, f_xp_b, DI_,
                                           proj, nullptr, nullptr, f_dt_b);
    scan_chunk_state<<<g_chunk, blk, 0, stream>>>(xi_bf, proj, f_A, st_prod, st_hend);
    scan_combine<<<g_comb, blk, 0, stream>>>(st_prod, st_hend);
    scan_chunk_out<<<g_chunk, blk, 0, stream>>>(xi_bf, zbuf, proj, f_A, f_D,
                                                st_prod, yg_bf);
    gemm_mfma<0><<<g_out, blk, 0, stream>>>(yg_bf, f_out_wb, f_out_b, DI_,
                                            y1, nullptr, nullptr, nullptr);
    ln_flip<<<dim3(M_), blk, 0, stream>>>(y1, norm_w, norm_b, a_bf);

    // ---- backward pass ----
    gemm_mfma<1><<<g_in, blk, 0, stream>>>(a_bf, b_in_wb, b_in_b, D_,
                                           nullptr, zbuf, xi_bf, nullptr);
    gemm_mfma<2><<<g_xp, blk, 0, stream>>>(xi_bf, b_xp_wb, b_xp_b, DI_,
                                           proj, nullptr, nullptr, b_dt_b);
    scan_chunk_state<<<g_chunk, blk, 0, stream>>>(xi_bf, proj, b_A, st_prod, st_hend);
    scan_combine<<<g_comb, blk, 0, stream>>>(st_prod, st_hend);
    scan_chunk_out<<<g_chunk, blk, 0, stream>>>(xi_bf, zbuf, proj, b_A, b_D,
                                                st_prod, yg_bf);
    gemm_mfma<3><<<g_out, blk, 0, stream>>>(yg_bf, b_out_wb, b_out_b, DI_,
                                            out, nullptr, nullptr, nullptr);

    // ---- locality branch ----
    conv_gelu_add<<<dim3(M_ * D_ / 256), blk, 0, stream>>>(inputs, conv_w, conv_b, out);
}

// Round 5
// 583.535 us; speedup vs baseline: 7.2816x; 1.0096x over previous
//
#include <hip/hip_runtime.h>
#include <hip/hip_bf16.h>
#include <cstdint>
#include <cstddef>

// ---------------- problem constants ----------------
#define B_  4
#define L_  4096
#define D_  256
#define DI_ 512
#define H_  8
#define P_  64
#define N_  16
#define M_  (B_ * L_)              // 16384 rows
#define PROJ_ (DI_ + 2 * H_ * N_)  // 768

// chunked scan parameters. Thread mapping: lane = (n-half 2) x (p 32),
// wave pair per chunk; each thread owns 8 of the 16 states for one channel.
#define NC_ 128                    // chunks along L
#define CL_ (L_ / NC_)             // 32
#define NSEQ_ (B_ * H_ * P_ * N_)  // 32768 scalar sequences
#define LOG2E_ 1.4426950408889634f

typedef __bf16 bf16x8 __attribute__((ext_vector_type(8)));
typedef float f32x4 __attribute__((ext_vector_type(4)));

__device__ __forceinline__ void cp16_lds(const __hip_bfloat16* g, short* lds) {
    __builtin_amdgcn_global_load_lds(
        (const __attribute__((address_space(1))) void*)g,
        (__attribute__((address_space(3))) void*)lds, 16, 0, 0);
}

// ---------------- fused fp32 -> bf16 conversion (7 segments) -----------------
#define FS0 (M_ * D_)          // inputs      4194304
#define FS1 (2 * DI_ * D_)     // in_proj_w    262144
#define FS2 (PROJ_ * DI_)      // x_proj_w     393216
#define FS3 (D_ * DI_)         // out_proj_w   131072
#define FC1 (FS0 + FS1)
#define FC2 (FC1 + FS2)
#define FC3 (FC2 + FS3)
#define FC4 (FC3 + FS1)
#define FC5 (FC4 + FS2)
#define FC6 (FC5 + FS3)

__launch_bounds__(256)
__global__ void f2b_all(const float* __restrict__ i0, const float* __restrict__ i1,
                        const float* __restrict__ i2, const float* __restrict__ i3,
                        const float* __restrict__ i4, const float* __restrict__ i5,
                        const float* __restrict__ i6,
                        __hip_bfloat16* o0, __hip_bfloat16* o1, __hip_bfloat16* o2,
                        __hip_bfloat16* o3, __hip_bfloat16* o4, __hip_bfloat16* o5,
                        __hip_bfloat16* o6) {
    for (int idx = blockIdx.x * 256 + threadIdx.x; idx < FC6; idx += gridDim.x * 256) {
        const float* s; __hip_bfloat16* d; int off;
        if (idx < FS0)      { s = i0; d = o0; off = idx; }
        else if (idx < FC1) { s = i1; d = o1; off = idx - FS0; }
        else if (idx < FC2) { s = i2; d = o2; off = idx - FC1; }
        else if (idx < FC3) { s = i3; d = o3; off = idx - FC2; }
        else if (idx < FC4) { s = i4; d = o4; off = idx - FC3; }
        else if (idx < FC5) { s = i5; d = o5; off = idx - FC4; }
        else                { s = i6; d = o6; off = idx - FC5; }
        d[off] = __float2bfloat16(s[off]);
    }
}

// ---------------- MFMA bf16 GEMM: C = A(M,K) * W(N,K)^T + bias --------------
// 128x128 tile, BK=32, 4 waves in 2x2, each wave 4x4 mfma_f32_16x16x32_bf16.
// EPI 0: fp32 store, ld=256 (y1)
// EPI 1: in_proj: col<DI -> silu -> obf bf16 (xi); else out1 fp32 (z)
// EPI 2: x_proj: col<DI -> softplus(v+aux); fp32 store ld=768
// EPI 3: fp32 store row-flipped along L, ld=256, fused depthwise-conv3+GELU add
template <int EPI>
__launch_bounds__(256)
__global__ void gemm_mfma(const __hip_bfloat16* __restrict__ A,
                          const __hip_bfloat16* __restrict__ W,
                          const float* __restrict__ bias, int Kv,
                          float* __restrict__ out0, float* __restrict__ out1,
                          __hip_bfloat16* __restrict__ obf,
                          const float* __restrict__ aux,
                          const float* __restrict__ cw,
                          const float* __restrict__ cb,
                          const float* __restrict__ cinp) {
    __shared__ short As[128 * 32];
    __shared__ short Bs[128 * 32];
    const int tid = threadIdx.x;
    const int lane = tid & 63;
    const int wave = tid >> 6;
    const int bm = blockIdx.x * 128;
    const int bn = blockIdx.y * 128;
    const int wm = (wave >> 1) * 64;
    const int wn = (wave & 1) * 64;

    f32x4 acc[4][4];
#pragma unroll
    for (int i = 0; i < 4; ++i)
#pragma unroll
        for (int j = 0; j < 4; ++j) acc[i][j] = (f32x4)0.f;

    const int srow = lane >> 2;
    const int sk = (lane & 3) * 8;
    const __hip_bfloat16* gA0 = A + (size_t)(bm + wave * 32 + srow) * Kv + sk;
    const __hip_bfloat16* gA1 = gA0 + (size_t)16 * Kv;
    const __hip_bfloat16* gB0 = W + (size_t)(bn + wave * 32 + srow) * Kv + sk;
    const __hip_bfloat16* gB1 = gB0 + (size_t)16 * Kv;
    short* lA0 = As + (wave * 32) * 32;
    short* lA1 = As + (wave * 32 + 16) * 32;
    short* lB0 = Bs + (wave * 32) * 32;
    short* lB1 = Bs + (wave * 32 + 16) * 32;

    const int fr = lane & 15;
    const int fk = (lane >> 4) * 8;

    for (int k0 = 0; k0 < Kv; k0 += 32) {
        cp16_lds(gA0 + k0, lA0);
        cp16_lds(gA1 + k0, lA1);
        cp16_lds(gB0 + k0, lB0);
        cp16_lds(gB1 + k0, lB1);
        __syncthreads();
        bf16x8 af[4], bv[4];
#pragma unroll
        for (int i = 0; i < 4; ++i)
            af[i] = *reinterpret_cast<const bf16x8*>(&As[(wm + i * 16 + fr) * 32 + fk]);
#pragma unroll
        for (int j = 0; j < 4; ++j)
            bv[j] = *reinterpret_cast<const bf16x8*>(&Bs[(wn + j * 16 + fr) * 32 + fk]);
#pragma unroll
        for (int i = 0; i < 4; ++i)
#pragma unroll
            for (int j = 0; j < 4; ++j)
                acc[i][j] = __builtin_amdgcn_mfma_f32_16x16x32_bf16(
                    af[i], bv[j], acc[i][j], 0, 0, 0);
        __syncthreads();
    }

    const int n16 = lane & 15;
    const int r4 = (lane >> 4) * 4;
#pragma unroll
    for (int i = 0; i < 4; ++i) {
#pragma unroll
        for (int j = 0; j < 4; ++j) {
            const int cg = bn + wn + j * 16 + n16;
            const float bb = bias[cg];
#pragma unroll
            for (int v = 0; v < 4; ++v) {
                const int r = bm + wm + i * 16 + r4 + v;
                float val = acc[i][j][v] + bb;
                if (EPI == 0) {
                    out0[(size_t)r * 256 + cg] = val;
                } else if (EPI == 1) {
                    if (cg < DI_) {
                        val = val / (1.f + __expf(-val));
                        obf[(size_t)r * DI_ + cg] = __float2bfloat16(val);
                    } else {
                        out1[(size_t)r * DI_ + cg - DI_] = val;
                    }
                } else if (EPI == 2) {
                    if (cg < DI_) {
                        float x = val + aux[cg];
                        val = (x > 20.f) ? x : log1pf(__expf(x));
                    }
                    out0[(size_t)r * PROJ_ + cg] = val;
                } else {
                    // flipped store + fused depthwise conv3 + exact GELU add
                    const int b = r >> 12;
                    const int l = r & (L_ - 1);
                    const int lo = L_ - 1 - l;
                    const size_t base = ((size_t)(b << 12) + lo) * 256 + cg;
                    float cv = fmaf(cinp[base], cw[cg * 3 + 1], cb[cg]);
                    if (lo > 0) cv = fmaf(cinp[base - 256], cw[cg * 3 + 0], cv);
                    if (lo + 1 < L_) cv = fmaf(cinp[base + 256], cw[cg * 3 + 2], cv);
                    const float g = 0.5f * cv * (1.f + erff(cv * 0.70710678118654752f));
                    out0[base] = val + g;
                }
            }
        }
    }
}

// ---------------- chunked selective scan, split-N mapping --------------------
// grid: (B_*H_, NC_/2), block 256 = 4 waves; wave pair (2 waves) per chunk.
// wave: bit0 = p-half; lane: bit5 = n-half, bits0-4 = p mod 32.

__launch_bounds__(256)
__global__ void scan_chunk_state(const __hip_bfloat16* __restrict__ xi,
                                 const float* __restrict__ proj,
                                 const float* __restrict__ A_log,
                                 float* __restrict__ st_prod,
                                 float* __restrict__ st_hend) {
    const int bh = blockIdx.x;
    const int b = bh >> 3;
    const int h = bh & 7;
    const int lane = threadIdx.x & 63;
    const int wave = threadIdx.x >> 6;
    const int chunk = blockIdx.y * 2 + (wave >> 1);
    const int p = (wave & 1) * 32 + (lane & 31);
    const int nh = lane >> 5;
    const int n0 = nh * 8;
    const int c = h * P_ + p;
    const int t0 = chunk * CL_;

    float A2[8], hs[8], pr[8];
#pragma unroll
    for (int n = 0; n < 8; ++n) {
        A2[n] = -__expf(A_log[c * N_ + n0 + n]) * LOG2E_;
        hs[n] = 0.f;
        pr[n] = 1.f;
    }

    const float* pP = proj + ((size_t)b * L_ + t0) * PROJ_;
    const __hip_bfloat16* px = xi + ((size_t)b * L_ + t0) * DI_ + c;
    const int bOff = DI_ + h * N_ + n0;

#pragma unroll 4
    for (int t = 0; t < CL_; ++t) {
        const float dt_v = pP[c];
        const float xv = __bfloat162float(px[0]);
        const float4 B0 = *reinterpret_cast<const float4*>(pP + bOff);
        const float4 B1 = *reinterpret_cast<const float4*>(pP + bOff + 4);
        const float Bv[8] = {B0.x, B0.y, B0.z, B0.w, B1.x, B1.y, B1.z, B1.w};
        const float dtx = dt_v * xv;
#pragma unroll
        for (int n = 0; n < 8; ++n) {
            const float dA = exp2f(dt_v * A2[n]);
            hs[n] = fmaf(hs[n], dA, dtx * Bv[n]);
            pr[n] *= dA;
        }
        pP += PROJ_; px += DI_;
    }

    const size_t s0 = (size_t)chunk * NSEQ_ + ((size_t)(bh * P_ + p)) * N_ + n0;
    *reinterpret_cast<float4*>(st_prod + s0) = make_float4(pr[0], pr[1], pr[2], pr[3]);
    *reinterpret_cast<float4*>(st_prod + s0 + 4) = make_float4(pr[4], pr[5], pr[6], pr[7]);
    *reinterpret_cast<float4*>(st_hend + s0) = make_float4(hs[0], hs[1], hs[2], hs[3]);
    *reinterpret_cast<float4*>(st_hend + s0 + 4) = make_float4(hs[4], hs[5], hs[6], hs[7]);
}

// Pass 2: sequential combine; writes incoming states IN PLACE over st_prod.
__launch_bounds__(256)
__global__ void scan_combine(float* __restrict__ st_prod,
                             const float* __restrict__ st_hend) {
    const int s = blockIdx.x * 256 + threadIdx.x;
    float H = 0.f;
#pragma unroll 8
    for (int k = 0; k < NC_; ++k) {
        const size_t o = (size_t)k * NSEQ_ + s;
        const float Pv = st_prod[o];
        const float Ev = st_hend[o];
        st_prod[o] = H;
        H = fmaf(Pv, H, Ev);
    }
}

__launch_bounds__(256)
__global__ void scan_chunk_out(const __hip_bfloat16* __restrict__ xi,
                               const float* __restrict__ z,
                               const float* __restrict__ proj,
                               const float* __restrict__ A_log,
                               const float* __restrict__ D_skip,
                               const float* __restrict__ st_hin,
                               __hip_bfloat16* __restrict__ yg) {
    const int bh = blockIdx.x;
    const int b = bh >> 3;
    const int h = bh & 7;
    const int lane = threadIdx.x & 63;
    const int wave = threadIdx.x >> 6;
    const int chunk = blockIdx.y * 2 + (wave >> 1);
    const int p = (wave & 1) * 32 + (lane & 31);
    const int nh = lane >> 5;
    const int n0 = nh * 8;
    const int c = h * P_ + p;
    const int t0 = chunk * CL_;

    float A2[8], hs[8];
    const size_t s0 = (size_t)chunk * NSEQ_ + ((size_t)(bh * P_ + p)) * N_ + n0;
    {
        const float4 h0 = *reinterpret_cast<const float4*>(st_hin + s0);
        const float4 h1 = *reinterpret_cast<const float4*>(st_hin + s0 + 4);
        hs[0] = h0.x; hs[1] = h0.y; hs[2] = h0.z; hs[3] = h0.w;
        hs[4] = h1.x; hs[5] = h1.y; hs[6] = h1.z; hs[7] = h1.w;
    }
#pragma unroll
    for (int n = 0; n < 8; ++n)
        A2[n] = -__expf(A_log[c * N_ + n0 + n]) * LOG2E_;
    const float Dv = D_skip[c];

    const float* pP = proj + ((size_t)b * L_ + t0) * PROJ_;
    const __hip_bfloat16* px = xi + ((size_t)b * L_ + t0) * DI_ + c;
    const float* pz = z + ((size_t)b * L_ + t0) * DI_ + c;
    __hip_bfloat16* py = yg + ((size_t)b * L_ + t0) * DI_ + c;
    const int bOff = DI_ + h * N_ + n0;
    const int cOff = DI_ + H_ * N_ + h * N_ + n0;

#pragma unroll 4
    for (int t = 0; t < CL_; ++t) {
        const float dt_v = pP[c];
        const float xv = __bfloat162float(px[0]);
        const float4 B0 = *reinterpret_cast<const float4*>(pP + bOff);
        const float4 B1 = *reinterpret_cast<const float4*>(pP + bOff + 4);
        const float4 C0 = *reinterpret_cast<const float4*>(pP + cOff);
        const float4 C1 = *reinterpret_cast<const float4*>(pP + cOff + 4);
        const float Bv[8] = {B0.x, B0.y, B0.z, B0.w, B1.x, B1.y, B1.z, B1.w};
        const float Cv[8] = {C0.x, C0.y, C0.z, C0.w, C1.x, C1.y, C1.z, C1.w};
        const float dtx = dt_v * xv;
        float part = 0.f;
#pragma unroll
        for (int n = 0; n < 8; ++n) {
            const float dA = exp2f(dt_v * A2[n]);
            hs[n] = fmaf(hs[n], dA, dtx * Bv[n]);
            part = fmaf(hs[n], Cv[n], part);
        }
        part += __shfl_xor(part, 32);          // combine the two n-halves
        if (nh == 0) {
            const float zv = pz[0];
            const float g = zv / (1.f + __expf(-zv));
            py[0] = __float2bfloat16((part + Dv * xv) * g);
        }
        pP += PROJ_; px += DI_; pz += DI_; py += DI_;
    }
}

// ---------------- layernorm + flip (bf16 out) --------------------------------
__launch_bounds__(256)
__global__ void ln_flip(const float* __restrict__ x, const float* __restrict__ w,
                        const float* __restrict__ bvec, __hip_bfloat16* __restrict__ y) {
    const int row = blockIdx.x;
    const int d = threadIdx.x;
    const float v = x[(size_t)row * D_ + d];
    float s = v, s2 = v * v;
#pragma unroll
    for (int m = 32; m; m >>= 1) {
        s += __shfl_xor(s, m);
        s2 += __shfl_xor(s2, m);
    }
    __shared__ float sh[8];
    const int wave = d >> 6;
    if ((d & 63) == 0) { sh[wave] = s; sh[4 + wave] = s2; }
    __syncthreads();
    const float ts = sh[0] + sh[1] + sh[2] + sh[3];
    const float ts2 = sh[4] + sh[5] + sh[6] + sh[7];
    const float mean = ts * (1.f / D_);
    const float var = ts2 * (1.f / D_) - mean * mean;
    const float inv = rsqrtf(var + 1e-5f);
    const int b = row >> 12;
    const int l = row & (L_ - 1);
    const int drow = (b << 12) + (L_ - 1 - l);
    y[(size_t)drow * D_ + d] = __float2bfloat16((v - mean) * inv * w[d] + bvec[d]);
}

// ---------------- host launcher --------------------------------------------
extern "C" void kernel_launch(void* const* d_in, const int* in_sizes, int n_in,
                              void* d_out, int out_size, void* d_ws, size_t ws_size,
                              hipStream_t stream) {
    const float* inputs = (const float*)d_in[0];
    const float* f_in_w = (const float*)d_in[1];
    const float* f_in_b = (const float*)d_in[2];
    const float* f_xp_w = (const float*)d_in[3];
    const float* f_xp_b = (const float*)d_in[4];
    const float* f_dt_b = (const float*)d_in[5];
    const float* f_A = (const float*)d_in[6];
    const float* f_D = (const float*)d_in[7];
    const float* f_out_w = (const float*)d_in[8];
    const float* f_out_b = (const float*)d_in[9];
    const float* b_in_w = (const float*)d_in[10];
    const float* b_in_b = (const float*)d_in[11];
    const float* b_xp_w = (const float*)d_in[12];
    const float* b_xp_b = (const float*)d_in[13];
    const float* b_dt_b = (const float*)d_in[14];
    const float* b_A = (const float*)d_in[15];
    const float* b_D = (const float*)d_in[16];
    const float* b_out_w = (const float*)d_in[17];
    const float* b_out_b = (const float*)d_in[18];
    const float* norm_w = (const float*)d_in[19];
    const float* norm_b = (const float*)d_in[20];
    const float* conv_w = (const float*)d_in[21];
    const float* conv_b = (const float*)d_in[22];
    float* out = (float*)d_out;

    // workspace layout (unchanged footprint from R4)
    float* ws = (float*)d_ws;
    float* st_prod = ws;                                  // 4,194,304 f
    float* st_hend = st_prod + (size_t)NSEQ_ * NC_;       // 4,194,304 f
    float* zbuf    = st_hend + (size_t)NSEQ_ * NC_;       // 8,388,608 f
    float* proj    = zbuf + (size_t)M_ * DI_;             // 12,582,912 f
    float* y1      = proj + (size_t)M_ * PROJ_;           // 4,194,304 f
    __hip_bfloat16* xi_bf = (__hip_bfloat16*)(y1 + (size_t)M_ * D_);   // 8,388,608 bf16
    __hip_bfloat16* yg_bf = xi_bf + (size_t)M_ * DI_;                  // 8,388,608 bf16
    __hip_bfloat16* a_bf  = yg_bf + (size_t)M_ * DI_;                  // 4,194,304 bf16
    __hip_bfloat16* wpool = a_bf + (size_t)M_ * D_;
    __hip_bfloat16* f_in_wb  = wpool;
    __hip_bfloat16* f_xp_wb  = f_in_wb + 2 * DI_ * D_;
    __hip_bfloat16* f_out_wb = f_xp_wb + PROJ_ * DI_;
    __hip_bfloat16* b_in_wb  = f_out_wb + D_ * DI_;
    __hip_bfloat16* b_xp_wb  = b_in_wb + 2 * DI_ * D_;
    __hip_bfloat16* b_out_wb = b_xp_wb + PROJ_ * DI_;

    const dim3 blk(256);
    const dim3 g_in(M_ / 128, (2 * DI_) / 128);   // (128,8)
    const dim3 g_xp(M_ / 128, PROJ_ / 128);       // (128,6)
    const dim3 g_out(M_ / 128, 2);                // (128,2)
    const dim3 g_chunk(B_ * H_, NC_ / 2);         // (32,64) = 2048 blocks, 8192 waves
    const dim3 g_comb(NSEQ_ / 256);               // 128 blocks

    // ---- fused fp32 -> bf16 conversions ----
    f2b_all<<<dim3(4096), blk, 0, stream>>>(inputs, f_in_w, f_xp_w, f_out_w,
                                            b_in_w, b_xp_w, b_out_w,
                                            a_bf, f_in_wb, f_xp_wb, f_out_wb,
                                            b_in_wb, b_xp_wb, b_out_wb);

    // ---- forward pass ----
    gemm_mfma<1><<<g_in, blk, 0, stream>>>(a_bf, f_in_wb, f_in_b, D_,
                                           nullptr, zbuf, xi_bf, nullptr,
                                           nullptr, nullptr, nullptr);
    gemm_mfma<2><<<g_xp, blk, 0, stream>>>(xi_bf, f_xp_wb, f_xp_b, DI_,
                                           proj, nullptr, nullptr, f_dt_b,
                                           nullptr, nullptr, nullptr);
    scan_chunk_state<<<g_chunk, blk, 0, stream>>>(xi_bf, proj, f_A, st_prod, st_hend);
    scan_combine<<<g_comb, blk, 0, stream>>>(st_prod, st_hend);
    scan_chunk_out<<<g_chunk, blk, 0, stream>>>(xi_bf, zbuf, proj, f_A, f_D,
                                                st_prod, yg_bf);
    gemm_mfma<0><<<g_out, blk, 0, stream>>>(yg_bf, f_out_wb, f_out_b, DI_,
                                            y1, nullptr, nullptr, nullptr,
                                            nullptr, nullptr, nullptr);
    ln_flip<<<dim3(M_), blk, 0, stream>>>(y1, norm_w, norm_b, a_bf);

    // ---- backward pass ----
    gemm_mfma<1><<<g_in, blk, 0, stream>>>(a_bf, b_in_wb, b_in_b, D_,
                                           nullptr, zbuf, xi_bf, nullptr,
                                           nullptr, nullptr, nullptr);
    gemm_mfma<2><<<g_xp, blk, 0, stream>>>(xi_bf, b_xp_wb, b_xp_b, DI_,
                                           proj, nullptr, nullptr, b_dt_b,
                                           nullptr, nullptr, nullptr);
    scan_chunk_state<<<g_chunk, blk, 0, stream>>>(xi_bf, proj, b_A, st_prod, st_hend);
    scan_combine<<<g_comb, blk, 0, stream>>>(st_prod, st_hend);
    scan_chunk_out<<<g_chunk, blk, 0, stream>>>(xi_bf, zbuf, proj, b_A, b_D,
                                                st_prod, yg_bf);
    // final out_proj with flipped store + fused conv3+GELU locality branch
    gemm_mfma<3><<<g_out, blk, 0, stream>>>(yg_bf, b_out_wb, b_out_b, DI_,
                                            out, nullptr, nullptr, nullptr,
                                            conv_w, conv_b, inputs);
}

// Round 6
// 515.088 us; speedup vs baseline: 8.2492x; 1.1329x over previous
//
#include <hip/hip_runtime.h>
#include <hip/hip_bf16.h>
#include <cstdint>
#include <cstddef>

// ---------------- problem constants ----------------
#define B_  4
#define L_  4096
#define D_  256
#define DI_ 512
#define H_  8
#define P_  64
#define N_  16
#define M_  (B_ * L_)              // 16384 rows
#define PROJ_ (DI_ + 2 * H_ * N_)  // 768

// chunked scan parameters (R4 mapping: 1 thread = 1 (b,h,p) channel, 16 states)
#define NC_ 128                    // chunks along L
#define CL_ (L_ / NC_)             // 32
#define NSEQ_ (B_ * H_ * P_ * N_)  // 32768 scalar sequences
#define LOG2E_ 1.4426950408889634f

typedef __bf16 bf16x8 __attribute__((ext_vector_type(8)));
typedef float f32x4 __attribute__((ext_vector_type(4)));

__device__ __forceinline__ void cp16_lds(const __hip_bfloat16* g, short* lds) {
    __builtin_amdgcn_global_load_lds(
        (const __attribute__((address_space(1))) void*)g,
        (__attribute__((address_space(3))) void*)lds, 16, 0, 0);
}

// ---------------- fused fp32 -> bf16 conversion (7 segments) -----------------
#define FS0 (M_ * D_)          // inputs      4194304
#define FS1 (2 * DI_ * D_)     // in_proj_w    262144
#define FS2 (PROJ_ * DI_)      // x_proj_w     393216
#define FS3 (D_ * DI_)         // out_proj_w   131072
#define FC1 (FS0 + FS1)
#define FC2 (FC1 + FS2)
#define FC3 (FC2 + FS3)
#define FC4 (FC3 + FS1)
#define FC5 (FC4 + FS2)
#define FC6 (FC5 + FS3)

__launch_bounds__(256)
__global__ void f2b_all(const float* __restrict__ i0, const float* __restrict__ i1,
                        const float* __restrict__ i2, const float* __restrict__ i3,
                        const float* __restrict__ i4, const float* __restrict__ i5,
                        const float* __restrict__ i6,
                        __hip_bfloat16* o0, __hip_bfloat16* o1, __hip_bfloat16* o2,
                        __hip_bfloat16* o3, __hip_bfloat16* o4, __hip_bfloat16* o5,
                        __hip_bfloat16* o6) {
    for (int idx = blockIdx.x * 256 + threadIdx.x; idx < FC6; idx += gridDim.x * 256) {
        const float* s; __hip_bfloat16* d; int off;
        if (idx < FS0)      { s = i0; d = o0; off = idx; }
        else if (idx < FC1) { s = i1; d = o1; off = idx - FS0; }
        else if (idx < FC2) { s = i2; d = o2; off = idx - FC1; }
        else if (idx < FC3) { s = i3; d = o3; off = idx - FC2; }
        else if (idx < FC4) { s = i4; d = o4; off = idx - FC3; }
        else if (idx < FC5) { s = i5; d = o5; off = idx - FC4; }
        else                { s = i6; d = o6; off = idx - FC5; }
        d[off] = __float2bfloat16(s[off]);
    }
}

// ---------------- MFMA bf16 GEMM: C = A(M,K) * W(N,K)^T + bias --------------
// EPI 0: fp32 store, ld=256 (y1)
// EPI 1: in_proj: col<DI -> silu -> obf bf16 (xi); else out1 fp32 (z)
// EPI 2: x_proj: col<DI -> softplus(v+aux); fp32 store ld=768
// EPI 3: fp32 store row-flipped along L, ld=256, fused depthwise-conv3+GELU add
template <int EPI>
__launch_bounds__(256)
__global__ void gemm_mfma(const __hip_bfloat16* __restrict__ A,
                          const __hip_bfloat16* __restrict__ W,
                          const float* __restrict__ bias, int Kv,
                          float* __restrict__ out0, float* __restrict__ out1,
                          __hip_bfloat16* __restrict__ obf,
                          const float* __restrict__ aux,
                          const float* __restrict__ cw,
                          const float* __restrict__ cb,
                          const float* __restrict__ cinp) {
    __shared__ short As[128 * 32];
    __shared__ short Bs[128 * 32];
    const int tid = threadIdx.x;
    const int lane = tid & 63;
    const int wave = tid >> 6;
    const int bm = blockIdx.x * 128;
    const int bn = blockIdx.y * 128;
    const int wm = (wave >> 1) * 64;
    const int wn = (wave & 1) * 64;

    f32x4 acc[4][4];
#pragma unroll
    for (int i = 0; i < 4; ++i)
#pragma unroll
        for (int j = 0; j < 4; ++j) acc[i][j] = (f32x4)0.f;

    const int srow = lane >> 2;
    const int sk = (lane & 3) * 8;
    const __hip_bfloat16* gA0 = A + (size_t)(bm + wave * 32 + srow) * Kv + sk;
    const __hip_bfloat16* gA1 = gA0 + (size_t)16 * Kv;
    const __hip_bfloat16* gB0 = W + (size_t)(bn + wave * 32 + srow) * Kv + sk;
    const __hip_bfloat16* gB1 = gB0 + (size_t)16 * Kv;
    short* lA0 = As + (wave * 32) * 32;
    short* lA1 = As + (wave * 32 + 16) * 32;
    short* lB0 = Bs + (wave * 32) * 32;
    short* lB1 = Bs + (wave * 32 + 16) * 32;

    const int fr = lane & 15;
    const int fk = (lane >> 4) * 8;

    for (int k0 = 0; k0 < Kv; k0 += 32) {
        cp16_lds(gA0 + k0, lA0);
        cp16_lds(gA1 + k0, lA1);
        cp16_lds(gB0 + k0, lB0);
        cp16_lds(gB1 + k0, lB1);
        __syncthreads();
        bf16x8 af[4], bv[4];
#pragma unroll
        for (int i = 0; i < 4; ++i)
            af[i] = *reinterpret_cast<const bf16x8*>(&As[(wm + i * 16 + fr) * 32 + fk]);
#pragma unroll
        for (int j = 0; j < 4; ++j)
            bv[j] = *reinterpret_cast<const bf16x8*>(&Bs[(wn + j * 16 + fr) * 32 + fk]);
#pragma unroll
        for (int i = 0; i < 4; ++i)
#pragma unroll
            for (int j = 0; j < 4; ++j)
                acc[i][j] = __builtin_amdgcn_mfma_f32_16x16x32_bf16(
                    af[i], bv[j], acc[i][j], 0, 0, 0);
        __syncthreads();
    }

    const int n16 = lane & 15;
    const int r4 = (lane >> 4) * 4;
#pragma unroll
    for (int i = 0; i < 4; ++i) {
#pragma unroll
        for (int j = 0; j < 4; ++j) {
            const int cg = bn + wn + j * 16 + n16;
            const float bb = bias[cg];
#pragma unroll
            for (int v = 0; v < 4; ++v) {
                const int r = bm + wm + i * 16 + r4 + v;
                float val = acc[i][j][v] + bb;
                if (EPI == 0) {
                    out0[(size_t)r * 256 + cg] = val;
                } else if (EPI == 1) {
                    if (cg < DI_) {
                        val = val / (1.f + __expf(-val));
                        obf[(size_t)r * DI_ + cg] = __float2bfloat16(val);
                    } else {
                        out1[(size_t)r * DI_ + cg - DI_] = val;
                    }
                } else if (EPI == 2) {
                    if (cg < DI_) {
                        float x = val + aux[cg];
                        val = (x > 20.f) ? x : log1pf(__expf(x));
                    }
                    out0[(size_t)r * PROJ_ + cg] = val;
                } else {
                    // flipped store + fused depthwise conv3 + exact GELU add
                    const int b = r >> 12;
                    const int l = r & (L_ - 1);
                    const int lo = L_ - 1 - l;
                    const size_t base = ((size_t)(b << 12) + lo) * 256 + cg;
                    float cv = fmaf(cinp[base], cw[cg * 3 + 1], cb[cg]);
                    if (lo > 0) cv = fmaf(cinp[base - 256], cw[cg * 3 + 0], cv);
                    if (lo + 1 < L_) cv = fmaf(cinp[base + 256], cw[cg * 3 + 2], cv);
                    const float g = 0.5f * cv * (1.f + erff(cv * 0.70710678118654752f));
                    out0[base] = val + g;
                }
            }
        }
    }
}

// ---------------- chunked selective scan, N in registers ---------------------
// grid: (B_*H_, NC_/4), block 256; wave w handles chunk blockIdx.y*4+w,
// lane = p. One thread owns h[16] for channel c = h*64+p.
// Fast path: A2[n] == (n+1)*A2[0] (checked at runtime) -> dA[n]=e1^(n+1),
// one exp2 per step instead of 16 (transcendentals are quarter-rate).

__device__ __forceinline__ bool a_is_arith(const float* A2) {
    bool ok = true;
#pragma unroll
    for (int n = 1; n < N_; ++n)
        ok = ok && (fabsf(A2[n] - (float)(n + 1) * A2[0]) <= 1e-4f * fabsf(A2[n]));
    return ok;
}

__launch_bounds__(256)
__global__ void scan_chunk_state(const __hip_bfloat16* __restrict__ xi,
                                 const float* __restrict__ proj,
                                 const float* __restrict__ A_log,
                                 float* __restrict__ st_prod,
                                 float* __restrict__ st_hend) {
    const int bh = blockIdx.x;
    const int b = bh >> 3;
    const int h = bh & 7;
    const int lane = threadIdx.x & 63;
    const int wave = threadIdx.x >> 6;
    const int chunk = blockIdx.y * 4 + wave;
    const int t0 = chunk * CL_;
    const int c = h * P_ + lane;

    float A2[N_], hs[N_];
#pragma unroll
    for (int n = 0; n < N_; ++n) {
        A2[n] = -__expf(A_log[c * N_ + n]) * LOG2E_;
        hs[n] = 0.f;
    }
    const bool fast = a_is_arith(A2);

    const float* pP = proj + ((size_t)b * L_ + t0) * PROJ_;
    const __hip_bfloat16* px = xi + ((size_t)b * L_ + t0) * DI_ + c;
    const int bOff = DI_ + h * N_;
    float S = 0.f;   // sum of dt; prod[n] = exp2(A2[n]*S) exactly

    if (fast) {
#pragma unroll 4
        for (int t = 0; t < CL_; ++t) {
            const float dt_v = pP[c];
            const float xv = __bfloat162float(px[0]);
            const float4 B0 = *reinterpret_cast<const float4*>(pP + bOff);
            const float4 B1 = *reinterpret_cast<const float4*>(pP + bOff + 4);
            const float4 B2 = *reinterpret_cast<const float4*>(pP + bOff + 8);
            const float4 B3 = *reinterpret_cast<const float4*>(pP + bOff + 12);
            const float Bv[N_] = {B0.x, B0.y, B0.z, B0.w, B1.x, B1.y, B1.z, B1.w,
                                  B2.x, B2.y, B2.z, B2.w, B3.x, B3.y, B3.z, B3.w};
            const float dtx = dt_v * xv;
            const float e1 = exp2f(dt_v * A2[0]);
            S += dt_v;
            float dA = e1;
#pragma unroll
            for (int n = 0; n < N_; ++n) {
                hs[n] = fmaf(hs[n], dA, dtx * Bv[n]);
                dA *= e1;
            }
            pP += PROJ_; px += DI_;
        }
    } else {
#pragma unroll 4
        for (int t = 0; t < CL_; ++t) {
            const float dt_v = pP[c];
            const float xv = __bfloat162float(px[0]);
            const float4 B0 = *reinterpret_cast<const float4*>(pP + bOff);
            const float4 B1 = *reinterpret_cast<const float4*>(pP + bOff + 4);
            const float4 B2 = *reinterpret_cast<const float4*>(pP + bOff + 8);
            const float4 B3 = *reinterpret_cast<const float4*>(pP + bOff + 12);
            const float Bv[N_] = {B0.x, B0.y, B0.z, B0.w, B1.x, B1.y, B1.z, B1.w,
                                  B2.x, B2.y, B2.z, B2.w, B3.x, B3.y, B3.z, B3.w};
            const float dtx = dt_v * xv;
            S += dt_v;
#pragma unroll
            for (int n = 0; n < N_; ++n) {
                const float dA = exp2f(dt_v * A2[n]);
                hs[n] = fmaf(hs[n], dA, dtx * Bv[n]);
            }
            pP += PROJ_; px += DI_;
        }
    }

    const size_t s0 = (size_t)chunk * NSEQ_ + ((size_t)(bh * P_ + lane)) * N_;
#pragma unroll
    for (int n = 0; n < N_; n += 4) {
        *reinterpret_cast<float4*>(st_prod + s0 + n) =
            make_float4(exp2f(A2[n] * S), exp2f(A2[n + 1] * S),
                        exp2f(A2[n + 2] * S), exp2f(A2[n + 3] * S));
        *reinterpret_cast<float4*>(st_hend + s0 + n) =
            make_float4(hs[n], hs[n + 1], hs[n + 2], hs[n + 3]);
    }
}

// Pass 2: sequential combine; writes incoming states IN PLACE over st_prod.
__launch_bounds__(256)
__global__ void scan_combine(float* __restrict__ st_prod,
                             const float* __restrict__ st_hend) {
    const int s = blockIdx.x * 256 + threadIdx.x;
    float H = 0.f;
#pragma unroll 8
    for (int k = 0; k < NC_; ++k) {
        const size_t o = (size_t)k * NSEQ_ + s;
        const float Pv = st_prod[o];
        const float Ev = st_hend[o];
        st_prod[o] = H;
        H = fmaf(Pv, H, Ev);
    }
}

__launch_bounds__(256)
__global__ void scan_chunk_out(const __hip_bfloat16* __restrict__ xi,
                               const float* __restrict__ z,
                               const float* __restrict__ proj,
                               const float* __restrict__ A_log,
                               const float* __restrict__ D_skip,
                               const float* __restrict__ st_hin,
                               __hip_bfloat16* __restrict__ yg) {
    const int bh = blockIdx.x;
    const int b = bh >> 3;
    const int h = bh & 7;
    const int lane = threadIdx.x & 63;
    const int wave = threadIdx.x >> 6;
    const int chunk = blockIdx.y * 4 + wave;
    const int t0 = chunk * CL_;
    const int c = h * P_ + lane;

    float A2[N_], hs[N_];
    const size_t s0 = (size_t)chunk * NSEQ_ + ((size_t)(bh * P_ + lane)) * N_;
#pragma unroll
    for (int n = 0; n < N_; n += 4) {
        const float4 h4 = *reinterpret_cast<const float4*>(st_hin + s0 + n);
        hs[n] = h4.x; hs[n + 1] = h4.y; hs[n + 2] = h4.z; hs[n + 3] = h4.w;
    }
#pragma unroll
    for (int n = 0; n < N_; ++n)
        A2[n] = -__expf(A_log[c * N_ + n]) * LOG2E_;
    const bool fast = a_is_arith(A2);
    const float Dv = D_skip[c];

    const float* pP = proj + ((size_t)b * L_ + t0) * PROJ_;
    const __hip_bfloat16* px = xi + ((size_t)b * L_ + t0) * DI_ + c;
    const float* pz = z + ((size_t)b * L_ + t0) * DI_ + c;
    __hip_bfloat16* py = yg + ((size_t)b * L_ + t0) * DI_ + c;
    const int bOff = DI_ + h * N_;
    const int cOff = DI_ + H_ * N_ + h * N_;

    if (fast) {
#pragma unroll 4
        for (int t = 0; t < CL_; ++t) {
            const float dt_v = pP[c];
            const float xv = __bfloat162float(px[0]);
            const float zv = pz[0];
            const float4 B0 = *reinterpret_cast<const float4*>(pP + bOff);
            const float4 B1 = *reinterpret_cast<const float4*>(pP + bOff + 4);
            const float4 B2 = *reinterpret_cast<const float4*>(pP + bOff + 8);
            const float4 B3 = *reinterpret_cast<const float4*>(pP + bOff + 12);
            const float4 C0 = *reinterpret_cast<const float4*>(pP + cOff);
            const float4 C1 = *reinterpret_cast<const float4*>(pP + cOff + 4);
            const float4 C2 = *reinterpret_cast<const float4*>(pP + cOff + 8);
            const float4 C3 = *reinterpret_cast<const float4*>(pP + cOff + 12);
            const float Bv[N_] = {B0.x, B0.y, B0.z, B0.w, B1.x, B1.y, B1.z, B1.w,
                                  B2.x, B2.y, B2.z, B2.w, B3.x, B3.y, B3.z, B3.w};
            const float Cv[N_] = {C0.x, C0.y, C0.z, C0.w, C1.x, C1.y, C1.z, C1.w,
                                  C2.x, C2.y, C2.z, C2.w, C3.x, C3.y, C3.z, C3.w};
            const float dtx = dt_v * xv;
            const float e1 = exp2f(dt_v * A2[0]);
            float dA = e1;
            float y = 0.f;
#pragma unroll
            for (int n = 0; n < N_; ++n) {
                hs[n] = fmaf(hs[n], dA, dtx * Bv[n]);
                y = fmaf(hs[n], Cv[n], y);
                dA *= e1;
            }
            const float g = zv / (1.f + __expf(-zv));
            py[0] = __float2bfloat16((y + Dv * xv) * g);
            pP += PROJ_; px += DI_; pz += DI_; py += DI_;
        }
    } else {
#pragma unroll 4
        for (int t = 0; t < CL_; ++t) {
            const float dt_v = pP[c];
            const float xv = __bfloat162float(px[0]);
            const float zv = pz[0];
            const float4 B0 = *reinterpret_cast<const float4*>(pP + bOff);
            const float4 B1 = *reinterpret_cast<const float4*>(pP + bOff + 4);
            const float4 B2 = *reinterpret_cast<const float4*>(pP + bOff + 8);
            const float4 B3 = *reinterpret_cast<const float4*>(pP + bOff + 12);
            const float4 C0 = *reinterpret_cast<const float4*>(pP + cOff);
            const float4 C1 = *reinterpret_cast<const float4*>(pP + cOff + 4);
            const float4 C2 = *reinterpret_cast<const float4*>(pP + cOff + 8);
            const float4 C3 = *reinterpret_cast<const float4*>(pP + cOff + 12);
            const float Bv[N_] = {B0.x, B0.y, B0.z, B0.w, B1.x, B1.y, B1.z, B1.w,
                                  B2.x, B2.y, B2.z, B2.w, B3.x, B3.y, B3.z, B3.w};
            const float Cv[N_] = {C0.x, C0.y, C0.z, C0.w, C1.x, C1.y, C1.z, C1.w,
                                  C2.x, C2.y, C2.z, C2.w, C3.x, C3.y, C3.z, C3.w};
            const float dtx = dt_v * xv;
            float y = 0.f;
#pragma unroll
            for (int n = 0; n < N_; ++n) {
                const float dA = exp2f(dt_v * A2[n]);
                hs[n] = fmaf(hs[n], dA, dtx * Bv[n]);
                y = fmaf(hs[n], Cv[n], y);
            }
            const float g = zv / (1.f + __expf(-zv));
            py[0] = __float2bfloat16((y + Dv * xv) * g);
            pP += PROJ_; px += DI_; pz += DI_; py += DI_;
        }
    }
}

// ---------------- layernorm + flip (bf16 out) --------------------------------
__launch_bounds__(256)
__global__ void ln_flip(const float* __restrict__ x, const float* __restrict__ w,
                        const float* __restrict__ bvec, __hip_bfloat16* __restrict__ y) {
    const int row = blockIdx.x;
    const int d = threadIdx.x;
    const float v = x[(size_t)row * D_ + d];
    float s = v, s2 = v * v;
#pragma unroll
    for (int m = 32; m; m >>= 1) {
        s += __shfl_xor(s, m);
        s2 += __shfl_xor(s2, m);
    }
    __shared__ float sh[8];
    const int wave = d >> 6;
    if ((d & 63) == 0) { sh[wave] = s; sh[4 + wave] = s2; }
    __syncthreads();
    const float ts = sh[0] + sh[1] + sh[2] + sh[3];
    const float ts2 = sh[4] + sh[5] + sh[6] + sh[7];
    const float mean = ts * (1.f / D_);
    const float var = ts2 * (1.f / D_) - mean * mean;
    const float inv = rsqrtf(var + 1e-5f);
    const int b = row >> 12;
    const int l = row & (L_ - 1);
    const int drow = (b << 12) + (L_ - 1 - l);
    y[(size_t)drow * D_ + d] = __float2bfloat16((v - mean) * inv * w[d] + bvec[d]);
}

// ---------------- host launcher --------------------------------------------
extern "C" void kernel_launch(void* const* d_in, const int* in_sizes, int n_in,
                              void* d_out, int out_size, void* d_ws, size_t ws_size,
                              hipStream_t stream) {
    const float* inputs = (const float*)d_in[0];
    const float* f_in_w = (const float*)d_in[1];
    const float* f_in_b = (const float*)d_in[2];
    const float* f_xp_w = (const float*)d_in[3];
    const float* f_xp_b = (const float*)d_in[4];
    const float* f_dt_b = (const float*)d_in[5];
    const float* f_A = (const float*)d_in[6];
    const float* f_D = (const float*)d_in[7];
    const float* f_out_w = (const float*)d_in[8];
    const float* f_out_b = (const float*)d_in[9];
    const float* b_in_w = (const float*)d_in[10];
    const float* b_in_b = (const float*)d_in[11];
    const float* b_xp_w = (const float*)d_in[12];
    const float* b_xp_b = (const float*)d_in[13];
    const float* b_dt_b = (const float*)d_in[14];
    const float* b_A = (const float*)d_in[15];
    const float* b_D = (const float*)d_in[16];
    const float* b_out_w = (const float*)d_in[17];
    const float* b_out_b = (const float*)d_in[18];
    const float* norm_w = (const float*)d_in[19];
    const float* norm_b = (const float*)d_in[20];
    const float* conv_w = (const float*)d_in[21];
    const float* conv_b = (const float*)d_in[22];
    float* out = (float*)d_out;

    // workspace layout (unchanged footprint from R5)
    float* ws = (float*)d_ws;
    float* st_prod = ws;                                  // 4,194,304 f
    float* st_hend = st_prod + (size_t)NSEQ_ * NC_;       // 4,194,304 f
    float* zbuf    = st_hend + (size_t)NSEQ_ * NC_;       // 8,388,608 f
    float* proj    = zbuf + (size_t)M_ * DI_;             // 12,582,912 f
    float* y1      = proj + (size_t)M_ * PROJ_;           // 4,194,304 f
    __hip_bfloat16* xi_bf = (__hip_bfloat16*)(y1 + (size_t)M_ * D_);   // 8,388,608 bf16
    __hip_bfloat16* yg_bf = xi_bf + (size_t)M_ * DI_;                  // 8,388,608 bf16
    __hip_bfloat16* a_bf  = yg_bf + (size_t)M_ * DI_;                  // 4,194,304 bf16
    __hip_bfloat16* wpool = a_bf + (size_t)M_ * D_;
    __hip_bfloat16* f_in_wb  = wpool;
    __hip_bfloat16* f_xp_wb  = f_in_wb + 2 * DI_ * D_;
    __hip_bfloat16* f_out_wb = f_xp_wb + PROJ_ * DI_;
    __hip_bfloat16* b_in_wb  = f_out_wb + D_ * DI_;
    __hip_bfloat16* b_xp_wb  = b_in_wb + 2 * DI_ * D_;
    __hip_bfloat16* b_out_wb = b_xp_wb + PROJ_ * DI_;

    const dim3 blk(256);
    const dim3 g_in(M_ / 128, (2 * DI_) / 128);   // (128,8)
    const dim3 g_xp(M_ / 128, PROJ_ / 128);       // (128,6)
    const dim3 g_out(M_ / 128, 2);                // (128,2)
    const dim3 g_chunk(B_ * H_, NC_ / 4);         // (32,32) = 1024 blocks, 4096 waves
    const dim3 g_comb(NSEQ_ / 256);               // 128 blocks

    // ---- fused fp32 -> bf16 conversions ----
    f2b_all<<<dim3(4096), blk, 0, stream>>>(inputs, f_in_w, f_xp_w, f_out_w,
                                            b_in_w, b_xp_w, b_out_w,
                                            a_bf, f_in_wb, f_xp_wb, f_out_wb,
                                            b_in_wb, b_xp_wb, b_out_wb);

    // ---- forward pass ----
    gemm_mfma<1><<<g_in, blk, 0, stream>>>(a_bf, f_in_wb, f_in_b, D_,
                                           nullptr, zbuf, xi_bf, nullptr,
                                           nullptr, nullptr, nullptr);
    gemm_mfma<2><<<g_xp, blk, 0, stream>>>(xi_bf, f_xp_wb, f_xp_b, DI_,
                                           proj, nullptr, nullptr, f_dt_b,
                                           nullptr, nullptr, nullptr);
    scan_chunk_state<<<g_chunk, blk, 0, stream>>>(xi_bf, proj, f_A, st_prod, st_hend);
    scan_combine<<<g_comb, blk, 0, stream>>>(st_prod, st_hend);
    scan_chunk_out<<<g_chunk, blk, 0, stream>>>(xi_bf, zbuf, proj, f_A, f_D,
                                                st_prod, yg_bf);
    gemm_mfma<0><<<g_out, blk, 0, stream>>>(yg_bf, f_out_wb, f_out_b, DI_,
                                            y1, nullptr, nullptr, nullptr,
                                            nullptr, nullptr, nullptr);
    ln_flip<<<dim3(M_), blk, 0, stream>>>(y1, norm_w, norm_b, a_bf);

    // ---- backward pass ----
    gemm_mfma<1><<<g_in, blk, 0, stream>>>(a_bf, b_in_wb, b_in_b, D_,
                                           nullptr, zbuf, xi_bf, nullptr,
                                           nullptr, nullptr, nullptr);
    gemm_mfma<2><<<g_xp, blk, 0, stream>>>(xi_bf, b_xp_wb, b_xp_b, DI_,
                                           proj, nullptr, nullptr, b_dt_b,
                                           nullptr, nullptr, nullptr);
    scan_chunk_state<<<g_chunk, blk, 0, stream>>>(xi_bf, proj, b_A, st_prod, st_hend);
    scan_combine<<<g_comb, blk, 0, stream>>>(st_prod, st_hend);
    scan_chunk_out<<<g_chunk, blk, 0, stream>>>(xi_bf, zbuf, proj, b_A, b_D,
                                                st_prod, yg_bf);
    // final out_proj with flipped store + fused conv3+GELU locality branch
    gemm_mfma<3><<<g_out, blk, 0, stream>>>(yg_bf, b_out_wb, b_out_b, DI_,
                                            out, nullptr, nullptr, nullptr,
                                            conv_w, conv_b, inputs);
}

// Round 7
// 467.406 us; speedup vs baseline: 9.0908x; 1.1020x over previous
//
#include <hip/hip_runtime.h>
#include <hip/hip_bf16.h>
#include <cstdint>
#include <cstddef>

// ---------------- problem constants ----------------
#define B_  4
#define L_  4096
#define D_  256
#define DI_ 512
#define H_  8
#define P_  64
#define N_  16
#define M_  (B_ * L_)              // 16384 rows
#define PROJ_ (DI_ + 2 * H_ * N_)  // 768

// chunked scan parameters (1 thread = 1 (b,h,p) channel, 16 states)
#define NC_ 128                    // chunks along L
#define CL_ (L_ / NC_)             // 32
#define NSEQ_ (B_ * H_ * P_ * N_)  // 32768 scalar sequences
#define LOG2E_ 1.4426950408889634f

typedef __bf16 bf16x8 __attribute__((ext_vector_type(8)));
typedef float f32x4 __attribute__((ext_vector_type(4)));

__device__ __forceinline__ void cp16_lds(const __hip_bfloat16* g, short* lds) {
    __builtin_amdgcn_global_load_lds(
        (const __attribute__((address_space(1))) void*)g,
        (__attribute__((address_space(3))) void*)lds, 16, 0, 0);
}

// ---------------- fused fp32 -> bf16 conversion (7 segments) -----------------
#define FS0 (M_ * D_)          // inputs      4194304
#define FS1 (2 * DI_ * D_)     // in_proj_w    262144
#define FS2 (PROJ_ * DI_)      // x_proj_w     393216
#define FS3 (D_ * DI_)         // out_proj_w   131072
#define FC1 (FS0 + FS1)
#define FC2 (FC1 + FS2)
#define FC3 (FC2 + FS3)
#define FC4 (FC3 + FS1)
#define FC5 (FC4 + FS2)
#define FC6 (FC5 + FS3)

__launch_bounds__(256)
__global__ void f2b_all(const float* __restrict__ i0, const float* __restrict__ i1,
                        const float* __restrict__ i2, const float* __restrict__ i3,
                        const float* __restrict__ i4, const float* __restrict__ i5,
                        const float* __restrict__ i6,
                        __hip_bfloat16* o0, __hip_bfloat16* o1, __hip_bfloat16* o2,
                        __hip_bfloat16* o3, __hip_bfloat16* o4, __hip_bfloat16* o5,
                        __hip_bfloat16* o6) {
    for (int idx = blockIdx.x * 256 + threadIdx.x; idx < FC6; idx += gridDim.x * 256) {
        const float* s; __hip_bfloat16* d; int off;
        if (idx < FS0)      { s = i0; d = o0; off = idx; }
        else if (idx < FC1) { s = i1; d = o1; off = idx - FS0; }
        else if (idx < FC2) { s = i2; d = o2; off = idx - FC1; }
        else if (idx < FC3) { s = i3; d = o3; off = idx - FC2; }
        else if (idx < FC4) { s = i4; d = o4; off = idx - FC3; }
        else if (idx < FC5) { s = i5; d = o5; off = idx - FC4; }
        else                { s = i6; d = o6; off = idx - FC5; }
        d[off] = __float2bfloat16(s[off]);
    }
}

// ---------------- MFMA bf16 GEMM: C = A(M,K) * W(N,K)^T + bias --------------
// 128x128 tile, BK=64, XOR-swizzled LDS (slot kgrp = kgrp ^ (row&7)) so that
// ds_read_b128 fragment loads are bank-conflict-free (each bank hit exactly 2x
// per wave = free per m136). Swizzle applied via per-lane global k-offsets at
// staging (LDS dest of global_load_lds stays lane-ordered contiguous).
// EPI 0: fp32 store, ld=256 (y1)
// EPI 1: in_proj: col<DI -> silu -> obf bf16 (xi); else out1 fp32 (z)
// EPI 2: x_proj: col<DI -> softplus(v+aux); fp32 store ld=768
// EPI 3: fp32 store row-flipped along L, ld=256, fused depthwise-conv3+GELU add
template <int EPI>
__launch_bounds__(256)
__global__ void gemm_mfma(const __hip_bfloat16* __restrict__ A,
                          const __hip_bfloat16* __restrict__ W,
                          const float* __restrict__ bias, int Kv,
                          float* __restrict__ out0, float* __restrict__ out1,
                          __hip_bfloat16* __restrict__ obf,
                          const float* __restrict__ aux,
                          const float* __restrict__ cw,
                          const float* __restrict__ cb,
                          const float* __restrict__ cinp) {
    __shared__ short As[128 * 64];   // 16 KB
    __shared__ short Bs[128 * 64];   // 16 KB
    const int tid = threadIdx.x;
    const int lane = tid & 63;
    const int wave = tid >> 6;
    const int bm = blockIdx.x * 128;
    const int bn = blockIdx.y * 128;
    const int wm = (wave >> 1) * 64;
    const int wn = (wave & 1) * 64;

    f32x4 acc[4][4];
#pragma unroll
    for (int i = 0; i < 4; ++i)
#pragma unroll
        for (int j = 0; j < 4; ++j) acc[i][j] = (f32x4)0.f;

    // staging: one cp16 inst = 8 rows x 8 k-segs of 16B. lane -> row lane>>3,
    // seg lane&7; global k-offset swizzled: ksrc = (seg ^ (row&7)) * 8 shorts.
    const int srow = lane >> 3;                       // 0..7
    const int ssegx = ((lane & 7) ^ srow) * 8;        // swizzled k offset (shorts)
    const __hip_bfloat16* gA0 = A + (size_t)(bm + wave * 32 + srow) * Kv + ssegx;
    const __hip_bfloat16* gB0 = W + (size_t)(bn + wave * 32 + srow) * Kv + ssegx;
    short* lA0 = As + (wave * 32) * 64;
    short* lB0 = Bs + (wave * 32) * 64;

    const int fr = lane & 15;        // fragment row within 16
    const int kq = lane >> 4;        // k-quarter 0..3

    for (int k0 = 0; k0 < Kv; k0 += 64) {
#pragma unroll
        for (int rb = 0; rb < 4; ++rb) {
            cp16_lds(gA0 + (size_t)(rb * 8) * Kv + k0, lA0 + rb * 8 * 64);
            cp16_lds(gB0 + (size_t)(rb * 8) * Kv + k0, lB0 + rb * 8 * 64);
        }
        __syncthreads();
#pragma unroll
        for (int ks = 0; ks < 2; ++ks) {
            const int kgg = ks * 4 + kq;                       // 0..7
            const int kslot = (kgg ^ (fr & 7)) * 8;            // un-swizzle
            bf16x8 af[4], bv[4];
#pragma unroll
            for (int i = 0; i < 4; ++i)
                af[i] = *reinterpret_cast<const bf16x8*>(
                    &As[(wm + i * 16 + fr) * 64 + kslot]);
#pragma unroll
            for (int j = 0; j < 4; ++j)
                bv[j] = *reinterpret_cast<const bf16x8*>(
                    &Bs[(wn + j * 16 + fr) * 64 + kslot]);
#pragma unroll
            for (int i = 0; i < 4; ++i)
#pragma unroll
                for (int j = 0; j < 4; ++j)
                    acc[i][j] = __builtin_amdgcn_mfma_f32_16x16x32_bf16(
                        af[i], bv[j], acc[i][j], 0, 0, 0);
        }
        __syncthreads();
    }

    // epilogue: C/D layout col = lane&15, row = (lane>>4)*4 + v
    const int n16 = lane & 15;
    const int r4 = (lane >> 4) * 4;
#pragma unroll
    for (int i = 0; i < 4; ++i) {
#pragma unroll
        for (int j = 0; j < 4; ++j) {
            const int cg = bn + wn + j * 16 + n16;
            const float bb = bias[cg];
#pragma unroll
            for (int v = 0; v < 4; ++v) {
                const int r = bm + wm + i * 16 + r4 + v;
                float val = acc[i][j][v] + bb;
                if (EPI == 0) {
                    out0[(size_t)r * 256 + cg] = val;
                } else if (EPI == 1) {
                    if (cg < DI_) {
                        val = val / (1.f + __expf(-val));
                        obf[(size_t)r * DI_ + cg] = __float2bfloat16(val);
                    } else {
                        out1[(size_t)r * DI_ + cg - DI_] = val;
                    }
                } else if (EPI == 2) {
                    if (cg < DI_) {
                        const float x = val + aux[cg];
                        // cheap softplus: 2 HW transcendentals, no libcall
                        val = (x > 20.f) ? x : __logf(1.f + __expf(x));
                    }
                    out0[(size_t)r * PROJ_ + cg] = val;
                } else {
                    // flipped store + fused depthwise conv3 + exact GELU add
                    const int b = r >> 12;
                    const int l = r & (L_ - 1);
                    const int lo = L_ - 1 - l;
                    const size_t base = ((size_t)(b << 12) + lo) * 256 + cg;
                    float cv = fmaf(cinp[base], cw[cg * 3 + 1], cb[cg]);
                    if (lo > 0) cv = fmaf(cinp[base - 256], cw[cg * 3 + 0], cv);
                    if (lo + 1 < L_) cv = fmaf(cinp[base + 256], cw[cg * 3 + 2], cv);
                    const float g = 0.5f * cv * (1.f + erff(cv * 0.70710678118654752f));
                    out0[base] = val + g;
                }
            }
        }
    }
}

// ---------------- chunked selective scan, N in registers ---------------------
// grid: (B_*H_, NC_/4), block 256; wave w handles chunk blockIdx.y*4+w,
// lane = p. One thread owns h[16] for channel c = h*64+p.
// Fast path: A2[n] == (n+1)*A2[0] (checked at runtime) -> dA[n]=e1^(n+1),
// one exp2 per step instead of 16 (transcendentals are quarter-rate).

__device__ __forceinline__ bool a_is_arith(const float* A2) {
    bool ok = true;
#pragma unroll
    for (int n = 1; n < N_; ++n)
        ok = ok && (fabsf(A2[n] - (float)(n + 1) * A2[0]) <= 1e-4f * fabsf(A2[n]));
    return ok;
}

__launch_bounds__(256)
__global__ void scan_chunk_state(const __hip_bfloat16* __restrict__ xi,
                                 const float* __restrict__ proj,
                                 const float* __restrict__ A_log,
                                 float* __restrict__ st_prod,
                                 float* __restrict__ st_hend) {
    const int bh = blockIdx.x;
    const int b = bh >> 3;
    const int h = bh & 7;
    const int lane = threadIdx.x & 63;
    const int wave = threadIdx.x >> 6;
    const int chunk = blockIdx.y * 4 + wave;
    const int t0 = chunk * CL_;
    const int c = h * P_ + lane;

    float A2[N_], hs[N_];
#pragma unroll
    for (int n = 0; n < N_; ++n) {
        A2[n] = -__expf(A_log[c * N_ + n]) * LOG2E_;
        hs[n] = 0.f;
    }
    const bool fast = a_is_arith(A2);

    const float* pP = proj + ((size_t)b * L_ + t0) * PROJ_;
    const __hip_bfloat16* px = xi + ((size_t)b * L_ + t0) * DI_ + c;
    const int bOff = DI_ + h * N_;
    float S = 0.f;   // sum of dt; prod[n] = exp2(A2[n]*S) exactly

    if (fast) {
#pragma unroll 4
        for (int t = 0; t < CL_; ++t) {
            const float dt_v = pP[c];
            const float xv = __bfloat162float(px[0]);
            const float4 B0 = *reinterpret_cast<const float4*>(pP + bOff);
            const float4 B1 = *reinterpret_cast<const float4*>(pP + bOff + 4);
            const float4 B2 = *reinterpret_cast<const float4*>(pP + bOff + 8);
            const float4 B3 = *reinterpret_cast<const float4*>(pP + bOff + 12);
            const float Bv[N_] = {B0.x, B0.y, B0.z, B0.w, B1.x, B1.y, B1.z, B1.w,
                                  B2.x, B2.y, B2.z, B2.w, B3.x, B3.y, B3.z, B3.w};
            const float dtx = dt_v * xv;
            const float e1 = exp2f(dt_v * A2[0]);
            S += dt_v;
            float dA = e1;
#pragma unroll
            for (int n = 0; n < N_; ++n) {
                hs[n] = fmaf(hs[n], dA, dtx * Bv[n]);
                dA *= e1;
            }
            pP += PROJ_; px += DI_;
        }
    } else {
#pragma unroll 4
        for (int t = 0; t < CL_; ++t) {
            const float dt_v = pP[c];
            const float xv = __bfloat162float(px[0]);
            const float4 B0 = *reinterpret_cast<const float4*>(pP + bOff);
            const float4 B1 = *reinterpret_cast<const float4*>(pP + bOff + 4);
            const float4 B2 = *reinterpret_cast<const float4*>(pP + bOff + 8);
            const float4 B3 = *reinterpret_cast<const float4*>(pP + bOff + 12);
            const float Bv[N_] = {B0.x, B0.y, B0.z, B0.w, B1.x, B1.y, B1.z, B1.w,
                                  B2.x, B2.y, B2.z, B2.w, B3.x, B3.y, B3.z, B3.w};
            const float dtx = dt_v * xv;
            S += dt_v;
#pragma unroll
            for (int n = 0; n < N_; ++n) {
                const float dA = exp2f(dt_v * A2[n]);
                hs[n] = fmaf(hs[n], dA, dtx * Bv[n]);
            }
            pP += PROJ_; px += DI_;
        }
    }

    const size_t s0 = (size_t)chunk * NSEQ_ + ((size_t)(bh * P_ + lane)) * N_;
#pragma unroll
    for (int n = 0; n < N_; n += 4) {
        *reinterpret_cast<float4*>(st_prod + s0 + n) =
            make_float4(exp2f(A2[n] * S), exp2f(A2[n + 1] * S),
                        exp2f(A2[n + 2] * S), exp2f(A2[n + 3] * S));
        *reinterpret_cast<float4*>(st_hend + s0 + n) =
            make_float4(hs[n], hs[n + 1], hs[n + 2], hs[n + 3]);
    }
}

// Pass 2: sequential combine; writes incoming states IN PLACE over st_prod.
__launch_bounds__(256)
__global__ void scan_combine(float* __restrict__ st_prod,
                             const float* __restrict__ st_hend) {
    const int s = blockIdx.x * 256 + threadIdx.x;
    float H = 0.f;
#pragma unroll 8
    for (int k = 0; k < NC_; ++k) {
        const size_t o = (size_t)k * NSEQ_ + s;
        const float Pv = st_prod[o];
        const float Ev = st_hend[o];
        st_prod[o] = H;
        H = fmaf(Pv, H, Ev);
    }
}

__launch_bounds__(256)
__global__ void scan_chunk_out(const __hip_bfloat16* __restrict__ xi,
                               const float* __restrict__ z,
                               const float* __restrict__ proj,
                               const float* __restrict__ A_log,
                               const float* __restrict__ D_skip,
                               const float* __restrict__ st_hin,
                               __hip_bfloat16* __restrict__ yg) {
    const int bh = blockIdx.x;
    const int b = bh >> 3;
    const int h = bh & 7;
    const int lane = threadIdx.x & 63;
    const int wave = threadIdx.x >> 6;
    const int chunk = blockIdx.y * 4 + wave;
    const int t0 = chunk * CL_;
    const int c = h * P_ + lane;

    float A2[N_], hs[N_];
    const size_t s0 = (size_t)chunk * NSEQ_ + ((size_t)(bh * P_ + lane)) * N_;
#pragma unroll
    for (int n = 0; n < N_; n += 4) {
        const float4 h4 = *reinterpret_cast<const float4*>(st_hin + s0 + n);
        hs[n] = h4.x; hs[n + 1] = h4.y; hs[n + 2] = h4.z; hs[n + 3] = h4.w;
    }
#pragma unroll
    for (int n = 0; n < N_; ++n)
        A2[n] = -__expf(A_log[c * N_ + n]) * LOG2E_;
    const bool fast = a_is_arith(A2);
    const float Dv = D_skip[c];

    const float* pP = proj + ((size_t)b * L_ + t0) * PROJ_;
    const __hip_bfloat16* px = xi + ((size_t)b * L_ + t0) * DI_ + c;
    const float* pz = z + ((size_t)b * L_ + t0) * DI_ + c;
    __hip_bfloat16* py = yg + ((size_t)b * L_ + t0) * DI_ + c;
    const int bOff = DI_ + h * N_;
    const int cOff = DI_ + H_ * N_ + h * N_;

    if (fast) {
#pragma unroll 4
        for (int t = 0; t < CL_; ++t) {
            const float dt_v = pP[c];
            const float xv = __bfloat162float(px[0]);
            const float zv = pz[0];
            const float4 B0 = *reinterpret_cast<const float4*>(pP + bOff);
            const float4 B1 = *reinterpret_cast<const float4*>(pP + bOff + 4);
            const float4 B2 = *reinterpret_cast<const float4*>(pP + bOff + 8);
            const float4 B3 = *reinterpret_cast<const float4*>(pP + bOff + 12);
            const float4 C0 = *reinterpret_cast<const float4*>(pP + cOff);
            const float4 C1 = *reinterpret_cast<const float4*>(pP + cOff + 4);
            const float4 C2 = *reinterpret_cast<const float4*>(pP + cOff + 8);
            const float4 C3 = *reinterpret_cast<const float4*>(pP + cOff + 12);
            const float Bv[N_] = {B0.x, B0.y, B0.z, B0.w, B1.x, B1.y, B1.z, B1.w,
                                  B2.x, B2.y, B2.z, B2.w, B3.x, B3.y, B3.z, B3.w};
            const float Cv[N_] = {C0.x, C0.y, C0.z, C0.w, C1.x, C1.y, C1.z, C1.w,
                                  C2.x, C2.y, C2.z, C2.w, C3.x, C3.y, C3.z, C3.w};
            const float dtx = dt_v * xv;
            const float e1 = exp2f(dt_v * A2[0]);
            float dA = e1;
            float y = 0.f;
#pragma unroll
            for (int n = 0; n < N_; ++n) {
                hs[n] = fmaf(hs[n], dA, dtx * Bv[n]);
                y = fmaf(hs[n], Cv[n], y);
                dA *= e1;
            }
            const float g = zv / (1.f + __expf(-zv));
            py[0] = __float2bfloat16((y + Dv * xv) * g);
            pP += PROJ_; px += DI_; pz += DI_; py += DI_;
        }
    } else {
#pragma unroll 4
        for (int t = 0; t < CL_; ++t) {
            const float dt_v = pP[c];
            const float xv = __bfloat162float(px[0]);
            const float zv = pz[0];
            const float4 B0 = *reinterpret_cast<const float4*>(pP + bOff);
            const float4 B1 = *reinterpret_cast<const float4*>(pP + bOff + 4);
            const float4 B2 = *reinterpret_cast<const float4*>(pP + bOff + 8);
            const float4 B3 = *reinterpret_cast<const float4*>(pP + bOff + 12);
            const float4 C0 = *reinterpret_cast<const float4*>(pP + cOff);
            const float4 C1 = *reinterpret_cast<const float4*>(pP + cOff + 4);
            const float4 C2 = *reinterpret_cast<const float4*>(pP + cOff + 8);
            const float4 C3 = *reinterpret_cast<const float4*>(pP + cOff + 12);
            const float Bv[N_] = {B0.x, B0.y, B0.z, B0.w, B1.x, B1.y, B1.z, B1.w,
                                  B2.x, B2.y, B2.z, B2.w, B3.x, B3.y, B3.z, B3.w};
            const float Cv[N_] = {C0.x, C0.y, C0.z, C0.w, C1.x, C1.y, C1.z, C1.w,
                                  C2.x, C2.y, C2.z, C2.w, C3.x, C3.y, C3.z, C3.w};
            const float dtx = dt_v * xv;
            float y = 0.f;
#pragma unroll
            for (int n = 0; n < N_; ++n) {
                const float dA = exp2f(dt_v * A2[n]);
                hs[n] = fmaf(hs[n], dA, dtx * Bv[n]);
                y = fmaf(hs[n], Cv[n], y);
            }
            const float g = zv / (1.f + __expf(-zv));
            py[0] = __float2bfloat16((y + Dv * xv) * g);
            pP += PROJ_; px += DI_; pz += DI_; py += DI_;
        }
    }
}

// ---------------- layernorm + flip (bf16 out) --------------------------------
__launch_bounds__(256)
__global__ void ln_flip(const float* __restrict__ x, const float* __restrict__ w,
                        const float* __restrict__ bvec, __hip_bfloat16* __restrict__ y) {
    const int row = blockIdx.x;
    const int d = threadIdx.x;
    const float v = x[(size_t)row * D_ + d];
    float s = v, s2 = v * v;
#pragma unroll
    for (int m = 32; m; m >>= 1) {
        s += __shfl_xor(s, m);
        s2 += __shfl_xor(s2, m);
    }
    __shared__ float sh[8];
    const int wave = d >> 6;
    if ((d & 63) == 0) { sh[wave] = s; sh[4 + wave] = s2; }
    __syncthreads();
    const float ts = sh[0] + sh[1] + sh[2] + sh[3];
    const float ts2 = sh[4] + sh[5] + sh[6] + sh[7];
    const float mean = ts * (1.f / D_);
    const float var = ts2 * (1.f / D_) - mean * mean;
    const float inv = rsqrtf(var + 1e-5f);
    const int b = row >> 12;
    const int l = row & (L_ - 1);
    const int drow = (b << 12) + (L_ - 1 - l);
    y[(size_t)drow * D_ + d] = __float2bfloat16((v - mean) * inv * w[d] + bvec[d]);
}

// ---------------- host launcher --------------------------------------------
extern "C" void kernel_launch(void* const* d_in, const int* in_sizes, int n_in,
                              void* d_out, int out_size, void* d_ws, size_t ws_size,
                              hipStream_t stream) {
    const float* inputs = (const float*)d_in[0];
    const float* f_in_w = (const float*)d_in[1];
    const float* f_in_b = (const float*)d_in[2];
    const float* f_xp_w = (const float*)d_in[3];
    const float* f_xp_b = (const float*)d_in[4];
    const float* f_dt_b = (const float*)d_in[5];
    const float* f_A = (const float*)d_in[6];
    const float* f_D = (const float*)d_in[7];
    const float* f_out_w = (const float*)d_in[8];
    const float* f_out_b = (const float*)d_in[9];
    const float* b_in_w = (const float*)d_in[10];
    const float* b_in_b = (const float*)d_in[11];
    const float* b_xp_w = (const float*)d_in[12];
    const float* b_xp_b = (const float*)d_in[13];
    const float* b_dt_b = (const float*)d_in[14];
    const float* b_A = (const float*)d_in[15];
    const float* b_D = (const float*)d_in[16];
    const float* b_out_w = (const float*)d_in[17];
    const float* b_out_b = (const float*)d_in[18];
    const float* norm_w = (const float*)d_in[19];
    const float* norm_b = (const float*)d_in[20];
    const float* conv_w = (const float*)d_in[21];
    const float* conv_b = (const float*)d_in[22];
    float* out = (float*)d_out;

    // workspace layout (unchanged footprint from R6)
    float* ws = (float*)d_ws;
    float* st_prod = ws;                                  // 4,194,304 f
    float* st_hend = st_prod + (size_t)NSEQ_ * NC_;       // 4,194,304 f
    float* zbuf    = st_hend + (size_t)NSEQ_ * NC_;       // 8,388,608 f
    float* proj    = zbuf + (size_t)M_ * DI_;             // 12,582,912 f
    float* y1      = proj + (size_t)M_ * PROJ_;           // 4,194,304 f
    __hip_bfloat16* xi_bf = (__hip_bfloat16*)(y1 + (size_t)M_ * D_);   // 8,388,608 bf16
    __hip_bfloat16* yg_bf = xi_bf + (size_t)M_ * DI_;                  // 8,388,608 bf16
    __hip_bfloat16* a_bf  = yg_bf + (size_t)M_ * DI_;                  // 4,194,304 bf16
    __hip_bfloat16* wpool = a_bf + (size_t)M_ * D_;
    __hip_bfloat16* f_in_wb  = wpool;
    __hip_bfloat16* f_xp_wb  = f_in_wb + 2 * DI_ * D_;
    __hip_bfloat16* f_out_wb = f_xp_wb + PROJ_ * DI_;
    __hip_bfloat16* b_in_wb  = f_out_wb + D_ * DI_;
    __hip_bfloat16* b_xp_wb  = b_in_wb + 2 * DI_ * D_;
    __hip_bfloat16* b_out_wb = b_xp_wb + PROJ_ * DI_;

    const dim3 blk(256);
    const dim3 g_in(M_ / 128, (2 * DI_) / 128);   // (128,8)
    const dim3 g_xp(M_ / 128, PROJ_ / 128);       // (128,6)
    const dim3 g_out(M_ / 128, 2);                // (128,2)
    const dim3 g_chunk(B_ * H_, NC_ / 4);         // (32,32) = 1024 blocks, 4096 waves
    const dim3 g_comb(NSEQ_ / 256);               // 128 blocks

    // ---- fused fp32 -> bf16 conversions ----
    f2b_all<<<dim3(4096), blk, 0, stream>>>(inputs, f_in_w, f_xp_w, f_out_w,
                                            b_in_w, b_xp_w, b_out_w,
                                            a_bf, f_in_wb, f_xp_wb, f_out_wb,
                                            b_in_wb, b_xp_wb, b_out_wb);

    // ---- forward pass ----
    gemm_mfma<1><<<g_in, blk, 0, stream>>>(a_bf, f_in_wb, f_in_b, D_,
                                           nullptr, zbuf, xi_bf, nullptr,
                                           nullptr, nullptr, nullptr);
    gemm_mfma<2><<<g_xp, blk, 0, stream>>>(xi_bf, f_xp_wb, f_xp_b, DI_,
                                           proj, nullptr, nullptr, f_dt_b,
                                           nullptr, nullptr, nullptr);
    scan_chunk_state<<<g_chunk, blk, 0, stream>>>(xi_bf, proj, f_A, st_prod, st_hend);
    scan_combine<<<g_comb, blk, 0, stream>>>(st_prod, st_hend);
    scan_chunk_out<<<g_chunk, blk, 0, stream>>>(xi_bf, zbuf, proj, f_A, f_D,
                                                st_prod, yg_bf);
    gemm_mfma<0><<<g_out, blk, 0, stream>>>(yg_bf, f_out_wb, f_out_b, DI_,
                                            y1, nullptr, nullptr, nullptr,
                                            nullptr, nullptr, nullptr);
    ln_flip<<<dim3(M_), blk, 0, stream>>>(y1, norm_w, norm_b, a_bf);

    // ---- backward pass ----
    gemm_mfma<1><<<g_in, blk, 0, stream>>>(a_bf, b_in_wb, b_in_b, D_,
                                           nullptr, zbuf, xi_bf, nullptr,
                                           nullptr, nullptr, nullptr);
    gemm_mfma<2><<<g_xp, blk, 0, stream>>>(xi_bf, b_xp_wb, b_xp_b, DI_,
                                           proj, nullptr, nullptr, b_dt_b,
                                           nullptr, nullptr, nullptr);
    scan_chunk_state<<<g_chunk, blk, 0, stream>>>(xi_bf, proj, b_A, st_prod, st_hend);
    scan_combine<<<g_comb, blk, 0, stream>>>(st_prod, st_hend);
    scan_chunk_out<<<g_chunk, blk, 0, stream>>>(xi_bf, zbuf, proj, b_A, b_D,
                                                st_prod, yg_bf);
    // final out_proj with flipped store + fused conv3+GELU locality branch
    gemm_mfma<3><<<g_out, blk, 0, stream>>>(yg_bf, b_out_wb, b_out_b, DI_,
                                            out, nullptr, nullptr, nullptr,
                                            conv_w, conv_b, inputs);
}

// Round 8
// 427.473 us; speedup vs baseline: 9.9400x; 1.0934x over previous
//
#include <hip/hip_runtime.h>
#include <hip/hip_bf16.h>
#include <cstdint>
#include <cstddef>

// ---------------- problem constants ----------------
#define B_  4
#define L_  4096
#define D_  256
#define DI_ 512
#define H_  8
#define P_  64
#define N_  16
#define M_  (B_ * L_)              // 16384 rows
#define PROJ_ (DI_ + 2 * H_ * N_)  // 768

// chunked scan parameters (1 thread = 1 (b,h,p) channel, 16 states)
#define NC_ 128                    // chunks along L
#define CL_ (L_ / NC_)             // 32
#define NSEQ_ (B_ * H_ * P_ * N_)  // 32768 scalar sequences
#define LOG2E_ 1.4426950408889634f

typedef __bf16 bf16x8 __attribute__((ext_vector_type(8)));
typedef float f32x4 __attribute__((ext_vector_type(4)));

__device__ __forceinline__ void cp16_lds(const __hip_bfloat16* g, short* lds) {
    __builtin_amdgcn_global_load_lds(
        (const __attribute__((address_space(1))) void*)g,
        (__attribute__((address_space(3))) void*)lds, 16, 0, 0);
}
__device__ __forceinline__ void cp16f_lds(const float* g, float* lds) {
    __builtin_amdgcn_global_load_lds(
        (const __attribute__((address_space(1))) void*)g,
        (__attribute__((address_space(3))) void*)lds, 16, 0, 0);
}

// ---------------- fused fp32 -> bf16 conversion (7 segments) -----------------
#define FS0 (M_ * D_)          // inputs      4194304
#define FS1 (2 * DI_ * D_)     // in_proj_w    262144
#define FS2 (PROJ_ * DI_)      // x_proj_w     393216
#define FS3 (D_ * DI_)         // out_proj_w   131072
#define FC1 (FS0 + FS1)
#define FC2 (FC1 + FS2)
#define FC3 (FC2 + FS3)
#define FC4 (FC3 + FS1)
#define FC5 (FC4 + FS2)
#define FC6 (FC5 + FS3)

__launch_bounds__(256)
__global__ void f2b_all(const float* __restrict__ i0, const float* __restrict__ i1,
                        const float* __restrict__ i2, const float* __restrict__ i3,
                        const float* __restrict__ i4, const float* __restrict__ i5,
                        const float* __restrict__ i6,
                        __hip_bfloat16* o0, __hip_bfloat16* o1, __hip_bfloat16* o2,
                        __hip_bfloat16* o3, __hip_bfloat16* o4, __hip_bfloat16* o5,
                        __hip_bfloat16* o6) {
    for (int idx = blockIdx.x * 256 + threadIdx.x; idx < FC6; idx += gridDim.x * 256) {
        const float* s; __hip_bfloat16* d; int off;
        if (idx < FS0)      { s = i0; d = o0; off = idx; }
        else if (idx < FC1) { s = i1; d = o1; off = idx - FS0; }
        else if (idx < FC2) { s = i2; d = o2; off = idx - FC1; }
        else if (idx < FC3) { s = i3; d = o3; off = idx - FC2; }
        else if (idx < FC4) { s = i4; d = o4; off = idx - FC3; }
        else if (idx < FC5) { s = i5; d = o5; off = idx - FC4; }
        else                { s = i6; d = o6; off = idx - FC5; }
        d[off] = __float2bfloat16(s[off]);
    }
}

// ---------------- MFMA bf16 GEMM: C = A(M,K) * W(N,K)^T + bias --------------
// 128x128 tile, BK=64, XOR-swizzled LDS -> conflict-free ds_read_b128.
template <int EPI>
__launch_bounds__(256)
__global__ void gemm_mfma(const __hip_bfloat16* __restrict__ A,
                          const __hip_bfloat16* __restrict__ W,
                          const float* __restrict__ bias, int Kv,
                          float* __restrict__ out0, float* __restrict__ out1,
                          __hip_bfloat16* __restrict__ obf,
                          const float* __restrict__ aux,
                          const float* __restrict__ cw,
                          const float* __restrict__ cb,
                          const float* __restrict__ cinp) {
    __shared__ short As[128 * 64];   // 16 KB
    __shared__ short Bs[128 * 64];   // 16 KB
    const int tid = threadIdx.x;
    const int lane = tid & 63;
    const int wave = tid >> 6;
    const int bm = blockIdx.x * 128;
    const int bn = blockIdx.y * 128;
    const int wm = (wave >> 1) * 64;
    const int wn = (wave & 1) * 64;

    f32x4 acc[4][4];
#pragma unroll
    for (int i = 0; i < 4; ++i)
#pragma unroll
        for (int j = 0; j < 4; ++j) acc[i][j] = (f32x4)0.f;

    const int srow = lane >> 3;                       // 0..7
    const int ssegx = ((lane & 7) ^ srow) * 8;        // swizzled k offset (shorts)
    const __hip_bfloat16* gA0 = A + (size_t)(bm + wave * 32 + srow) * Kv + ssegx;
    const __hip_bfloat16* gB0 = W + (size_t)(bn + wave * 32 + srow) * Kv + ssegx;
    short* lA0 = As + (wave * 32) * 64;
    short* lB0 = Bs + (wave * 32) * 64;

    const int fr = lane & 15;        // fragment row within 16
    const int kq = lane >> 4;        // k-quarter 0..3

    for (int k0 = 0; k0 < Kv; k0 += 64) {
#pragma unroll
        for (int rb = 0; rb < 4; ++rb) {
            cp16_lds(gA0 + (size_t)(rb * 8) * Kv + k0, lA0 + rb * 8 * 64);
            cp16_lds(gB0 + (size_t)(rb * 8) * Kv + k0, lB0 + rb * 8 * 64);
        }
        __syncthreads();
#pragma unroll
        for (int ks = 0; ks < 2; ++ks) {
            const int kgg = ks * 4 + kq;                       // 0..7
            const int kslot = (kgg ^ (fr & 7)) * 8;            // un-swizzle
            bf16x8 af[4], bv[4];
#pragma unroll
            for (int i = 0; i < 4; ++i)
                af[i] = *reinterpret_cast<const bf16x8*>(
                    &As[(wm + i * 16 + fr) * 64 + kslot]);
#pragma unroll
            for (int j = 0; j < 4; ++j)
                bv[j] = *reinterpret_cast<const bf16x8*>(
                    &Bs[(wn + j * 16 + fr) * 64 + kslot]);
#pragma unroll
            for (int i = 0; i < 4; ++i)
#pragma unroll
                for (int j = 0; j < 4; ++j)
                    acc[i][j] = __builtin_amdgcn_mfma_f32_16x16x32_bf16(
                        af[i], bv[j], acc[i][j], 0, 0, 0);
        }
        __syncthreads();
    }

    const int n16 = lane & 15;
    const int r4 = (lane >> 4) * 4;
#pragma unroll
    for (int i = 0; i < 4; ++i) {
#pragma unroll
        for (int j = 0; j < 4; ++j) {
            const int cg = bn + wn + j * 16 + n16;
            const float bb = bias[cg];
#pragma unroll
            for (int v = 0; v < 4; ++v) {
                const int r = bm + wm + i * 16 + r4 + v;
                float val = acc[i][j][v] + bb;
                if (EPI == 0) {
                    out0[(size_t)r * 256 + cg] = val;
                } else if (EPI == 1) {
                    if (cg < DI_) {
                        val = val / (1.f + __expf(-val));
                        obf[(size_t)r * DI_ + cg] = __float2bfloat16(val);
                    } else {
                        out1[(size_t)r * DI_ + cg - DI_] = val;
                    }
                } else if (EPI == 2) {
                    if (cg < DI_) {
                        const float x = val + aux[cg];
                        val = (x > 20.f) ? x : __logf(1.f + __expf(x));
                    }
                    out0[(size_t)r * PROJ_ + cg] = val;
                } else {
                    const int b = r >> 12;
                    const int l = r & (L_ - 1);
                    const int lo = L_ - 1 - l;
                    const size_t base = ((size_t)(b << 12) + lo) * 256 + cg;
                    float cv = fmaf(cinp[base], cw[cg * 3 + 1], cb[cg]);
                    if (lo > 0) cv = fmaf(cinp[base - 256], cw[cg * 3 + 0], cv);
                    if (lo + 1 < L_) cv = fmaf(cinp[base + 256], cw[cg * 3 + 2], cv);
                    const float g = 0.5f * cv * (1.f + erff(cv * 0.70710678118654752f));
                    out0[base] = val + g;
                }
            }
        }
    }
}

// ---------------- chunked selective scan, software-pipelined -----------------
// grid: (B_*H_, NC_/4), block 256; wave w owns chunk blockIdx.y*4+w, lane = p.
// One thread owns h[16] for channel c = h*64+p.
// B (and C) staged per-chunk into LDS via global_load_lds (wave-uniform data);
// dt/x/z register-double-buffered in batches of 4 so next batch's global loads
// overlap current batch's compute (fixes the 34%-VALUBusy load-compute serial
// schedule seen in R7 rocprof).

__device__ __forceinline__ bool a_is_arith(const float* A2) {
    bool ok = true;
#pragma unroll
    for (int n = 1; n < N_; ++n)
        ok = ok && (fabsf(A2[n] - (float)(n + 1) * A2[0]) <= 1e-4f * fabsf(A2[n]));
    return ok;
}

__launch_bounds__(256)
__global__ void scan_chunk_state(const __hip_bfloat16* __restrict__ xi,
                                 const float* __restrict__ proj,
                                 const float* __restrict__ A_log,
                                 float* __restrict__ st_prod,
                                 float* __restrict__ st_hend) {
    __shared__ float bsh[4][CL_][16];   // 8 KB: per-wave B cache
    const int bh = blockIdx.x;
    const int b = bh >> 3;
    const int h = bh & 7;
    const int lane = threadIdx.x & 63;
    const int wave = threadIdx.x >> 6;
    const int chunk = blockIdx.y * 4 + wave;
    const int t0 = chunk * CL_;
    const int c = h * P_ + lane;
    const int bOff = DI_ + h * N_;

    // ---- stage B for whole chunk into LDS (2 cp16 per wave) ----
    {
        const int stp = lane >> 2;           // 16 steps per inst
        const int off4 = (lane & 3) * 4;
        const float* base = proj + ((size_t)b * L_ + t0) * PROJ_ + bOff + off4;
#pragma unroll
        for (int r = 0; r < 2; ++r)
            cp16f_lds(base + (size_t)(r * 16 + stp) * PROJ_,
                      &bsh[wave][0][0] + r * 256);
    }

    float A2[N_], hs[N_];
#pragma unroll
    for (int n = 0; n < N_; ++n) {
        A2[n] = -__expf(A_log[c * N_ + n]) * LOG2E_;
        hs[n] = 0.f;
    }
    const bool fast = a_is_arith(A2);
    __syncthreads();   // drain global_load_lds before reading own LDS region

    const float* pDt = proj + ((size_t)b * L_ + t0) * PROJ_ + c;
    const __hip_bfloat16* px = xi + ((size_t)b * L_ + t0) * DI_ + c;
    float S = 0.f;

    if (fast) {
        float dtb[2][4], xb[2][4];
#pragma unroll
        for (int i = 0; i < 4; ++i) {
            dtb[0][i] = pDt[(size_t)i * PROJ_];
            xb[0][i] = __bfloat162float(px[(size_t)i * DI_]);
        }
#pragma unroll
        for (int k = 0; k < CL_ / 4; ++k) {
            const int cur = k & 1, nxt = cur ^ 1;
            if (k + 1 < CL_ / 4) {
#pragma unroll
                for (int i = 0; i < 4; ++i) {
                    dtb[nxt][i] = pDt[(size_t)((k + 1) * 4 + i) * PROJ_];
                    xb[nxt][i] = __bfloat162float(px[(size_t)((k + 1) * 4 + i) * DI_]);
                }
            }
#pragma unroll
            for (int i = 0; i < 4; ++i) {
                const int t = k * 4 + i;
                const float dt_v = dtb[cur][i];
                const float dtx = dt_v * xb[cur][i];
                const float e1 = exp2f(dt_v * A2[0]);
                S += dt_v;
                const f32x4* bp = reinterpret_cast<const f32x4*>(&bsh[wave][t][0]);
                float dA = e1;
#pragma unroll
                for (int q = 0; q < 4; ++q) {
                    const f32x4 Bq = bp[q];
#pragma unroll
                    for (int j = 0; j < 4; ++j) {
                        hs[q * 4 + j] = fmaf(hs[q * 4 + j], dA, dtx * Bq[j]);
                        dA *= e1;
                    }
                }
            }
        }
    } else {
#pragma unroll 4
        for (int t = 0; t < CL_; ++t) {
            const float dt_v = pDt[(size_t)t * PROJ_];
            const float xv = __bfloat162float(px[(size_t)t * DI_]);
            const float dtx = dt_v * xv;
            S += dt_v;
#pragma unroll
            for (int n = 0; n < N_; ++n) {
                const float dA = exp2f(dt_v * A2[n]);
                hs[n] = fmaf(hs[n], dA, dtx * bsh[wave][t][n]);
            }
        }
    }

    const size_t s0 = (size_t)chunk * NSEQ_ + ((size_t)(bh * P_ + lane)) * N_;
#pragma unroll
    for (int n = 0; n < N_; n += 4) {
        *reinterpret_cast<float4*>(st_prod + s0 + n) =
            make_float4(exp2f(A2[n] * S), exp2f(A2[n + 1] * S),
                        exp2f(A2[n + 2] * S), exp2f(A2[n + 3] * S));
        *reinterpret_cast<float4*>(st_hend + s0 + n) =
            make_float4(hs[n], hs[n + 1], hs[n + 2], hs[n + 3]);
    }
}

// Pass 2: sequential combine; writes incoming states IN PLACE over st_prod.
__launch_bounds__(256)
__global__ void scan_combine(float* __restrict__ st_prod,
                             const float* __restrict__ st_hend) {
    const int s = blockIdx.x * 256 + threadIdx.x;
    float H = 0.f;
#pragma unroll 8
    for (int k = 0; k < NC_; ++k) {
        const size_t o = (size_t)k * NSEQ_ + s;
        const float Pv = st_prod[o];
        const float Ev = st_hend[o];
        st_prod[o] = H;
        H = fmaf(Pv, H, Ev);
    }
}

__launch_bounds__(256)
__global__ void scan_chunk_out(const __hip_bfloat16* __restrict__ xi,
                               const float* __restrict__ z,
                               const float* __restrict__ proj,
                               const float* __restrict__ A_log,
                               const float* __restrict__ D_skip,
                               const float* __restrict__ st_hin,
                               __hip_bfloat16* __restrict__ yg) {
    __shared__ float bc[4][CL_][32];   // 16 KB: per-wave B|C cache
    const int bh = blockIdx.x;
    const int b = bh >> 3;
    const int h = bh & 7;
    const int lane = threadIdx.x & 63;
    const int wave = threadIdx.x >> 6;
    const int chunk = blockIdx.y * 4 + wave;
    const int t0 = chunk * CL_;
    const int c = h * P_ + lane;
    const int bOff = DI_ + h * N_;
    const int cOff = DI_ + H_ * N_ + h * N_;

    // ---- stage B and C for whole chunk into LDS (4 cp16 per wave) ----
    {
        const int seg = lane >> 2;           // 16 segments per inst
        const int off4 = (lane & 3) * 4;
        const float* rowb = proj + ((size_t)b * L_ + t0) * PROJ_;
#pragma unroll
        for (int r = 0; r < 4; ++r) {
            const int s = r * 16 + seg;      // 0..63
            const int stp = s >> 1;
            const int half = s & 1;
            cp16f_lds(rowb + (size_t)stp * PROJ_ + (half ? cOff : bOff) + off4,
                      &bc[wave][0][0] + r * 256);
        }
    }

    float A2[N_], hs[N_];
    const size_t s0 = (size_t)chunk * NSEQ_ + ((size_t)(bh * P_ + lane)) * N_;
#pragma unroll
    for (int n = 0; n < N_; n += 4) {
        const float4 h4 = *reinterpret_cast<const float4*>(st_hin + s0 + n);
        hs[n] = h4.x; hs[n + 1] = h4.y; hs[n + 2] = h4.z; hs[n + 3] = h4.w;
    }
#pragma unroll
    for (int n = 0; n < N_; ++n)
        A2[n] = -__expf(A_log[c * N_ + n]) * LOG2E_;
    const bool fast = a_is_arith(A2);
    const float Dv = D_skip[c];
    __syncthreads();   // drain global_load_lds before reading own LDS region

    const float* pDt = proj + ((size_t)b * L_ + t0) * PROJ_ + c;
    const __hip_bfloat16* px = xi + ((size_t)b * L_ + t0) * DI_ + c;
    const float* pz = z + ((size_t)b * L_ + t0) * DI_ + c;
    __hip_bfloat16* py = yg + ((size_t)b * L_ + t0) * DI_ + c;

    if (fast) {
        float dtb[2][4], xb[2][4], zb[2][4];
#pragma unroll
        for (int i = 0; i < 4; ++i) {
            dtb[0][i] = pDt[(size_t)i * PROJ_];
            xb[0][i] = __bfloat162float(px[(size_t)i * DI_]);
            zb[0][i] = pz[(size_t)i * DI_];
        }
#pragma unroll
        for (int k = 0; k < CL_ / 4; ++k) {
            const int cur = k & 1, nxt = cur ^ 1;
            if (k + 1 < CL_ / 4) {
#pragma unroll
                for (int i = 0; i < 4; ++i) {
                    const int t = (k + 1) * 4 + i;
                    dtb[nxt][i] = pDt[(size_t)t * PROJ_];
                    xb[nxt][i] = __bfloat162float(px[(size_t)t * DI_]);
                    zb[nxt][i] = pz[(size_t)t * DI_];
                }
            }
#pragma unroll
            for (int i = 0; i < 4; ++i) {
                const int t = k * 4 + i;
                const float dt_v = dtb[cur][i];
                const float xv = xb[cur][i];
                const float zv = zb[cur][i];
                const float dtx = dt_v * xv;
                const float e1 = exp2f(dt_v * A2[0]);
                const f32x4* bp = reinterpret_cast<const f32x4*>(&bc[wave][t][0]);
                float dA = e1;
                float y = 0.f;
#pragma unroll
                for (int q = 0; q < 4; ++q) {
                    const f32x4 Bq = bp[q];
                    const f32x4 Cq = bp[4 + q];
#pragma unroll
                    for (int j = 0; j < 4; ++j) {
                        hs[q * 4 + j] = fmaf(hs[q * 4 + j], dA, dtx * Bq[j]);
                        y = fmaf(hs[q * 4 + j], Cq[j], y);
                        dA *= e1;
                    }
                }
                const float g = zv / (1.f + __expf(-zv));
                py[(size_t)t * DI_] = __float2bfloat16((y + Dv * xv) * g);
            }
        }
    } else {
#pragma unroll 4
        for (int t = 0; t < CL_; ++t) {
            const float dt_v = pDt[(size_t)t * PROJ_];
            const float xv = __bfloat162float(px[(size_t)t * DI_]);
            const float zv = pz[(size_t)t * DI_];
            const float dtx = dt_v * xv;
            float y = 0.f;
#pragma unroll
            for (int n = 0; n < N_; ++n) {
                const float dA = exp2f(dt_v * A2[n]);
                hs[n] = fmaf(hs[n], dA, dtx * bc[wave][t][n]);
                y = fmaf(hs[n], bc[wave][t][16 + n], y);
            }
            const float g = zv / (1.f + __expf(-zv));
            py[(size_t)t * DI_] = __float2bfloat16((y + Dv * xv) * g);
        }
    }
}

// ---------------- layernorm + flip (bf16 out) --------------------------------
__launch_bounds__(256)
__global__ void ln_flip(const float* __restrict__ x, const float* __restrict__ w,
                        const float* __restrict__ bvec, __hip_bfloat16* __restrict__ y) {
    const int row = blockIdx.x;
    const int d = threadIdx.x;
    const float v = x[(size_t)row * D_ + d];
    float s = v, s2 = v * v;
#pragma unroll
    for (int m = 32; m; m >>= 1) {
        s += __shfl_xor(s, m);
        s2 += __shfl_xor(s2, m);
    }
    __shared__ float sh[8];
    const int wave = d >> 6;
    if ((d & 63) == 0) { sh[wave] = s; sh[4 + wave] = s2; }
    __syncthreads();
    const float ts = sh[0] + sh[1] + sh[2] + sh[3];
    const float ts2 = sh[4] + sh[5] + sh[6] + sh[7];
    const float mean = ts * (1.f / D_);
    const float var = ts2 * (1.f / D_) - mean * mean;
    const float inv = rsqrtf(var + 1e-5f);
    const int b = row >> 12;
    const int l = row & (L_ - 1);
    const int drow = (b << 12) + (L_ - 1 - l);
    y[(size_t)drow * D_ + d] = __float2bfloat16((v - mean) * inv * w[d] + bvec[d]);
}

// ---------------- host launcher --------------------------------------------
extern "C" void kernel_launch(void* const* d_in, const int* in_sizes, int n_in,
                              void* d_out, int out_size, void* d_ws, size_t ws_size,
                              hipStream_t stream) {
    const float* inputs = (const float*)d_in[0];
    const float* f_in_w = (const float*)d_in[1];
    const float* f_in_b = (const float*)d_in[2];
    const float* f_xp_w = (const float*)d_in[3];
    const float* f_xp_b = (const float*)d_in[4];
    const float* f_dt_b = (const float*)d_in[5];
    const float* f_A = (const float*)d_in[6];
    const float* f_D = (const float*)d_in[7];
    const float* f_out_w = (const float*)d_in[8];
    const float* f_out_b = (const float*)d_in[9];
    const float* b_in_w = (const float*)d_in[10];
    const float* b_in_b = (const float*)d_in[11];
    const float* b_xp_w = (const float*)d_in[12];
    const float* b_xp_b = (const float*)d_in[13];
    const float* b_dt_b = (const float*)d_in[14];
    const float* b_A = (const float*)d_in[15];
    const float* b_D = (const float*)d_in[16];
    const float* b_out_w = (const float*)d_in[17];
    const float* b_out_b = (const float*)d_in[18];
    const float* norm_w = (const float*)d_in[19];
    const float* norm_b = (const float*)d_in[20];
    const float* conv_w = (const float*)d_in[21];
    const float* conv_b = (const float*)d_in[22];
    float* out = (float*)d_out;

    // workspace layout (unchanged footprint from R7)
    float* ws = (float*)d_ws;
    float* st_prod = ws;                                  // 4,194,304 f
    float* st_hend = st_prod + (size_t)NSEQ_ * NC_;       // 4,194,304 f
    float* zbuf    = st_hend + (size_t)NSEQ_ * NC_;       // 8,388,608 f
    float* proj    = zbuf + (size_t)M_ * DI_;             // 12,582,912 f
    float* y1      = proj + (size_t)M_ * PROJ_;           // 4,194,304 f
    __hip_bfloat16* xi_bf = (__hip_bfloat16*)(y1 + (size_t)M_ * D_);   // 8,388,608 bf16
    __hip_bfloat16* yg_bf = xi_bf + (size_t)M_ * DI_;                  // 8,388,608 bf16
    __hip_bfloat16* a_bf  = yg_bf + (size_t)M_ * DI_;                  // 4,194,304 bf16
    __hip_bfloat16* wpool = a_bf + (size_t)M_ * D_;
    __hip_bfloat16* f_in_wb  = wpool;
    __hip_bfloat16* f_xp_wb  = f_in_wb + 2 * DI_ * D_;
    __hip_bfloat16* f_out_wb = f_xp_wb + PROJ_ * DI_;
    __hip_bfloat16* b_in_wb  = f_out_wb + D_ * DI_;
    __hip_bfloat16* b_xp_wb  = b_in_wb + 2 * DI_ * D_;
    __hip_bfloat16* b_out_wb = b_xp_wb + PROJ_ * DI_;

    const dim3 blk(256);
    const dim3 g_in(M_ / 128, (2 * DI_) / 128);   // (128,8)
    const dim3 g_xp(M_ / 128, PROJ_ / 128);       // (128,6)
    const dim3 g_out(M_ / 128, 2);                // (128,2)
    const dim3 g_chunk(B_ * H_, NC_ / 4);         // (32,32) = 1024 blocks, 4096 waves
    const dim3 g_comb(NSEQ_ / 256);               // 128 blocks

    // ---- fused fp32 -> bf16 conversions ----
    f2b_all<<<dim3(4096), blk, 0, stream>>>(inputs, f_in_w, f_xp_w, f_out_w,
                                            b_in_w, b_xp_w, b_out_w,
                                            a_bf, f_in_wb, f_xp_wb, f_out_wb,
                                            b_in_wb, b_xp_wb, b_out_wb);

    // ---- forward pass ----
    gemm_mfma<1><<<g_in, blk, 0, stream>>>(a_bf, f_in_wb, f_in_b, D_,
                                           nullptr, zbuf, xi_bf, nullptr,
                                           nullptr, nullptr, nullptr);
    gemm_mfma<2><<<g_xp, blk, 0, stream>>>(xi_bf, f_xp_wb, f_xp_b, DI_,
                                           proj, nullptr, nullptr, f_dt_b,
                                           nullptr, nullptr, nullptr);
    scan_chunk_state<<<g_chunk, blk, 0, stream>>>(xi_bf, proj, f_A, st_prod, st_hend);
    scan_combine<<<g_comb, blk, 0, stream>>>(st_prod, st_hend);
    scan_chunk_out<<<g_chunk, blk, 0, stream>>>(xi_bf, zbuf, proj, f_A, f_D,
                                                st_prod, yg_bf);
    gemm_mfma<0><<<g_out, blk, 0, stream>>>(yg_bf, f_out_wb, f_out_b, DI_,
                                            y1, nullptr, nullptr, nullptr,
                                            nullptr, nullptr, nullptr);
    ln_flip<<<dim3(M_), blk, 0, stream>>>(y1, norm_w, norm_b, a_bf);

    // ---- backward pass ----
    gemm_mfma<1><<<g_in, blk, 0, stream>>>(a_bf, b_in_wb, b_in_b, D_,
                                           nullptr, zbuf, xi_bf, nullptr,
                                           nullptr, nullptr, nullptr);
    gemm_mfma<2><<<g_xp, blk, 0, stream>>>(xi_bf, b_xp_wb, b_xp_b, DI_,
                                           proj, nullptr, nullptr, b_dt_b,
                                           nullptr, nullptr, nullptr);
    scan_chunk_state<<<g_chunk, blk, 0, stream>>>(xi_bf, proj, b_A, st_prod, st_hend);
    scan_combine<<<g_comb, blk, 0, stream>>>(st_prod, st_hend);
    scan_chunk_out<<<g_chunk, blk, 0, stream>>>(xi_bf, zbuf, proj, b_A, b_D,
                                                st_prod, yg_bf);
    // final out_proj with flipped store + fused conv3+GELU locality branch
    gemm_mfma<3><<<g_out, blk, 0, stream>>>(yg_bf, b_out_wb, b_out_b, DI_,
                                            out, nullptr, nullptr, nullptr,
                                            conv_w, conv_b, inputs);
}

// Round 9
// 399.865 us; speedup vs baseline: 10.6263x; 1.0690x over previous
//
#include <hip/hip_runtime.h>
#include <hip/hip_bf16.h>
#include <cstdint>
#include <cstddef>

// ---------------- problem constants ----------------
#define B_  4
#define L_  4096
#define D_  256
#define DI_ 512
#define H_  8
#define P_  64
#define N_  16
#define M_  (B_ * L_)              // 16384 rows
#define PROJ_ (DI_ + 2 * H_ * N_)  // 768

// chunked scan parameters (1 thread = 1 (b,h,p) channel, 16 states)
#define NC_ 128                    // chunks along L
#define CL_ (L_ / NC_)             // 32
#define NSEQ_ (B_ * H_ * P_ * N_)  // 32768 scalar sequences
#define LOG2E_ 1.4426950408889634f

typedef __bf16 bf16x8 __attribute__((ext_vector_type(8)));
typedef float f32x4 __attribute__((ext_vector_type(4)));

__device__ __forceinline__ void cp16_lds(const __hip_bfloat16* g, short* lds) {
    __builtin_amdgcn_global_load_lds(
        (const __attribute__((address_space(1))) void*)g,
        (__attribute__((address_space(3))) void*)lds, 16, 0, 0);
}
__device__ __forceinline__ void cp16f_lds(const float* g, float* lds) {
    __builtin_amdgcn_global_load_lds(
        (const __attribute__((address_space(1))) void*)g,
        (__attribute__((address_space(3))) void*)lds, 16, 0, 0);
}

// ---------------- fused fp32 -> bf16 conversion (7 segments) -----------------
#define FS0 (M_ * D_)          // inputs      4194304
#define FS1 (2 * DI_ * D_)     // in_proj_w    262144
#define FS2 (PROJ_ * DI_)      // x_proj_w     393216
#define FS3 (D_ * DI_)         // out_proj_w   131072
#define FC1 (FS0 + FS1)
#define FC2 (FC1 + FS2)
#define FC3 (FC2 + FS3)
#define FC4 (FC3 + FS1)
#define FC5 (FC4 + FS2)
#define FC6 (FC5 + FS3)

__launch_bounds__(256)
__global__ void f2b_all(const float* __restrict__ i0, const float* __restrict__ i1,
                        const float* __restrict__ i2, const float* __restrict__ i3,
                        const float* __restrict__ i4, const float* __restrict__ i5,
                        const float* __restrict__ i6,
                        __hip_bfloat16* o0, __hip_bfloat16* o1, __hip_bfloat16* o2,
                        __hip_bfloat16* o3, __hip_bfloat16* o4, __hip_bfloat16* o5,
                        __hip_bfloat16* o6) {
    for (int idx = blockIdx.x * 256 + threadIdx.x; idx < FC6; idx += gridDim.x * 256) {
        const float* s; __hip_bfloat16* d; int off;
        if (idx < FS0)      { s = i0; d = o0; off = idx; }
        else if (idx < FC1) { s = i1; d = o1; off = idx - FS0; }
        else if (idx < FC2) { s = i2; d = o2; off = idx - FC1; }
        else if (idx < FC3) { s = i3; d = o3; off = idx - FC2; }
        else if (idx < FC4) { s = i4; d = o4; off = idx - FC3; }
        else if (idx < FC5) { s = i5; d = o5; off = idx - FC4; }
        else                { s = i6; d = o6; off = idx - FC5; }
        d[off] = __float2bfloat16(s[off]);
    }
}

// ---------------- MFMA bf16 GEMM: C = A(M,K) * W(N,K)^T + bias --------------
// 128x128 tile, BK=64, XOR-swizzled LDS -> conflict-free ds_read_b128.
// EPI 1: in_proj: col<DI -> silu -> obf bf16 (xi); else z bf16 (zb)
// EPI 2: x_proj: col<DI -> softplus(v+aux); fp32 store ld=768
// EPI 3: fp32 store row-flipped along L, ld=256, fused depthwise-conv3+GELU add
template <int EPI>
__launch_bounds__(256)
__global__ void gemm_mfma(const __hip_bfloat16* __restrict__ A,
                          const __hip_bfloat16* __restrict__ W,
                          const float* __restrict__ bias, int Kv,
                          float* __restrict__ out0,
                          __hip_bfloat16* __restrict__ zb,
                          __hip_bfloat16* __restrict__ obf,
                          const float* __restrict__ aux,
                          const float* __restrict__ cw,
                          const float* __restrict__ cb,
                          const float* __restrict__ cinp) {
    __shared__ short As[128 * 64];   // 16 KB
    __shared__ short Bs[128 * 64];   // 16 KB
    const int tid = threadIdx.x;
    const int lane = tid & 63;
    const int wave = tid >> 6;
    const int bm = blockIdx.x * 128;
    const int bn = blockIdx.y * 128;
    const int wm = (wave >> 1) * 64;
    const int wn = (wave & 1) * 64;

    f32x4 acc[4][4];
#pragma unroll
    for (int i = 0; i < 4; ++i)
#pragma unroll
        for (int j = 0; j < 4; ++j) acc[i][j] = (f32x4)0.f;

    const int srow = lane >> 3;                       // 0..7
    const int ssegx = ((lane & 7) ^ srow) * 8;        // swizzled k offset (shorts)
    const __hip_bfloat16* gA0 = A + (size_t)(bm + wave * 32 + srow) * Kv + ssegx;
    const __hip_bfloat16* gB0 = W + (size_t)(bn + wave * 32 + srow) * Kv + ssegx;
    short* lA0 = As + (wave * 32) * 64;
    short* lB0 = Bs + (wave * 32) * 64;

    const int fr = lane & 15;        // fragment row within 16
    const int kq = lane >> 4;        // k-quarter 0..3

    for (int k0 = 0; k0 < Kv; k0 += 64) {
#pragma unroll
        for (int rb = 0; rb < 4; ++rb) {
            cp16_lds(gA0 + (size_t)(rb * 8) * Kv + k0, lA0 + rb * 8 * 64);
            cp16_lds(gB0 + (size_t)(rb * 8) * Kv + k0, lB0 + rb * 8 * 64);
        }
        __syncthreads();
#pragma unroll
        for (int ks = 0; ks < 2; ++ks) {
            const int kgg = ks * 4 + kq;                       // 0..7
            const int kslot = (kgg ^ (fr & 7)) * 8;            // un-swizzle
            bf16x8 af[4], bv[4];
#pragma unroll
            for (int i = 0; i < 4; ++i)
                af[i] = *reinterpret_cast<const bf16x8*>(
                    &As[(wm + i * 16 + fr) * 64 + kslot]);
#pragma unroll
            for (int j = 0; j < 4; ++j)
                bv[j] = *reinterpret_cast<const bf16x8*>(
                    &Bs[(wn + j * 16 + fr) * 64 + kslot]);
#pragma unroll
            for (int i = 0; i < 4; ++i)
#pragma unroll
                for (int j = 0; j < 4; ++j)
                    acc[i][j] = __builtin_amdgcn_mfma_f32_16x16x32_bf16(
                        af[i], bv[j], acc[i][j], 0, 0, 0);
        }
        __syncthreads();
    }

    const int n16 = lane & 15;
    const int r4 = (lane >> 4) * 4;
#pragma unroll
    for (int i = 0; i < 4; ++i) {
#pragma unroll
        for (int j = 0; j < 4; ++j) {
            const int cg = bn + wn + j * 16 + n16;
            const float bb = bias[cg];
#pragma unroll
            for (int v = 0; v < 4; ++v) {
                const int r = bm + wm + i * 16 + r4 + v;
                float val = acc[i][j][v] + bb;
                if (EPI == 1) {
                    if (cg < DI_) {
                        val = val / (1.f + __expf(-val));
                        obf[(size_t)r * DI_ + cg] = __float2bfloat16(val);
                    } else {
                        zb[(size_t)r * DI_ + cg - DI_] = __float2bfloat16(val);
                    }
                } else if (EPI == 2) {
                    if (cg < DI_) {
                        const float x = val + aux[cg];
                        val = (x > 20.f) ? x : __logf(1.f + __expf(x));
                    }
                    out0[(size_t)r * PROJ_ + cg] = val;
                } else {
                    const int b = r >> 12;
                    const int l = r & (L_ - 1);
                    const int lo = L_ - 1 - l;
                    const size_t base = ((size_t)(b << 12) + lo) * 256 + cg;
                    float cv = fmaf(cinp[base], cw[cg * 3 + 1], cb[cg]);
                    if (lo > 0) cv = fmaf(cinp[base - 256], cw[cg * 3 + 0], cv);
                    if (lo + 1 < L_) cv = fmaf(cinp[base + 256], cw[cg * 3 + 2], cv);
                    const float g = 0.5f * cv * (1.f + erff(cv * 0.70710678118654752f));
                    out0[base] = val + g;
                }
            }
        }
    }
}

// ---------------- fwd out_proj + LayerNorm + flip, fused ---------------------
// Tile 32x256 (full output row per block), grid M/32 = 512. 4 waves, wave w
// owns cols w*64. After GEMM: row mean/var via shfl (16 col-lanes) + LDS
// (4 waves), then LN, flip along L, bf16 store to a_bf (feeds bwd in_proj).
__launch_bounds__(256)
__global__ void gemm_out_ln(const __hip_bfloat16* __restrict__ A,
                            const __hip_bfloat16* __restrict__ W,
                            const float* __restrict__ bias,
                            const float* __restrict__ lnw,
                            const float* __restrict__ lnb,
                            __hip_bfloat16* __restrict__ outb) {
    __shared__ short As[32 * 64];     // 4 KB
    __shared__ short Ws[256 * 64];    // 32 KB
    __shared__ float rs[2][4][32];    // 1 KB row partial sums
    const int tid = threadIdx.x;
    const int lane = tid & 63;
    const int wave = tid >> 6;
    const int bm = blockIdx.x * 32;
    const int Kv = DI_;

    f32x4 acc[2][4];
#pragma unroll
    for (int i = 0; i < 2; ++i)
#pragma unroll
        for (int j = 0; j < 4; ++j) acc[i][j] = (f32x4)0.f;

    const int srow = lane >> 3;                       // 0..7
    const int ssegx = ((lane & 7) ^ srow) * 8;        // swizzled k offset
    const __hip_bfloat16* gA0 = A + (size_t)(bm + wave * 8 + srow) * Kv + ssegx;
    const __hip_bfloat16* gW0 = W + (size_t)(wave * 64 + srow) * Kv + ssegx;
    short* lA0 = As + (wave * 8) * 64;
    short* lW0 = Ws + (wave * 64) * 64;

    const int fr = lane & 15;
    const int kq = lane >> 4;

    for (int k0 = 0; k0 < Kv; k0 += 64) {
        cp16_lds(gA0 + k0, lA0);
#pragma unroll
        for (int rb = 0; rb < 8; ++rb)
            cp16_lds(gW0 + (size_t)(rb * 8) * Kv + k0, lW0 + rb * 8 * 64);
        __syncthreads();
#pragma unroll
        for (int ks = 0; ks < 2; ++ks) {
            const int kgg = ks * 4 + kq;
            const int kslot = (kgg ^ (fr & 7)) * 8;
            bf16x8 af[2], bv[4];
#pragma unroll
            for (int i = 0; i < 2; ++i)
                af[i] = *reinterpret_cast<const bf16x8*>(
                    &As[(i * 16 + fr) * 64 + kslot]);
#pragma unroll
            for (int j = 0; j < 4; ++j)
                bv[j] = *reinterpret_cast<const bf16x8*>(
                    &Ws[(wave * 64 + j * 16 + fr) * 64 + kslot]);
#pragma unroll
            for (int i = 0; i < 2; ++i)
#pragma unroll
                for (int j = 0; j < 4; ++j)
                    acc[i][j] = __builtin_amdgcn_mfma_f32_16x16x32_bf16(
                        af[i], bv[j], acc[i][j], 0, 0, 0);
        }
        __syncthreads();
    }

    const int n16 = lane & 15;
    const int r4 = (lane >> 4) * 4;
    float vals[2][4][4];
#pragma unroll
    for (int i = 0; i < 2; ++i)
#pragma unroll
        for (int j = 0; j < 4; ++j) {
            const float bb = bias[wave * 64 + j * 16 + n16];
#pragma unroll
            for (int v = 0; v < 4; ++v) vals[i][j][v] = acc[i][j][v] + bb;
        }

    // per-row partial sums over this wave's 64 cols
#pragma unroll
    for (int i = 0; i < 2; ++i)
#pragma unroll
        for (int v = 0; v < 4; ++v) {
            float s = 0.f, s2 = 0.f;
#pragma unroll
            for (int j = 0; j < 4; ++j) {
                const float t = vals[i][j][v];
                s += t; s2 = fmaf(t, t, s2);
            }
            s += __shfl_xor(s, 1); s2 += __shfl_xor(s2, 1);
            s += __shfl_xor(s, 2); s2 += __shfl_xor(s2, 2);
            s += __shfl_xor(s, 4); s2 += __shfl_xor(s2, 4);
            s += __shfl_xor(s, 8); s2 += __shfl_xor(s2, 8);
            if (n16 == 0) {
                rs[0][wave][i * 16 + r4 + v] = s;
                rs[1][wave][i * 16 + r4 + v] = s2;
            }
        }
    __syncthreads();

#pragma unroll
    for (int i = 0; i < 2; ++i)
#pragma unroll
        for (int v = 0; v < 4; ++v) {
            const int row = i * 16 + r4 + v;
            const float ts = rs[0][0][row] + rs[0][1][row] + rs[0][2][row] + rs[0][3][row];
            const float ts2 = rs[1][0][row] + rs[1][1][row] + rs[1][2][row] + rs[1][3][row];
            const float mean = ts * (1.f / 256.f);
            const float var = ts2 * (1.f / 256.f) - mean * mean;
            const float inv = rsqrtf(var + 1e-5f);
            const int rg = bm + row;
            const int b = rg >> 12;
            const int l = rg & (L_ - 1);
            const size_t drow = (size_t)((b << 12) + (L_ - 1 - l)) * 256;
#pragma unroll
            for (int j = 0; j < 4; ++j) {
                const int cg = wave * 64 + j * 16 + n16;
                const float o = (vals[i][j][v] - mean) * inv * lnw[cg] + lnb[cg];
                outb[drow + cg] = __float2bfloat16(o);
            }
        }
}

// ---------------- chunked selective scan, software-pipelined -----------------
__device__ __forceinline__ bool a_is_arith(const float* A2) {
    bool ok = true;
#pragma unroll
    for (int n = 1; n < N_; ++n)
        ok = ok && (fabsf(A2[n] - (float)(n + 1) * A2[0]) <= 1e-4f * fabsf(A2[n]));
    return ok;
}

__launch_bounds__(256)
__global__ void scan_chunk_state(const __hip_bfloat16* __restrict__ xi,
                                 const float* __restrict__ proj,
                                 const float* __restrict__ A_log,
                                 float* __restrict__ st_prod,
                                 float* __restrict__ st_hend) {
    __shared__ float bsh[4][CL_][16];   // 8 KB: per-wave B cache
    const int bh = blockIdx.x;
    const int b = bh >> 3;
    const int h = bh & 7;
    const int lane = threadIdx.x & 63;
    const int wave = threadIdx.x >> 6;
    const int chunk = blockIdx.y * 4 + wave;
    const int t0 = chunk * CL_;
    const int c = h * P_ + lane;
    const int bOff = DI_ + h * N_;

    {
        const int stp = lane >> 2;
        const int off4 = (lane & 3) * 4;
        const float* base = proj + ((size_t)b * L_ + t0) * PROJ_ + bOff + off4;
#pragma unroll
        for (int r = 0; r < 2; ++r)
            cp16f_lds(base + (size_t)(r * 16 + stp) * PROJ_,
                      &bsh[wave][0][0] + r * 256);
    }

    float A2[N_], hs[N_];
#pragma unroll
    for (int n = 0; n < N_; ++n) {
        A2[n] = -__expf(A_log[c * N_ + n]) * LOG2E_;
        hs[n] = 0.f;
    }
    const bool fast = a_is_arith(A2);
    __syncthreads();

    const float* pDt = proj + ((size_t)b * L_ + t0) * PROJ_ + c;
    const __hip_bfloat16* px = xi + ((size_t)b * L_ + t0) * DI_ + c;
    float S = 0.f;

    if (fast) {
        float dtb[2][4], xb[2][4];
#pragma unroll
        for (int i = 0; i < 4; ++i) {
            dtb[0][i] = pDt[(size_t)i * PROJ_];
            xb[0][i] = __bfloat162float(px[(size_t)i * DI_]);
        }
#pragma unroll
        for (int k = 0; k < CL_ / 4; ++k) {
            const int cur = k & 1, nxt = cur ^ 1;
            if (k + 1 < CL_ / 4) {
#pragma unroll
                for (int i = 0; i < 4; ++i) {
                    dtb[nxt][i] = pDt[(size_t)((k + 1) * 4 + i) * PROJ_];
                    xb[nxt][i] = __bfloat162float(px[(size_t)((k + 1) * 4 + i) * DI_]);
                }
            }
#pragma unroll
            for (int i = 0; i < 4; ++i) {
                const int t = k * 4 + i;
                const float dt_v = dtb[cur][i];
                const float dtx = dt_v * xb[cur][i];
                const float e1 = exp2f(dt_v * A2[0]);
                S += dt_v;
                const f32x4* bp = reinterpret_cast<const f32x4*>(&bsh[wave][t][0]);
                float dA = e1;
#pragma unroll
                for (int q = 0; q < 4; ++q) {
                    const f32x4 Bq = bp[q];
#pragma unroll
                    for (int j = 0; j < 4; ++j) {
                        hs[q * 4 + j] = fmaf(hs[q * 4 + j], dA, dtx * Bq[j]);
                        dA *= e1;
                    }
                }
            }
        }
    } else {
#pragma unroll 4
        for (int t = 0; t < CL_; ++t) {
            const float dt_v = pDt[(size_t)t * PROJ_];
            const float xv = __bfloat162float(px[(size_t)t * DI_]);
            const float dtx = dt_v * xv;
            S += dt_v;
#pragma unroll
            for (int n = 0; n < N_; ++n) {
                const float dA = exp2f(dt_v * A2[n]);
                hs[n] = fmaf(hs[n], dA, dtx * bsh[wave][t][n]);
            }
        }
    }

    const size_t s0 = (size_t)chunk * NSEQ_ + ((size_t)(bh * P_ + lane)) * N_;
#pragma unroll
    for (int n = 0; n < N_; n += 4) {
        *reinterpret_cast<float4*>(st_prod + s0 + n) =
            make_float4(exp2f(A2[n] * S), exp2f(A2[n + 1] * S),
                        exp2f(A2[n + 2] * S), exp2f(A2[n + 3] * S));
        *reinterpret_cast<float4*>(st_hend + s0 + n) =
            make_float4(hs[n], hs[n + 1], hs[n + 2], hs[n + 3]);
    }
}

__launch_bounds__(256)
__global__ void scan_combine(float* __restrict__ st_prod,
                             const float* __restrict__ st_hend) {
    const int s = blockIdx.x * 256 + threadIdx.x;
    float H = 0.f;
#pragma unroll 8
    for (int k = 0; k < NC_; ++k) {
        const size_t o = (size_t)k * NSEQ_ + s;
        const float Pv = st_prod[o];
        const float Ev = st_hend[o];
        st_prod[o] = H;
        H = fmaf(Pv, H, Ev);
    }
}

__launch_bounds__(256)
__global__ void scan_chunk_out(const __hip_bfloat16* __restrict__ xi,
                               const __hip_bfloat16* __restrict__ z,
                               const float* __restrict__ proj,
                               const float* __restrict__ A_log,
                               const float* __restrict__ D_skip,
                               const float* __restrict__ st_hin,
                               __hip_bfloat16* __restrict__ yg) {
    __shared__ float bc[4][CL_][32];   // 16 KB: per-wave B|C cache
    const int bh = blockIdx.x;
    const int b = bh >> 3;
    const int h = bh & 7;
    const int lane = threadIdx.x & 63;
    const int wave = threadIdx.x >> 6;
    const int chunk = blockIdx.y * 4 + wave;
    const int t0 = chunk * CL_;
    const int c = h * P_ + lane;
    const int bOff = DI_ + h * N_;
    const int cOff = DI_ + H_ * N_ + h * N_;

    {
        const int seg = lane >> 2;
        const int off4 = (lane & 3) * 4;
        const float* rowb = proj + ((size_t)b * L_ + t0) * PROJ_;
#pragma unroll
        for (int r = 0; r < 4; ++r) {
            const int s = r * 16 + seg;
            const int stp = s >> 1;
            const int half = s & 1;
            cp16f_lds(rowb + (size_t)stp * PROJ_ + (half ? cOff : bOff) + off4,
                      &bc[wave][0][0] + r * 256);
        }
    }

    float A2[N_], hs[N_];
    const size_t s0 = (size_t)chunk * NSEQ_ + ((size_t)(bh * P_ + lane)) * N_;
#pragma unroll
    for (int n = 0; n < N_; n += 4) {
        const float4 h4 = *reinterpret_cast<const float4*>(st_hin + s0 + n);
        hs[n] = h4.x; hs[n + 1] = h4.y; hs[n + 2] = h4.z; hs[n + 3] = h4.w;
    }
#pragma unroll
    for (int n = 0; n < N_; ++n)
        A2[n] = -__expf(A_log[c * N_ + n]) * LOG2E_;
    const bool fast = a_is_arith(A2);
    const float Dv = D_skip[c];
    __syncthreads();

    const float* pDt = proj + ((size_t)b * L_ + t0) * PROJ_ + c;
    const __hip_bfloat16* px = xi + ((size_t)b * L_ + t0) * DI_ + c;
    const __hip_bfloat16* pz = z + ((size_t)b * L_ + t0) * DI_ + c;
    __hip_bfloat16* py = yg + ((size_t)b * L_ + t0) * DI_ + c;

    if (fast) {
        float dtb[2][4], xb[2][4], zb[2][4];
#pragma unroll
        for (int i = 0; i < 4; ++i) {
            dtb[0][i] = pDt[(size_t)i * PROJ_];
            xb[0][i] = __bfloat162float(px[(size_t)i * DI_]);
            zb[0][i] = __bfloat162float(pz[(size_t)i * DI_]);
        }
#pragma unroll
        for (int k = 0; k < CL_ / 4; ++k) {
            const int cur = k & 1, nxt = cur ^ 1;
            if (k + 1 < CL_ / 4) {
#pragma unroll
                for (int i = 0; i < 4; ++i) {
                    const int t = (k + 1) * 4 + i;
                    dtb[nxt][i] = pDt[(size_t)t * PROJ_];
                    xb[nxt][i] = __bfloat162float(px[(size_t)t * DI_]);
                    zb[nxt][i] = __bfloat162float(pz[(size_t)t * DI_]);
                }
            }
#pragma unroll
            for (int i = 0; i < 4; ++i) {
                const int t = k * 4 + i;
                const float dt_v = dtb[cur][i];
                const float xv = xb[cur][i];
                const float zv = zb[cur][i];
                const float dtx = dt_v * xv;
                const float e1 = exp2f(dt_v * A2[0]);
                const f32x4* bp = reinterpret_cast<const f32x4*>(&bc[wave][t][0]);
                float dA = e1;
                float y = 0.f;
#pragma unroll
                for (int q = 0; q < 4; ++q) {
                    const f32x4 Bq = bp[q];
                    const f32x4 Cq = bp[4 + q];
#pragma unroll
                    for (int j = 0; j < 4; ++j) {
                        hs[q * 4 + j] = fmaf(hs[q * 4 + j], dA, dtx * Bq[j]);
                        y = fmaf(hs[q * 4 + j], Cq[j], y);
                        dA *= e1;
                    }
                }
                const float g = zv / (1.f + __expf(-zv));
                py[(size_t)t * DI_] = __float2bfloat16((y + Dv * xv) * g);
            }
        }
    } else {
#pragma unroll 4
        for (int t = 0; t < CL_; ++t) {
            const float dt_v = pDt[(size_t)t * PROJ_];
            const float xv = __bfloat162float(px[(size_t)t * DI_]);
            const float zv = __bfloat162float(pz[(size_t)t * DI_]);
            const float dtx = dt_v * xv;
            float y = 0.f;
#pragma unroll
            for (int n = 0; n < N_; ++n) {
                const float dA = exp2f(dt_v * A2[n]);
                hs[n] = fmaf(hs[n], dA, dtx * bc[wave][t][n]);
                y = fmaf(hs[n], bc[wave][t][16 + n], y);
            }
            const float g = zv / (1.f + __expf(-zv));
            py[(size_t)t * DI_] = __float2bfloat16((y + Dv * xv) * g);
        }
    }
}

// ---------------- host launcher --------------------------------------------
extern "C" void kernel_launch(void* const* d_in, const int* in_sizes, int n_in,
                              void* d_out, int out_size, void* d_ws, size_t ws_size,
                              hipStream_t stream) {
    const float* inputs = (const float*)d_in[0];
    const float* f_in_w = (const float*)d_in[1];
    const float* f_in_b = (const float*)d_in[2];
    const float* f_xp_w = (const float*)d_in[3];
    const float* f_xp_b = (const float*)d_in[4];
    const float* f_dt_b = (const float*)d_in[5];
    const float* f_A = (const float*)d_in[6];
    const float* f_D = (const float*)d_in[7];
    const float* f_out_w = (const float*)d_in[8];
    const float* f_out_b = (const float*)d_in[9];
    const float* b_in_w = (const float*)d_in[10];
    const float* b_in_b = (const float*)d_in[11];
    const float* b_xp_w = (const float*)d_in[12];
    const float* b_xp_b = (const float*)d_in[13];
    const float* b_dt_b = (const float*)d_in[14];
    const float* b_A = (const float*)d_in[15];
    const float* b_D = (const float*)d_in[16];
    const float* b_out_w = (const float*)d_in[17];
    const float* b_out_b = (const float*)d_in[18];
    const float* norm_w = (const float*)d_in[19];
    const float* norm_b = (const float*)d_in[20];
    const float* conv_w = (const float*)d_in[21];
    const float* conv_b = (const float*)d_in[22];
    float* out = (float*)d_out;

    // workspace layout (footprint unchanged from R8; zbuf slot reused as bf16 z)
    float* ws = (float*)d_ws;
    float* st_prod = ws;                                  // 4,194,304 f
    float* st_hend = st_prod + (size_t)NSEQ_ * NC_;       // 4,194,304 f
    float* zslot   = st_hend + (size_t)NSEQ_ * NC_;       // 8,388,608 f slot
    __hip_bfloat16* z_bf = (__hip_bfloat16*)zslot;        // uses half the slot
    float* proj    = zslot + (size_t)M_ * DI_;            // 12,582,912 f
    float* y1      = proj + (size_t)M_ * PROJ_;           // (unused slot, kept)
    __hip_bfloat16* xi_bf = (__hip_bfloat16*)(y1 + (size_t)M_ * D_);   // 8,388,608 bf16
    __hip_bfloat16* yg_bf = xi_bf + (size_t)M_ * DI_;                  // 8,388,608 bf16
    __hip_bfloat16* a_bf  = yg_bf + (size_t)M_ * DI_;                  // 4,194,304 bf16
    __hip_bfloat16* wpool = a_bf + (size_t)M_ * D_;
    __hip_bfloat16* f_in_wb  = wpool;
    __hip_bfloat16* f_xp_wb  = f_in_wb + 2 * DI_ * D_;
    __hip_bfloat16* f_out_wb = f_xp_wb + PROJ_ * DI_;
    __hip_bfloat16* b_in_wb  = f_out_wb + D_ * DI_;
    __hip_bfloat16* b_xp_wb  = b_in_wb + 2 * DI_ * D_;
    __hip_bfloat16* b_out_wb = b_xp_wb + PROJ_ * DI_;

    const dim3 blk(256);
    const dim3 g_in(M_ / 128, (2 * DI_) / 128);   // (128,8)
    const dim3 g_xp(M_ / 128, PROJ_ / 128);       // (128,6)
    const dim3 g_out(M_ / 128, 2);                // (128,2) bwd out_proj
    const dim3 g_oln(M_ / 32);                    // 512 blocks fwd out_proj+LN
    const dim3 g_chunk(B_ * H_, NC_ / 4);         // (32,32)
    const dim3 g_comb(NSEQ_ / 256);               // 128 blocks

    // ---- fused fp32 -> bf16 conversions ----
    f2b_all<<<dim3(4096), blk, 0, stream>>>(inputs, f_in_w, f_xp_w, f_out_w,
                                            b_in_w, b_xp_w, b_out_w,
                                            a_bf, f_in_wb, f_xp_wb, f_out_wb,
                                            b_in_wb, b_xp_wb, b_out_wb);

    // ---- forward pass ----
    gemm_mfma<1><<<g_in, blk, 0, stream>>>(a_bf, f_in_wb, f_in_b, D_,
                                           nullptr, z_bf, xi_bf, nullptr,
                                           nullptr, nullptr, nullptr);
    gemm_mfma<2><<<g_xp, blk, 0, stream>>>(xi_bf, f_xp_wb, f_xp_b, DI_,
                                           proj, nullptr, nullptr, f_dt_b,
                                           nullptr, nullptr, nullptr);
    scan_chunk_state<<<g_chunk, blk, 0, stream>>>(xi_bf, proj, f_A, st_prod, st_hend);
    scan_combine<<<g_comb, blk, 0, stream>>>(st_prod, st_hend);
    scan_chunk_out<<<g_chunk, blk, 0, stream>>>(xi_bf, z_bf, proj, f_A, f_D,
                                                st_prod, yg_bf);
    gemm_out_ln<<<g_oln, blk, 0, stream>>>(yg_bf, f_out_wb, f_out_b,
                                           norm_w, norm_b, a_bf);

    // ---- backward pass ----
    gemm_mfma<1><<<g_in, blk, 0, stream>>>(a_bf, b_in_wb, b_in_b, D_,
                                           nullptr, z_bf, xi_bf, nullptr,
                                           nullptr, nullptr, nullptr);
    gemm_mfma<2><<<g_xp, blk, 0, stream>>>(xi_bf, b_xp_wb, b_xp_b, DI_,
                                           proj, nullptr, nullptr, b_dt_b,
                                           nullptr, nullptr, nullptr);
    scan_chunk_state<<<g_chunk, blk, 0, stream>>>(xi_bf, proj, b_A, st_prod, st_hend);
    scan_combine<<<g_comb, blk, 0, stream>>>(st_prod, st_hend);
    scan_chunk_out<<<g_chunk, blk, 0, stream>>>(xi_bf, z_bf, proj, b_A, b_D,
                                                st_prod, yg_bf);
    // final out_proj with flipped store + fused conv3+GELU locality branch
    gemm_mfma<3><<<g_out, blk, 0, stream>>>(yg_bf, b_out_wb, b_out_b, DI_,
                                            out, nullptr, nullptr, nullptr,
                                            conv_w, conv_b, inputs);
}

// Round 10
// 388.303 us; speedup vs baseline: 10.9427x; 1.0298x over previous
//
#include <hip/hip_runtime.h>
#include <hip/hip_bf16.h>
#include <cstdint>
#include <cstddef>

// ---------------- problem constants ----------------
#define B_  4
#define L_  4096
#define D_  256
#define DI_ 512
#define H_  8
#define P_  64
#define N_  16
#define M_  (B_ * L_)              // 16384 rows
#define PROJ_ (DI_ + 2 * H_ * N_)  // 768

// chunked scan parameters (1 thread = 1 (b,h,p) channel, 16 states)
#define NC_ 128                    // chunks along L
#define CL_ (L_ / NC_)             // 32
#define NSEQ_ (B_ * H_ * P_ * N_)  // 32768 scalar sequences
#define LOG2E_ 1.4426950408889634f

typedef __bf16 bf16x8 __attribute__((ext_vector_type(8)));
typedef float f32x4 __attribute__((ext_vector_type(4)));

__device__ __forceinline__ void cp16_lds(const __hip_bfloat16* g, short* lds) {
    __builtin_amdgcn_global_load_lds(
        (const __attribute__((address_space(1))) void*)g,
        (__attribute__((address_space(3))) void*)lds, 16, 0, 0);
}
__device__ __forceinline__ void cp16f_lds(const float* g, float* lds) {
    __builtin_amdgcn_global_load_lds(
        (const __attribute__((address_space(1))) void*)g,
        (__attribute__((address_space(3))) void*)lds, 16, 0, 0);
}

// ---------------- fused fp32 -> bf16 conversion (7 segments) -----------------
#define FS0 (M_ * D_)          // inputs      4194304
#define FS1 (2 * DI_ * D_)     // in_proj_w    262144
#define FS2 (PROJ_ * DI_)      // x_proj_w     393216
#define FS3 (D_ * DI_)         // out_proj_w   131072
#define FC1 (FS0 + FS1)
#define FC2 (FC1 + FS2)
#define FC3 (FC2 + FS3)
#define FC4 (FC3 + FS1)
#define FC5 (FC4 + FS2)
#define FC6 (FC5 + FS3)

__launch_bounds__(256)
__global__ void f2b_all(const float* __restrict__ i0, const float* __restrict__ i1,
                        const float* __restrict__ i2, const float* __restrict__ i3,
                        const float* __restrict__ i4, const float* __restrict__ i5,
                        const float* __restrict__ i6,
                        __hip_bfloat16* o0, __hip_bfloat16* o1, __hip_bfloat16* o2,
                        __hip_bfloat16* o3, __hip_bfloat16* o4, __hip_bfloat16* o5,
                        __hip_bfloat16* o6) {
    for (int idx = blockIdx.x * 256 + threadIdx.x; idx < FC6; idx += gridDim.x * 256) {
        const float* s; __hip_bfloat16* d; int off;
        if (idx < FS0)      { s = i0; d = o0; off = idx; }
        else if (idx < FC1) { s = i1; d = o1; off = idx - FS0; }
        else if (idx < FC2) { s = i2; d = o2; off = idx - FC1; }
        else if (idx < FC3) { s = i3; d = o3; off = idx - FC2; }
        else if (idx < FC4) { s = i4; d = o4; off = idx - FC3; }
        else if (idx < FC5) { s = i5; d = o5; off = idx - FC4; }
        else                { s = i6; d = o6; off = idx - FC5; }
        d[off] = __float2bfloat16(s[off]);
    }
}

// ---------------- MFMA bf16 GEMM 128x128: C = A * W^T + bias -----------------
// BK=64, XOR-swizzled LDS -> conflict-free ds_read_b128.
// EPI 1: in_proj: col<DI -> silu -> obf bf16 (xi); else z bf16 (zb)
// EPI 2: x_proj: col<DI -> softplus(v+aux); fp32 store ld=768
template <int EPI>
__launch_bounds__(256)
__global__ void gemm_mfma(const __hip_bfloat16* __restrict__ A,
                          const __hip_bfloat16* __restrict__ W,
                          const float* __restrict__ bias, int Kv,
                          float* __restrict__ out0,
                          __hip_bfloat16* __restrict__ zb,
                          __hip_bfloat16* __restrict__ obf,
                          const float* __restrict__ aux) {
    __shared__ short As[128 * 64];   // 16 KB
    __shared__ short Bs[128 * 64];   // 16 KB
    const int tid = threadIdx.x;
    const int lane = tid & 63;
    const int wave = tid >> 6;
    const int bm = blockIdx.x * 128;
    const int bn = blockIdx.y * 128;
    const int wm = (wave >> 1) * 64;
    const int wn = (wave & 1) * 64;

    f32x4 acc[4][4];
#pragma unroll
    for (int i = 0; i < 4; ++i)
#pragma unroll
        for (int j = 0; j < 4; ++j) acc[i][j] = (f32x4)0.f;

    const int srow = lane >> 3;                       // 0..7
    const int ssegx = ((lane & 7) ^ srow) * 8;        // swizzled k offset (shorts)
    const __hip_bfloat16* gA0 = A + (size_t)(bm + wave * 32 + srow) * Kv + ssegx;
    const __hip_bfloat16* gB0 = W + (size_t)(bn + wave * 32 + srow) * Kv + ssegx;
    short* lA0 = As + (wave * 32) * 64;
    short* lB0 = Bs + (wave * 32) * 64;

    const int fr = lane & 15;        // fragment row within 16
    const int kq = lane >> 4;        // k-quarter 0..3

    for (int k0 = 0; k0 < Kv; k0 += 64) {
#pragma unroll
        for (int rb = 0; rb < 4; ++rb) {
            cp16_lds(gA0 + (size_t)(rb * 8) * Kv + k0, lA0 + rb * 8 * 64);
            cp16_lds(gB0 + (size_t)(rb * 8) * Kv + k0, lB0 + rb * 8 * 64);
        }
        __syncthreads();
#pragma unroll
        for (int ks = 0; ks < 2; ++ks) {
            const int kgg = ks * 4 + kq;                       // 0..7
            const int kslot = (kgg ^ (fr & 7)) * 8;            // un-swizzle
            bf16x8 af[4], bv[4];
#pragma unroll
            for (int i = 0; i < 4; ++i)
                af[i] = *reinterpret_cast<const bf16x8*>(
                    &As[(wm + i * 16 + fr) * 64 + kslot]);
#pragma unroll
            for (int j = 0; j < 4; ++j)
                bv[j] = *reinterpret_cast<const bf16x8*>(
                    &Bs[(wn + j * 16 + fr) * 64 + kslot]);
#pragma unroll
            for (int i = 0; i < 4; ++i)
#pragma unroll
                for (int j = 0; j < 4; ++j)
                    acc[i][j] = __builtin_amdgcn_mfma_f32_16x16x32_bf16(
                        af[i], bv[j], acc[i][j], 0, 0, 0);
        }
        __syncthreads();
    }

    const int n16 = lane & 15;
    const int r4 = (lane >> 4) * 4;
#pragma unroll
    for (int i = 0; i < 4; ++i) {
#pragma unroll
        for (int j = 0; j < 4; ++j) {
            const int cg = bn + wn + j * 16 + n16;
            const float bb = bias[cg];
#pragma unroll
            for (int v = 0; v < 4; ++v) {
                const int r = bm + wm + i * 16 + r4 + v;
                float val = acc[i][j][v] + bb;
                if (EPI == 1) {
                    if (cg < DI_) {
                        val = val / (1.f + __expf(-val));
                        obf[(size_t)r * DI_ + cg] = __float2bfloat16(val);
                    } else {
                        zb[(size_t)r * DI_ + cg - DI_] = __float2bfloat16(val);
                    }
                } else {  // EPI 2
                    if (cg < DI_) {
                        const float x = val + aux[cg];
                        val = (x > 20.f) ? x : __logf(1.f + __expf(x));
                    }
                    out0[(size_t)r * PROJ_ + cg] = val;
                }
            }
        }
    }
}

// ---------------- small-tile GEMM 64x64: bwd out_proj + conv/GELU ------------
// grid (M/64, 256/64) = 1024 blocks -> 4 blocks/CU (vs 1 at 128x128): fixes the
// 12.5%-occupancy grid starvation of the N=256 GEMM. Numerically identical.
__launch_bounds__(256)
__global__ void gemm64_convout(const __hip_bfloat16* __restrict__ A,
                               const __hip_bfloat16* __restrict__ W,
                               const float* __restrict__ bias, int Kv,
                               float* __restrict__ out0,
                               const float* __restrict__ cw,
                               const float* __restrict__ cb,
                               const float* __restrict__ cinp) {
    __shared__ short As[64 * 64];    // 8 KB
    __shared__ short Bs[64 * 64];    // 8 KB
    const int tid = threadIdx.x;
    const int lane = tid & 63;
    const int wave = tid >> 6;
    const int bm = blockIdx.x * 64;
    const int bn = blockIdx.y * 64;
    const int wm = (wave >> 1) * 32;
    const int wn = (wave & 1) * 32;

    f32x4 acc[2][2];
#pragma unroll
    for (int i = 0; i < 2; ++i)
#pragma unroll
        for (int j = 0; j < 2; ++j) acc[i][j] = (f32x4)0.f;

    const int srow = lane >> 3;                       // 0..7
    const int ssegx = ((lane & 7) ^ srow) * 8;
    const __hip_bfloat16* gA0 = A + (size_t)(bm + wave * 16 + srow) * Kv + ssegx;
    const __hip_bfloat16* gB0 = W + (size_t)(bn + wave * 16 + srow) * Kv + ssegx;
    short* lA0 = As + (wave * 16) * 64;
    short* lB0 = Bs + (wave * 16) * 64;

    const int fr = lane & 15;
    const int kq = lane >> 4;

    for (int k0 = 0; k0 < Kv; k0 += 64) {
#pragma unroll
        for (int rb = 0; rb < 2; ++rb) {
            cp16_lds(gA0 + (size_t)(rb * 8) * Kv + k0, lA0 + rb * 8 * 64);
            cp16_lds(gB0 + (size_t)(rb * 8) * Kv + k0, lB0 + rb * 8 * 64);
        }
        __syncthreads();
#pragma unroll
        for (int ks = 0; ks < 2; ++ks) {
            const int kgg = ks * 4 + kq;
            const int kslot = (kgg ^ (fr & 7)) * 8;
            bf16x8 af[2], bv[2];
#pragma unroll
            for (int i = 0; i < 2; ++i)
                af[i] = *reinterpret_cast<const bf16x8*>(
                    &As[(wm + i * 16 + fr) * 64 + kslot]);
#pragma unroll
            for (int j = 0; j < 2; ++j)
                bv[j] = *reinterpret_cast<const bf16x8*>(
                    &Bs[(wn + j * 16 + fr) * 64 + kslot]);
#pragma unroll
            for (int i = 0; i < 2; ++i)
#pragma unroll
                for (int j = 0; j < 2; ++j)
                    acc[i][j] = __builtin_amdgcn_mfma_f32_16x16x32_bf16(
                        af[i], bv[j], acc[i][j], 0, 0, 0);
        }
        __syncthreads();
    }

    const int n16 = lane & 15;
    const int r4 = (lane >> 4) * 4;
#pragma unroll
    for (int i = 0; i < 2; ++i) {
#pragma unroll
        for (int j = 0; j < 2; ++j) {
            const int cg = bn + wn + j * 16 + n16;
            const float bb = bias[cg];
#pragma unroll
            for (int v = 0; v < 4; ++v) {
                const int r = bm + wm + i * 16 + r4 + v;
                float val = acc[i][j][v] + bb;
                // flipped store + fused depthwise conv3 + exact GELU add
                const int b = r >> 12;
                const int l = r & (L_ - 1);
                const int lo = L_ - 1 - l;
                const size_t base = ((size_t)(b << 12) + lo) * 256 + cg;
                float cv = fmaf(cinp[base], cw[cg * 3 + 1], cb[cg]);
                if (lo > 0) cv = fmaf(cinp[base - 256], cw[cg * 3 + 0], cv);
                if (lo + 1 < L_) cv = fmaf(cinp[base + 256], cw[cg * 3 + 2], cv);
                const float g = 0.5f * cv * (1.f + erff(cv * 0.70710678118654752f));
                out0[base] = val + g;
            }
        }
    }
}

// ---------------- fwd out_proj + LayerNorm + flip, 16-row tiles --------------
// grid M/16 = 1024 blocks, LDS ~34.5 KB -> 4 blocks/CU (vs 2 at 32-row tiles).
// Wave w owns cols w*64 over all 16 rows; LN row-reduce via shfl + LDS.
__launch_bounds__(256)
__global__ void gemm_out_ln(const __hip_bfloat16* __restrict__ A,
                            const __hip_bfloat16* __restrict__ W,
                            const float* __restrict__ bias,
                            const float* __restrict__ lnw,
                            const float* __restrict__ lnb,
                            __hip_bfloat16* __restrict__ outb) {
    __shared__ short As[16 * 64];     // 2 KB
    __shared__ short Ws[256 * 64];    // 32 KB
    __shared__ float rs[2][4][16];    // 512 B row partial sums
    const int tid = threadIdx.x;
    const int lane = tid & 63;
    const int wave = tid >> 6;
    const int bm = blockIdx.x * 16;
    const int Kv = DI_;

    f32x4 acc[4];
#pragma unroll
    for (int j = 0; j < 4; ++j) acc[j] = (f32x4)0.f;

    const int srow = lane >> 3;                       // 0..7
    const int ssegx = ((lane & 7) ^ srow) * 8;
    const __hip_bfloat16* gA0 = A + (size_t)(bm + wave * 8 + srow) * Kv + ssegx;
    const __hip_bfloat16* gW0 = W + (size_t)(wave * 64 + srow) * Kv + ssegx;
    short* lA0 = As + (wave * 8) * 64;
    short* lW0 = Ws + (wave * 64) * 64;

    const int fr = lane & 15;
    const int kq = lane >> 4;

    for (int k0 = 0; k0 < Kv; k0 += 64) {
        if (wave < 2) cp16_lds(gA0 + k0, lA0);
#pragma unroll
        for (int rb = 0; rb < 8; ++rb)
            cp16_lds(gW0 + (size_t)(rb * 8) * Kv + k0, lW0 + rb * 8 * 64);
        __syncthreads();
#pragma unroll
        for (int ks = 0; ks < 2; ++ks) {
            const int kgg = ks * 4 + kq;
            const int kslot = (kgg ^ (fr & 7)) * 8;
            const bf16x8 af = *reinterpret_cast<const bf16x8*>(
                &As[fr * 64 + kslot]);
#pragma unroll
            for (int j = 0; j < 4; ++j) {
                const bf16x8 bv = *reinterpret_cast<const bf16x8*>(
                    &Ws[(wave * 64 + j * 16 + fr) * 64 + kslot]);
                acc[j] = __builtin_amdgcn_mfma_f32_16x16x32_bf16(
                    af, bv, acc[j], 0, 0, 0);
            }
        }
        __syncthreads();
    }

    const int n16 = lane & 15;
    const int r4 = (lane >> 4) * 4;
    float vals[4][4];
#pragma unroll
    for (int j = 0; j < 4; ++j) {
        const float bb = bias[wave * 64 + j * 16 + n16];
#pragma unroll
        for (int v = 0; v < 4; ++v) vals[j][v] = acc[j][v] + bb;
    }

    // per-row partial sums over this wave's 64 cols
#pragma unroll
    for (int v = 0; v < 4; ++v) {
        float s = 0.f, s2 = 0.f;
#pragma unroll
        for (int j = 0; j < 4; ++j) {
            const float t = vals[j][v];
            s += t; s2 = fmaf(t, t, s2);
        }
        s += __shfl_xor(s, 1); s2 += __shfl_xor(s2, 1);
        s += __shfl_xor(s, 2); s2 += __shfl_xor(s2, 2);
        s += __shfl_xor(s, 4); s2 += __shfl_xor(s2, 4);
        s += __shfl_xor(s, 8); s2 += __shfl_xor(s2, 8);
        if (n16 == 0) {
            rs[0][wave][r4 + v] = s;
            rs[1][wave][r4 + v] = s2;
        }
    }
    __syncthreads();

#pragma unroll
    for (int v = 0; v < 4; ++v) {
        const int row = r4 + v;
        const float ts = rs[0][0][row] + rs[0][1][row] + rs[0][2][row] + rs[0][3][row];
        const float ts2 = rs[1][0][row] + rs[1][1][row] + rs[1][2][row] + rs[1][3][row];
        const float mean = ts * (1.f / 256.f);
        const float var = ts2 * (1.f / 256.f) - mean * mean;
        const float inv = rsqrtf(var + 1e-5f);
        const int rg = bm + row;
        const int b = rg >> 12;
        const int l = rg & (L_ - 1);
        const size_t drow = (size_t)((b << 12) + (L_ - 1 - l)) * 256;
#pragma unroll
        for (int j = 0; j < 4; ++j) {
            const int cg = wave * 64 + j * 16 + n16;
            const float o = (vals[j][v] - mean) * inv * lnw[cg] + lnb[cg];
            outb[drow + cg] = __float2bfloat16(o);
        }
    }
}

// ---------------- chunked selective scan, software-pipelined -----------------
__device__ __forceinline__ bool a_is_arith(const float* A2) {
    bool ok = true;
#pragma unroll
    for (int n = 1; n < N_; ++n)
        ok = ok && (fabsf(A2[n] - (float)(n + 1) * A2[0]) <= 1e-4f * fabsf(A2[n]));
    return ok;
}

__launch_bounds__(256)
__global__ void scan_chunk_state(const __hip_bfloat16* __restrict__ xi,
                                 const float* __restrict__ proj,
                                 const float* __restrict__ A_log,
                                 float* __restrict__ st_prod,
                                 float* __restrict__ st_hend) {
    __shared__ float bsh[4][CL_][16];   // 8 KB: per-wave B cache
    const int bh = blockIdx.x;
    const int b = bh >> 3;
    const int h = bh & 7;
    const int lane = threadIdx.x & 63;
    const int wave = threadIdx.x >> 6;
    const int chunk = blockIdx.y * 4 + wave;
    const int t0 = chunk * CL_;
    const int c = h * P_ + lane;
    const int bOff = DI_ + h * N_;

    {
        const int stp = lane >> 2;
        const int off4 = (lane & 3) * 4;
        const float* base = proj + ((size_t)b * L_ + t0) * PROJ_ + bOff + off4;
#pragma unroll
        for (int r = 0; r < 2; ++r)
            cp16f_lds(base + (size_t)(r * 16 + stp) * PROJ_,
                      &bsh[wave][0][0] + r * 256);
    }

    float A2[N_], hs[N_];
#pragma unroll
    for (int n = 0; n < N_; ++n) {
        A2[n] = -__expf(A_log[c * N_ + n]) * LOG2E_;
        hs[n] = 0.f;
    }
    const bool fast = a_is_arith(A2);
    __syncthreads();

    const float* pDt = proj + ((size_t)b * L_ + t0) * PROJ_ + c;
    const __hip_bfloat16* px = xi + ((size_t)b * L_ + t0) * DI_ + c;
    float S = 0.f;

    if (fast) {
        float dtb[2][4], xb[2][4];
#pragma unroll
        for (int i = 0; i < 4; ++i) {
            dtb[0][i] = pDt[(size_t)i * PROJ_];
            xb[0][i] = __bfloat162float(px[(size_t)i * DI_]);
        }
#pragma unroll
        for (int k = 0; k < CL_ / 4; ++k) {
            const int cur = k & 1, nxt = cur ^ 1;
            if (k + 1 < CL_ / 4) {
#pragma unroll
                for (int i = 0; i < 4; ++i) {
                    dtb[nxt][i] = pDt[(size_t)((k + 1) * 4 + i) * PROJ_];
                    xb[nxt][i] = __bfloat162float(px[(size_t)((k + 1) * 4 + i) * DI_]);
                }
            }
#pragma unroll
            for (int i = 0; i < 4; ++i) {
                const int t = k * 4 + i;
                const float dt_v = dtb[cur][i];
                const float dtx = dt_v * xb[cur][i];
                const float e1 = exp2f(dt_v * A2[0]);
                S += dt_v;
                const f32x4* bp = reinterpret_cast<const f32x4*>(&bsh[wave][t][0]);
                float dA = e1;
#pragma unroll
                for (int q = 0; q < 4; ++q) {
                    const f32x4 Bq = bp[q];
#pragma unroll
                    for (int j = 0; j < 4; ++j) {
                        hs[q * 4 + j] = fmaf(hs[q * 4 + j], dA, dtx * Bq[j]);
                        dA *= e1;
                    }
                }
            }
        }
    } else {
#pragma unroll 4
        for (int t = 0; t < CL_; ++t) {
            const float dt_v = pDt[(size_t)t * PROJ_];
            const float xv = __bfloat162float(px[(size_t)t * DI_]);
            const float dtx = dt_v * xv;
            S += dt_v;
#pragma unroll
            for (int n = 0; n < N_; ++n) {
                const float dA = exp2f(dt_v * A2[n]);
                hs[n] = fmaf(hs[n], dA, dtx * bsh[wave][t][n]);
            }
        }
    }

    const size_t s0 = (size_t)chunk * NSEQ_ + ((size_t)(bh * P_ + lane)) * N_;
#pragma unroll
    for (int n = 0; n < N_; n += 4) {
        *reinterpret_cast<float4*>(st_prod + s0 + n) =
            make_float4(exp2f(A2[n] * S), exp2f(A2[n + 1] * S),
                        exp2f(A2[n + 2] * S), exp2f(A2[n + 3] * S));
        *reinterpret_cast<float4*>(st_hend + s0 + n) =
            make_float4(hs[n], hs[n + 1], hs[n + 2], hs[n + 3]);
    }
}

__launch_bounds__(256)
__global__ void scan_combine(float* __restrict__ st_prod,
                             const float* __restrict__ st_hend) {
    const int s = blockIdx.x * 256 + threadIdx.x;
    float H = 0.f;
#pragma unroll 8
    for (int k = 0; k < NC_; ++k) {
        const size_t o = (size_t)k * NSEQ_ + s;
        const float Pv = st_prod[o];
        const float Ev = st_hend[o];
        st_prod[o] = H;
        H = fmaf(Pv, H, Ev);
    }
}

__launch_bounds__(256)
__global__ void scan_chunk_out(const __hip_bfloat16* __restrict__ xi,
                               const __hip_bfloat16* __restrict__ z,
                               const float* __restrict__ proj,
                               const float* __restrict__ A_log,
                               const float* __restrict__ D_skip,
                               const float* __restrict__ st_hin,
                               __hip_bfloat16* __restrict__ yg) {
    __shared__ float bc[4][CL_][32];   // 16 KB: per-wave B|C cache
    const int bh = blockIdx.x;
    const int b = bh >> 3;
    const int h = bh & 7;
    const int lane = threadIdx.x & 63;
    const int wave = threadIdx.x >> 6;
    const int chunk = blockIdx.y * 4 + wave;
    const int t0 = chunk * CL_;
    const int c = h * P_ + lane;
    const int bOff = DI_ + h * N_;
    const int cOff = DI_ + H_ * N_ + h * N_;

    {
        const int seg = lane >> 2;
        const int off4 = (lane & 3) * 4;
        const float* rowb = proj + ((size_t)b * L_ + t0) * PROJ_;
#pragma unroll
        for (int r = 0; r < 4; ++r) {
            const int s = r * 16 + seg;
            const int stp = s >> 1;
            const int half = s & 1;
            cp16f_lds(rowb + (size_t)stp * PROJ_ + (half ? cOff : bOff) + off4,
                      &bc[wave][0][0] + r * 256);
        }
    }

    float A2[N_], hs[N_];
    const size_t s0 = (size_t)chunk * NSEQ_ + ((size_t)(bh * P_ + lane)) * N_;
#pragma unroll
    for (int n = 0; n < N_; n += 4) {
        const float4 h4 = *reinterpret_cast<const float4*>(st_hin + s0 + n);
        hs[n] = h4.x; hs[n + 1] = h4.y; hs[n + 2] = h4.z; hs[n + 3] = h4.w;
    }
#pragma unroll
    for (int n = 0; n < N_; ++n)
        A2[n] = -__expf(A_log[c * N_ + n]) * LOG2E_;
    const bool fast = a_is_arith(A2);
    const float Dv = D_skip[c];
    __syncthreads();

    const float* pDt = proj + ((size_t)b * L_ + t0) * PROJ_ + c;
    const __hip_bfloat16* px = xi + ((size_t)b * L_ + t0) * DI_ + c;
    const __hip_bfloat16* pz = z + ((size_t)b * L_ + t0) * DI_ + c;
    __hip_bfloat16* py = yg + ((size_t)b * L_ + t0) * DI_ + c;

    if (fast) {
        float dtb[2][4], xb[2][4], zb[2][4];
#pragma unroll
        for (int i = 0; i < 4; ++i) {
            dtb[0][i] = pDt[(size_t)i * PROJ_];
            xb[0][i] = __bfloat162float(px[(size_t)i * DI_]);
            zb[0][i] = __bfloat162float(pz[(size_t)i * DI_]);
        }
#pragma unroll
        for (int k = 0; k < CL_ / 4; ++k) {
            const int cur = k & 1, nxt = cur ^ 1;
            if (k + 1 < CL_ / 4) {
#pragma unroll
                for (int i = 0; i < 4; ++i) {
                    const int t = (k + 1) * 4 + i;
                    dtb[nxt][i] = pDt[(size_t)t * PROJ_];
                    xb[nxt][i] = __bfloat162float(px[(size_t)t * DI_]);
                    zb[nxt][i] = __bfloat162float(pz[(size_t)t * DI_]);
                }
            }
#pragma unroll
            for (int i = 0; i < 4; ++i) {
                const int t = k * 4 + i;
                const float dt_v = dtb[cur][i];
                const float xv = xb[cur][i];
                const float zv = zb[cur][i];
                const float dtx = dt_v * xv;
                const float e1 = exp2f(dt_v * A2[0]);
                const f32x4* bp = reinterpret_cast<const f32x4*>(&bc[wave][t][0]);
                float dA = e1;
                float y = 0.f;
#pragma unroll
                for (int q = 0; q < 4; ++q) {
                    const f32x4 Bq = bp[q];
                    const f32x4 Cq = bp[4 + q];
#pragma unroll
                    for (int j = 0; j < 4; ++j) {
                        hs[q * 4 + j] = fmaf(hs[q * 4 + j], dA, dtx * Bq[j]);
                        y = fmaf(hs[q * 4 + j], Cq[j], y);
                        dA *= e1;
                    }
                }
                const float g = zv / (1.f + __expf(-zv));
                py[(size_t)t * DI_] = __float2bfloat16((y + Dv * xv) * g);
            }
        }
    } else {
#pragma unroll 4
        for (int t = 0; t < CL_; ++t) {
            const float dt_v = pDt[(size_t)t * PROJ_];
            const float xv = __bfloat162float(px[(size_t)t * DI_]);
            const float zv = __bfloat162float(pz[(size_t)t * DI_]);
            const float dtx = dt_v * xv;
            float y = 0.f;
#pragma unroll
            for (int n = 0; n < N_; ++n) {
                const float dA = exp2f(dt_v * A2[n]);
                hs[n] = fmaf(hs[n], dA, dtx * bc[wave][t][n]);
                y = fmaf(hs[n], bc[wave][t][16 + n], y);
            }
            const float g = zv / (1.f + __expf(-zv));
            py[(size_t)t * DI_] = __float2bfloat16((y + Dv * xv) * g);
        }
    }
}

// ---------------- host launcher --------------------------------------------
extern "C" void kernel_launch(void* const* d_in, const int* in_sizes, int n_in,
                              void* d_out, int out_size, void* d_ws, size_t ws_size,
                              hipStream_t stream) {
    const float* inputs = (const float*)d_in[0];
    const float* f_in_w = (const float*)d_in[1];
    const float* f_in_b = (const float*)d_in[2];
    const float* f_xp_w = (const float*)d_in[3];
    const float* f_xp_b = (const float*)d_in[4];
    const float* f_dt_b = (const float*)d_in[5];
    const float* f_A = (const float*)d_in[6];
    const float* f_D = (const float*)d_in[7];
    const float* f_out_w = (const float*)d_in[8];
    const float* f_out_b = (const float*)d_in[9];
    const float* b_in_w = (const float*)d_in[10];
    const float* b_in_b = (const float*)d_in[11];
    const float* b_xp_w = (const float*)d_in[12];
    const float* b_xp_b = (const float*)d_in[13];
    const float* b_dt_b = (const float*)d_in[14];
    const float* b_A = (const float*)d_in[15];
    const float* b_D = (const float*)d_in[16];
    const float* b_out_w = (const float*)d_in[17];
    const float* b_out_b = (const float*)d_in[18];
    const float* norm_w = (const float*)d_in[19];
    const float* norm_b = (const float*)d_in[20];
    const float* conv_w = (const float*)d_in[21];
    const float* conv_b = (const float*)d_in[22];
    float* out = (float*)d_out;

    // workspace layout (unchanged from R9)
    float* ws = (float*)d_ws;
    float* st_prod = ws;                                  // 4,194,304 f
    float* st_hend = st_prod + (size_t)NSEQ_ * NC_;       // 4,194,304 f
    float* zslot   = st_hend + (size_t)NSEQ_ * NC_;       // 8,388,608 f slot
    __hip_bfloat16* z_bf = (__hip_bfloat16*)zslot;        // uses half the slot
    float* proj    = zslot + (size_t)M_ * DI_;            // 12,582,912 f
    float* y1      = proj + (size_t)M_ * PROJ_;           // (unused slot, kept)
    __hip_bfloat16* xi_bf = (__hip_bfloat16*)(y1 + (size_t)M_ * D_);   // 8,388,608 bf16
    __hip_bfloat16* yg_bf = xi_bf + (size_t)M_ * DI_;                  // 8,388,608 bf16
    __hip_bfloat16* a_bf  = yg_bf + (size_t)M_ * DI_;                  // 4,194,304 bf16
    __hip_bfloat16* wpool = a_bf + (size_t)M_ * D_;
    __hip_bfloat16* f_in_wb  = wpool;
    __hip_bfloat16* f_xp_wb  = f_in_wb + 2 * DI_ * D_;
    __hip_bfloat16* f_out_wb = f_xp_wb + PROJ_ * DI_;
    __hip_bfloat16* b_in_wb  = f_out_wb + D_ * DI_;
    __hip_bfloat16* b_xp_wb  = b_in_wb + 2 * DI_ * D_;
    __hip_bfloat16* b_out_wb = b_xp_wb + PROJ_ * DI_;

    const dim3 blk(256);
    const dim3 g_in(M_ / 128, (2 * DI_) / 128);   // (128,8)
    const dim3 g_xp(M_ / 128, PROJ_ / 128);       // (128,6)
    const dim3 g_out64(M_ / 64, D_ / 64);         // (256,4) bwd out_proj
    const dim3 g_oln(M_ / 16);                    // 1024 blocks fwd out_proj+LN
    const dim3 g_chunk(B_ * H_, NC_ / 4);         // (32,32)
    const dim3 g_comb(NSEQ_ / 256);               // 128 blocks

    // ---- fused fp32 -> bf16 conversions ----
    f2b_all<<<dim3(4096), blk, 0, stream>>>(inputs, f_in_w, f_xp_w, f_out_w,
                                            b_in_w, b_xp_w, b_out_w,
                                            a_bf, f_in_wb, f_xp_wb, f_out_wb,
                                            b_in_wb, b_xp_wb, b_out_wb);

    // ---- forward pass ----
    gemm_mfma<1><<<g_in, blk, 0, stream>>>(a_bf, f_in_wb, f_in_b, D_,
                                           nullptr, z_bf, xi_bf, nullptr);
    gemm_mfma<2><<<g_xp, blk, 0, stream>>>(xi_bf, f_xp_wb, f_xp_b, DI_,
                                           proj, nullptr, nullptr, f_dt_b);
    scan_chunk_state<<<g_chunk, blk, 0, stream>>>(xi_bf, proj, f_A, st_prod, st_hend);
    scan_combine<<<g_comb, blk, 0, stream>>>(st_prod, st_hend);
    scan_chunk_out<<<g_chunk, blk, 0, stream>>>(xi_bf, z_bf, proj, f_A, f_D,
                                                st_prod, yg_bf);
    gemm_out_ln<<<g_oln, blk, 0, stream>>>(yg_bf, f_out_wb, f_out_b,
                                           norm_w, norm_b, a_bf);

    // ---- backward pass ----
    gemm_mfma<1><<<g_in, blk, 0, stream>>>(a_bf, b_in_wb, b_in_b, D_,
                                           nullptr, z_bf, xi_bf, nullptr);
    gemm_mfma<2><<<g_xp, blk, 0, stream>>>(xi_bf, b_xp_wb, b_xp_b, DI_,
                                           proj, nullptr, nullptr, b_dt_b);
    scan_chunk_state<<<g_chunk, blk, 0, stream>>>(xi_bf, proj, b_A, st_prod, st_hend);
    scan_combine<<<g_comb, blk, 0, stream>>>(st_prod, st_hend);
    scan_chunk_out<<<g_chunk, blk, 0, stream>>>(xi_bf, z_bf, proj, b_A, b_D,
                                                st_prod, yg_bf);
    // final out_proj with flipped store + fused conv3+GELU, 64x64 tiles
    gemm64_convout<<<g_out64, blk, 0, stream>>>(yg_bf, b_out_wb, b_out_b, DI_,
                                                out, conv_w, conv_b, inputs);
}

// Round 11
// 388.007 us; speedup vs baseline: 10.9511x; 1.0008x over previous
//
#include <hip/hip_runtime.h>
#include <hip/hip_bf16.h>
#include <cstdint>
#include <cstddef>

// ---------------- problem constants ----------------
#define B_  4
#define L_  4096
#define D_  256
#define DI_ 512
#define H_  8
#define P_  64
#define N_  16
#define M_  (B_ * L_)              // 16384 rows
#define PROJ_ (DI_ + 2 * H_ * N_)  // 768

// chunked scan parameters (1 thread = 1 (b,h,p) channel, 16 states)
#define NC_ 128                    // chunks along L
#define CL_ (L_ / NC_)             // 32
#define NSEQ_ (B_ * H_ * P_ * N_)  // 32768 scalar sequences
#define LOG2E_ 1.4426950408889634f

typedef __bf16 bf16x8 __attribute__((ext_vector_type(8)));
typedef float f32x4 __attribute__((ext_vector_type(4)));

__device__ __forceinline__ void cp16_lds(const __hip_bfloat16* g, short* lds) {
    __builtin_amdgcn_global_load_lds(
        (const __attribute__((address_space(1))) void*)g,
        (__attribute__((address_space(3))) void*)lds, 16, 0, 0);
}

// ---------------- fused fp32 -> bf16 conversion (7 segments) -----------------
#define FS0 (M_ * D_)          // inputs      4194304
#define FS1 (2 * DI_ * D_)     // in_proj_w    262144
#define FS2 (PROJ_ * DI_)      // x_proj_w     393216
#define FS3 (D_ * DI_)         // out_proj_w   131072
#define FC1 (FS0 + FS1)
#define FC2 (FC1 + FS2)
#define FC3 (FC2 + FS3)
#define FC4 (FC3 + FS1)
#define FC5 (FC4 + FS2)
#define FC6 (FC5 + FS3)

__launch_bounds__(256)
__global__ void f2b_all(const float* __restrict__ i0, const float* __restrict__ i1,
                        const float* __restrict__ i2, const float* __restrict__ i3,
                        const float* __restrict__ i4, const float* __restrict__ i5,
                        const float* __restrict__ i6,
                        __hip_bfloat16* o0, __hip_bfloat16* o1, __hip_bfloat16* o2,
                        __hip_bfloat16* o3, __hip_bfloat16* o4, __hip_bfloat16* o5,
                        __hip_bfloat16* o6) {
    for (int idx = blockIdx.x * 256 + threadIdx.x; idx < FC6; idx += gridDim.x * 256) {
        const float* s; __hip_bfloat16* d; int off;
        if (idx < FS0)      { s = i0; d = o0; off = idx; }
        else if (idx < FC1) { s = i1; d = o1; off = idx - FS0; }
        else if (idx < FC2) { s = i2; d = o2; off = idx - FC1; }
        else if (idx < FC3) { s = i3; d = o3; off = idx - FC2; }
        else if (idx < FC4) { s = i4; d = o4; off = idx - FC3; }
        else if (idx < FC5) { s = i5; d = o5; off = idx - FC4; }
        else                { s = i6; d = o6; off = idx - FC5; }
        d[off] = __float2bfloat16(s[off]);
    }
}

// ---------------- MFMA bf16 GEMM 128x128: C = A * W^T + bias -----------------
// BK=64, XOR-swizzled LDS -> conflict-free ds_read_b128.
// EPI 1: in_proj: col<DI -> silu -> obf bf16 (xi, ld 512); else z bf16 (zb)
// EPI 2: x_proj: col<DI -> softplus(v+aux); bf16 store to obf (ld 768)
template <int EPI>
__launch_bounds__(256)
__global__ void gemm_mfma(const __hip_bfloat16* __restrict__ A,
                          const __hip_bfloat16* __restrict__ W,
                          const float* __restrict__ bias, int Kv,
                          __hip_bfloat16* __restrict__ zb,
                          __hip_bfloat16* __restrict__ obf,
                          const float* __restrict__ aux) {
    __shared__ short As[128 * 64];   // 16 KB
    __shared__ short Bs[128 * 64];   // 16 KB
    const int tid = threadIdx.x;
    const int lane = tid & 63;
    const int wave = tid >> 6;
    const int bm = blockIdx.x * 128;
    const int bn = blockIdx.y * 128;
    const int wm = (wave >> 1) * 64;
    const int wn = (wave & 1) * 64;

    f32x4 acc[4][4];
#pragma unroll
    for (int i = 0; i < 4; ++i)
#pragma unroll
        for (int j = 0; j < 4; ++j) acc[i][j] = (f32x4)0.f;

    const int srow = lane >> 3;                       // 0..7
    const int ssegx = ((lane & 7) ^ srow) * 8;        // swizzled k offset (shorts)
    const __hip_bfloat16* gA0 = A + (size_t)(bm + wave * 32 + srow) * Kv + ssegx;
    const __hip_bfloat16* gB0 = W + (size_t)(bn + wave * 32 + srow) * Kv + ssegx;
    short* lA0 = As + (wave * 32) * 64;
    short* lB0 = Bs + (wave * 32) * 64;

    const int fr = lane & 15;        // fragment row within 16
    const int kq = lane >> 4;        // k-quarter 0..3

    for (int k0 = 0; k0 < Kv; k0 += 64) {
#pragma unroll
        for (int rb = 0; rb < 4; ++rb) {
            cp16_lds(gA0 + (size_t)(rb * 8) * Kv + k0, lA0 + rb * 8 * 64);
            cp16_lds(gB0 + (size_t)(rb * 8) * Kv + k0, lB0 + rb * 8 * 64);
        }
        __syncthreads();
#pragma unroll
        for (int ks = 0; ks < 2; ++ks) {
            const int kgg = ks * 4 + kq;                       // 0..7
            const int kslot = (kgg ^ (fr & 7)) * 8;            // un-swizzle
            bf16x8 af[4], bv[4];
#pragma unroll
            for (int i = 0; i < 4; ++i)
                af[i] = *reinterpret_cast<const bf16x8*>(
                    &As[(wm + i * 16 + fr) * 64 + kslot]);
#pragma unroll
            for (int j = 0; j < 4; ++j)
                bv[j] = *reinterpret_cast<const bf16x8*>(
                    &Bs[(wn + j * 16 + fr) * 64 + kslot]);
#pragma unroll
            for (int i = 0; i < 4; ++i)
#pragma unroll
                for (int j = 0; j < 4; ++j)
                    acc[i][j] = __builtin_amdgcn_mfma_f32_16x16x32_bf16(
                        af[i], bv[j], acc[i][j], 0, 0, 0);
        }
        __syncthreads();
    }

    const int n16 = lane & 15;
    const int r4 = (lane >> 4) * 4;
#pragma unroll
    for (int i = 0; i < 4; ++i) {
#pragma unroll
        for (int j = 0; j < 4; ++j) {
            const int cg = bn + wn + j * 16 + n16;
            const float bb = bias[cg];
#pragma unroll
            for (int v = 0; v < 4; ++v) {
                const int r = bm + wm + i * 16 + r4 + v;
                float val = acc[i][j][v] + bb;
                if (EPI == 1) {
                    if (cg < DI_) {
                        val = val / (1.f + __expf(-val));
                        obf[(size_t)r * DI_ + cg] = __float2bfloat16(val);
                    } else {
                        zb[(size_t)r * DI_ + cg - DI_] = __float2bfloat16(val);
                    }
                } else {  // EPI 2: all-bf16 proj store
                    if (cg < DI_) {
                        const float x = val + aux[cg];
                        val = (x > 20.f) ? x : __logf(1.f + __expf(x));
                    }
                    obf[(size_t)r * PROJ_ + cg] = __float2bfloat16(val);
                }
            }
        }
    }
}

// ---------------- small-tile GEMM 64x64: bwd out_proj + conv/GELU ------------
__launch_bounds__(256)
__global__ void gemm64_convout(const __hip_bfloat16* __restrict__ A,
                               const __hip_bfloat16* __restrict__ W,
                               const float* __restrict__ bias, int Kv,
                               float* __restrict__ out0,
                               const float* __restrict__ cw,
                               const float* __restrict__ cb,
                               const float* __restrict__ cinp) {
    __shared__ short As[64 * 64];    // 8 KB
    __shared__ short Bs[64 * 64];    // 8 KB
    const int tid = threadIdx.x;
    const int lane = tid & 63;
    const int wave = tid >> 6;
    const int bm = blockIdx.x * 64;
    const int bn = blockIdx.y * 64;
    const int wm = (wave >> 1) * 32;
    const int wn = (wave & 1) * 32;

    f32x4 acc[2][2];
#pragma unroll
    for (int i = 0; i < 2; ++i)
#pragma unroll
        for (int j = 0; j < 2; ++j) acc[i][j] = (f32x4)0.f;

    const int srow = lane >> 3;
    const int ssegx = ((lane & 7) ^ srow) * 8;
    const __hip_bfloat16* gA0 = A + (size_t)(bm + wave * 16 + srow) * Kv + ssegx;
    const __hip_bfloat16* gB0 = W + (size_t)(bn + wave * 16 + srow) * Kv + ssegx;
    short* lA0 = As + (wave * 16) * 64;
    short* lB0 = Bs + (wave * 16) * 64;

    const int fr = lane & 15;
    const int kq = lane >> 4;

    for (int k0 = 0; k0 < Kv; k0 += 64) {
#pragma unroll
        for (int rb = 0; rb < 2; ++rb) {
            cp16_lds(gA0 + (size_t)(rb * 8) * Kv + k0, lA0 + rb * 8 * 64);
            cp16_lds(gB0 + (size_t)(rb * 8) * Kv + k0, lB0 + rb * 8 * 64);
        }
        __syncthreads();
#pragma unroll
        for (int ks = 0; ks < 2; ++ks) {
            const int kgg = ks * 4 + kq;
            const int kslot = (kgg ^ (fr & 7)) * 8;
            bf16x8 af[2], bv[2];
#pragma unroll
            for (int i = 0; i < 2; ++i)
                af[i] = *reinterpret_cast<const bf16x8*>(
                    &As[(wm + i * 16 + fr) * 64 + kslot]);
#pragma unroll
            for (int j = 0; j < 2; ++j)
                bv[j] = *reinterpret_cast<const bf16x8*>(
                    &Bs[(wn + j * 16 + fr) * 64 + kslot]);
#pragma unroll
            for (int i = 0; i < 2; ++i)
#pragma unroll
                for (int j = 0; j < 2; ++j)
                    acc[i][j] = __builtin_amdgcn_mfma_f32_16x16x32_bf16(
                        af[i], bv[j], acc[i][j], 0, 0, 0);
        }
        __syncthreads();
    }

    const int n16 = lane & 15;
    const int r4 = (lane >> 4) * 4;
#pragma unroll
    for (int i = 0; i < 2; ++i) {
#pragma unroll
        for (int j = 0; j < 2; ++j) {
            const int cg = bn + wn + j * 16 + n16;
            const float bb = bias[cg];
#pragma unroll
            for (int v = 0; v < 4; ++v) {
                const int r = bm + wm + i * 16 + r4 + v;
                float val = acc[i][j][v] + bb;
                const int b = r >> 12;
                const int l = r & (L_ - 1);
                const int lo = L_ - 1 - l;
                const size_t base = ((size_t)(b << 12) + lo) * 256 + cg;
                float cv = fmaf(cinp[base], cw[cg * 3 + 1], cb[cg]);
                if (lo > 0) cv = fmaf(cinp[base - 256], cw[cg * 3 + 0], cv);
                if (lo + 1 < L_) cv = fmaf(cinp[base + 256], cw[cg * 3 + 2], cv);
                const float g = 0.5f * cv * (1.f + erff(cv * 0.70710678118654752f));
                out0[base] = val + g;
            }
        }
    }
}

// ---------------- fwd out_proj + LayerNorm + flip, 16-row tiles --------------
__launch_bounds__(256)
__global__ void gemm_out_ln(const __hip_bfloat16* __restrict__ A,
                            const __hip_bfloat16* __restrict__ W,
                            const float* __restrict__ bias,
                            const float* __restrict__ lnw,
                            const float* __restrict__ lnb,
                            __hip_bfloat16* __restrict__ outb) {
    __shared__ short As[16 * 64];     // 2 KB
    __shared__ short Ws[256 * 64];    // 32 KB
    __shared__ float rs[2][4][16];    // 512 B row partial sums
    const int tid = threadIdx.x;
    const int lane = tid & 63;
    const int wave = tid >> 6;
    const int bm = blockIdx.x * 16;
    const int Kv = DI_;

    f32x4 acc[4];
#pragma unroll
    for (int j = 0; j < 4; ++j) acc[j] = (f32x4)0.f;

    const int srow = lane >> 3;
    const int ssegx = ((lane & 7) ^ srow) * 8;
    const __hip_bfloat16* gA0 = A + (size_t)(bm + wave * 8 + srow) * Kv + ssegx;
    const __hip_bfloat16* gW0 = W + (size_t)(wave * 64 + srow) * Kv + ssegx;
    short* lA0 = As + (wave * 8) * 64;
    short* lW0 = Ws + (wave * 64) * 64;

    const int fr = lane & 15;
    const int kq = lane >> 4;

    for (int k0 = 0; k0 < Kv; k0 += 64) {
        if (wave < 2) cp16_lds(gA0 + k0, lA0);
#pragma unroll
        for (int rb = 0; rb < 8; ++rb)
            cp16_lds(gW0 + (size_t)(rb * 8) * Kv + k0, lW0 + rb * 8 * 64);
        __syncthreads();
#pragma unroll
        for (int ks = 0; ks < 2; ++ks) {
            const int kgg = ks * 4 + kq;
            const int kslot = (kgg ^ (fr & 7)) * 8;
            const bf16x8 af = *reinterpret_cast<const bf16x8*>(
                &As[fr * 64 + kslot]);
#pragma unroll
            for (int j = 0; j < 4; ++j) {
                const bf16x8 bv = *reinterpret_cast<const bf16x8*>(
                    &Ws[(wave * 64 + j * 16 + fr) * 64 + kslot]);
                acc[j] = __builtin_amdgcn_mfma_f32_16x16x32_bf16(
                    af, bv, acc[j], 0, 0, 0);
            }
        }
        __syncthreads();
    }

    const int n16 = lane & 15;
    const int r4 = (lane >> 4) * 4;
    float vals[4][4];
#pragma unroll
    for (int j = 0; j < 4; ++j) {
        const float bb = bias[wave * 64 + j * 16 + n16];
#pragma unroll
        for (int v = 0; v < 4; ++v) vals[j][v] = acc[j][v] + bb;
    }

#pragma unroll
    for (int v = 0; v < 4; ++v) {
        float s = 0.f, s2 = 0.f;
#pragma unroll
        for (int j = 0; j < 4; ++j) {
            const float t = vals[j][v];
            s += t; s2 = fmaf(t, t, s2);
        }
        s += __shfl_xor(s, 1); s2 += __shfl_xor(s2, 1);
        s += __shfl_xor(s, 2); s2 += __shfl_xor(s2, 2);
        s += __shfl_xor(s, 4); s2 += __shfl_xor(s2, 4);
        s += __shfl_xor(s, 8); s2 += __shfl_xor(s2, 8);
        if (n16 == 0) {
            rs[0][wave][r4 + v] = s;
            rs[1][wave][r4 + v] = s2;
        }
    }
    __syncthreads();

#pragma unroll
    for (int v = 0; v < 4; ++v) {
        const int row = r4 + v;
        const float ts = rs[0][0][row] + rs[0][1][row] + rs[0][2][row] + rs[0][3][row];
        const float ts2 = rs[1][0][row] + rs[1][1][row] + rs[1][2][row] + rs[1][3][row];
        const float mean = ts * (1.f / 256.f);
        const float var = ts2 * (1.f / 256.f) - mean * mean;
        const float inv = rsqrtf(var + 1e-5f);
        const int rg = bm + row;
        const int b = rg >> 12;
        const int l = rg & (L_ - 1);
        const size_t drow = (size_t)((b << 12) + (L_ - 1 - l)) * 256;
#pragma unroll
        for (int j = 0; j < 4; ++j) {
            const int cg = wave * 64 + j * 16 + n16;
            const float o = (vals[j][v] - mean) * inv * lnw[cg] + lnb[cg];
            outb[drow + cg] = __float2bfloat16(o);
        }
    }
}

// ---------------- chunked selective scan, all-bf16 proj ----------------------
// B/C register-staged bf16 -> fp32 LDS (per-wave region: no barrier needed);
// dt read as bf16 scalars. Inner loop unchanged (fp32 ds_read_b128).
__device__ __forceinline__ bool a_is_arith(const float* A2) {
    bool ok = true;
#pragma unroll
    for (int n = 1; n < N_; ++n)
        ok = ok && (fabsf(A2[n] - (float)(n + 1) * A2[0]) <= 1e-4f * fabsf(A2[n]));
    return ok;
}

__launch_bounds__(256)
__global__ void scan_chunk_state(const __hip_bfloat16* __restrict__ xi,
                                 const __hip_bfloat16* __restrict__ projb,
                                 const float* __restrict__ A_log,
                                 float* __restrict__ st_prod,
                                 float* __restrict__ st_hend) {
    __shared__ float bsh[4][CL_][16];   // 8 KB: per-wave B cache
    const int bh = blockIdx.x;
    const int b = bh >> 3;
    const int h = bh & 7;
    const int lane = threadIdx.x & 63;
    const int wave = threadIdx.x >> 6;
    const int chunk = blockIdx.y * 4 + wave;
    const int t0 = chunk * CL_;
    const int c = h * P_ + lane;
    const int bOff = DI_ + h * N_;

    // register-stage B (bf16 -> fp32 LDS), per-wave region
    {
        const int stp = lane >> 1;            // 0..31
        const int half = (lane & 1) * 8;
        const __hip_bfloat16* src =
            projb + ((size_t)b * L_ + t0 + stp) * PROJ_ + bOff + half;
        const bf16x8 v = *reinterpret_cast<const bf16x8*>(src);
        float4* dst = reinterpret_cast<float4*>(&bsh[wave][stp][half]);
        dst[0] = make_float4((float)v[0], (float)v[1], (float)v[2], (float)v[3]);
        dst[1] = make_float4((float)v[4], (float)v[5], (float)v[6], (float)v[7]);
    }

    float A2[N_], hs[N_];
#pragma unroll
    for (int n = 0; n < N_; ++n) {
        A2[n] = -__expf(A_log[c * N_ + n]) * LOG2E_;
        hs[n] = 0.f;
    }
    const bool fast = a_is_arith(A2);

    const __hip_bfloat16* pDt = projb + ((size_t)b * L_ + t0) * PROJ_ + c;
    const __hip_bfloat16* px = xi + ((size_t)b * L_ + t0) * DI_ + c;
    float S = 0.f;

    if (fast) {
        float dtb[2][4], xb[2][4];
#pragma unroll
        for (int i = 0; i < 4; ++i) {
            dtb[0][i] = __bfloat162float(pDt[(size_t)i * PROJ_]);
            xb[0][i] = __bfloat162float(px[(size_t)i * DI_]);
        }
#pragma unroll
        for (int k = 0; k < CL_ / 4; ++k) {
            const int cur = k & 1, nxt = cur ^ 1;
            if (k + 1 < CL_ / 4) {
#pragma unroll
                for (int i = 0; i < 4; ++i) {
                    dtb[nxt][i] = __bfloat162float(pDt[(size_t)((k + 1) * 4 + i) * PROJ_]);
                    xb[nxt][i] = __bfloat162float(px[(size_t)((k + 1) * 4 + i) * DI_]);
                }
            }
#pragma unroll
            for (int i = 0; i < 4; ++i) {
                const int t = k * 4 + i;
                const float dt_v = dtb[cur][i];
                const float dtx = dt_v * xb[cur][i];
                const float e1 = exp2f(dt_v * A2[0]);
                S += dt_v;
                const f32x4* bp = reinterpret_cast<const f32x4*>(&bsh[wave][t][0]);
                float dA = e1;
#pragma unroll
                for (int q = 0; q < 4; ++q) {
                    const f32x4 Bq = bp[q];
#pragma unroll
                    for (int j = 0; j < 4; ++j) {
                        hs[q * 4 + j] = fmaf(hs[q * 4 + j], dA, dtx * Bq[j]);
                        dA *= e1;
                    }
                }
            }
        }
    } else {
#pragma unroll 4
        for (int t = 0; t < CL_; ++t) {
            const float dt_v = __bfloat162float(pDt[(size_t)t * PROJ_]);
            const float xv = __bfloat162float(px[(size_t)t * DI_]);
            const float dtx = dt_v * xv;
            S += dt_v;
#pragma unroll
            for (int n = 0; n < N_; ++n) {
                const float dA = exp2f(dt_v * A2[n]);
                hs[n] = fmaf(hs[n], dA, dtx * bsh[wave][t][n]);
            }
        }
    }

    const size_t s0 = (size_t)chunk * NSEQ_ + ((size_t)(bh * P_ + lane)) * N_;
#pragma unroll
    for (int n = 0; n < N_; n += 4) {
        *reinterpret_cast<float4*>(st_prod + s0 + n) =
            make_float4(exp2f(A2[n] * S), exp2f(A2[n + 1] * S),
                        exp2f(A2[n + 2] * S), exp2f(A2[n + 3] * S));
        *reinterpret_cast<float4*>(st_hend + s0 + n) =
            make_float4(hs[n], hs[n + 1], hs[n + 2], hs[n + 3]);
    }
}

__launch_bounds__(256)
__global__ void scan_combine(float* __restrict__ st_prod,
                             const float* __restrict__ st_hend) {
    const int s = blockIdx.x * 256 + threadIdx.x;
    float H = 0.f;
#pragma unroll 8
    for (int k = 0; k < NC_; ++k) {
        const size_t o = (size_t)k * NSEQ_ + s;
        const float Pv = st_prod[o];
        const float Ev = st_hend[o];
        st_prod[o] = H;
        H = fmaf(Pv, H, Ev);
    }
}

__launch_bounds__(256)
__global__ void scan_chunk_out(const __hip_bfloat16* __restrict__ xi,
                               const __hip_bfloat16* __restrict__ z,
                               const __hip_bfloat16* __restrict__ projb,
                               const float* __restrict__ A_log,
                               const float* __restrict__ D_skip,
                               const float* __restrict__ st_hin,
                               __hip_bfloat16* __restrict__ yg) {
    __shared__ float bc[4][CL_][32];   // 16 KB: per-wave B|C cache
    const int bh = blockIdx.x;
    const int b = bh >> 3;
    const int h = bh & 7;
    const int lane = threadIdx.x & 63;
    const int wave = threadIdx.x >> 6;
    const int chunk = blockIdx.y * 4 + wave;
    const int t0 = chunk * CL_;
    const int c = h * P_ + lane;
    const int bOff = DI_ + h * N_;
    const int cOff = DI_ + H_ * N_ + h * N_;

    // register-stage B and C (bf16 -> fp32 LDS), per-wave region
    {
#pragma unroll
        for (int r = 0; r < 2; ++r) {
            const int g = r * 64 + lane;     // 0..127 groups of 8 values
            const int stp = g >> 2;
            const int q = g & 3;             // 0,1: B halves; 2,3: C halves
            const int soff = (q < 2) ? (bOff + q * 8) : (cOff + (q - 2) * 8);
            const __hip_bfloat16* src =
                projb + ((size_t)b * L_ + t0 + stp) * PROJ_ + soff;
            const bf16x8 v = *reinterpret_cast<const bf16x8*>(src);
            float4* dst = reinterpret_cast<float4*>(&bc[wave][stp][q * 8]);
            dst[0] = make_float4((float)v[0], (float)v[1], (float)v[2], (float)v[3]);
            dst[1] = make_float4((float)v[4], (float)v[5], (float)v[6], (float)v[7]);
        }
    }

    float A2[N_], hs[N_];
    const size_t s0 = (size_t)chunk * NSEQ_ + ((size_t)(bh * P_ + lane)) * N_;
#pragma unroll
    for (int n = 0; n < N_; n += 4) {
        const float4 h4 = *reinterpret_cast<const float4*>(st_hin + s0 + n);
        hs[n] = h4.x; hs[n + 1] = h4.y; hs[n + 2] = h4.z; hs[n + 3] = h4.w;
    }
#pragma unroll
    for (int n = 0; n < N_; ++n)
        A2[n] = -__expf(A_log[c * N_ + n]) * LOG2E_;
    const bool fast = a_is_arith(A2);
    const float Dv = D_skip[c];

    const __hip_bfloat16* pDt = projb + ((size_t)b * L_ + t0) * PROJ_ + c;
    const __hip_bfloat16* px = xi + ((size_t)b * L_ + t0) * DI_ + c;
    const __hip_bfloat16* pz = z + ((size_t)b * L_ + t0) * DI_ + c;
    __hip_bfloat16* py = yg + ((size_t)b * L_ + t0) * DI_ + c;

    if (fast) {
        float dtb[2][4], xb[2][4], zb[2][4];
#pragma unroll
        for (int i = 0; i < 4; ++i) {
            dtb[0][i] = __bfloat162float(pDt[(size_t)i * PROJ_]);
            xb[0][i] = __bfloat162float(px[(size_t)i * DI_]);
            zb[0][i] = __bfloat162float(pz[(size_t)i * DI_]);
        }
#pragma unroll
        for (int k = 0; k < CL_ / 4; ++k) {
            const int cur = k & 1, nxt = cur ^ 1;
            if (k + 1 < CL_ / 4) {
#pragma unroll
                for (int i = 0; i < 4; ++i) {
                    const int t = (k + 1) * 4 + i;
                    dtb[nxt][i] = __bfloat162float(pDt[(size_t)t * PROJ_]);
                    xb[nxt][i] = __bfloat162float(px[(size_t)t * DI_]);
                    zb[nxt][i] = __bfloat162float(pz[(size_t)t * DI_]);
                }
            }
#pragma unroll
            for (int i = 0; i < 4; ++i) {
                const int t = k * 4 + i;
                const float dt_v = dtb[cur][i];
                const float xv = xb[cur][i];
                const float zv = zb[cur][i];
                const float dtx = dt_v * xv;
                const float e1 = exp2f(dt_v * A2[0]);
                const f32x4* bp = reinterpret_cast<const f32x4*>(&bc[wave][t][0]);
                float dA = e1;
                float y = 0.f;
#pragma unroll
                for (int q = 0; q < 4; ++q) {
                    const f32x4 Bq = bp[q];
                    const f32x4 Cq = bp[4 + q];
#pragma unroll
                    for (int j = 0; j < 4; ++j) {
                        hs[q * 4 + j] = fmaf(hs[q * 4 + j], dA, dtx * Bq[j]);
                        y = fmaf(hs[q * 4 + j], Cq[j], y);
                        dA *= e1;
                    }
                }
                const float g = zv / (1.f + __expf(-zv));
                py[(size_t)t * DI_] = __float2bfloat16((y + Dv * xv) * g);
            }
        }
    } else {
#pragma unroll 4
        for (int t = 0; t < CL_; ++t) {
            const float dt_v = __bfloat162float(pDt[(size_t)t * PROJ_]);
            const float xv = __bfloat162float(px[(size_t)t * DI_]);
            const float zv = __bfloat162float(pz[(size_t)t * DI_]);
            const float dtx = dt_v * xv;
            float y = 0.f;
#pragma unroll
            for (int n = 0; n < N_; ++n) {
                const float dA = exp2f(dt_v * A2[n]);
                hs[n] = fmaf(hs[n], dA, dtx * bc[wave][t][n]);
                y = fmaf(hs[n], bc[wave][t][16 + n], y);
            }
            const float g = zv / (1.f + __expf(-zv));
            py[(size_t)t * DI_] = __float2bfloat16((y + Dv * xv) * g);
        }
    }
}

// ---------------- host launcher --------------------------------------------
extern "C" void kernel_launch(void* const* d_in, const int* in_sizes, int n_in,
                              void* d_out, int out_size, void* d_ws, size_t ws_size,
                              hipStream_t stream) {
    const float* inputs = (const float*)d_in[0];
    const float* f_in_w = (const float*)d_in[1];
    const float* f_in_b = (const float*)d_in[2];
    const float* f_xp_w = (const float*)d_in[3];
    const float* f_xp_b = (const float*)d_in[4];
    const float* f_dt_b = (const float*)d_in[5];
    const float* f_A = (const float*)d_in[6];
    const float* f_D = (const float*)d_in[7];
    const float* f_out_w = (const float*)d_in[8];
    const float* f_out_b = (const float*)d_in[9];
    const float* b_in_w = (const float*)d_in[10];
    const float* b_in_b = (const float*)d_in[11];
    const float* b_xp_w = (const float*)d_in[12];
    const float* b_xp_b = (const float*)d_in[13];
    const float* b_dt_b = (const float*)d_in[14];
    const float* b_A = (const float*)d_in[15];
    const float* b_D = (const float*)d_in[16];
    const float* b_out_w = (const float*)d_in[17];
    const float* b_out_b = (const float*)d_in[18];
    const float* norm_w = (const float*)d_in[19];
    const float* norm_b = (const float*)d_in[20];
    const float* conv_w = (const float*)d_in[21];
    const float* conv_b = (const float*)d_in[22];
    float* out = (float*)d_out;

    // workspace layout
    float* ws = (float*)d_ws;
    float* st_prod = ws;                                  // 4,194,304 f
    float* st_hend = st_prod + (size_t)NSEQ_ * NC_;       // 4,194,304 f
    float* zslot   = st_hend + (size_t)NSEQ_ * NC_;       // 8,388,608 f slot
    __hip_bfloat16* z_bf = (__hip_bfloat16*)zslot;
    float* pslot   = zslot + (size_t)M_ * DI_;            // proj slot
    __hip_bfloat16* proj_bf = (__hip_bfloat16*)pslot;     // M*768 bf16 = 25 MB
    float* y1      = pslot + (size_t)M_ * PROJ_;          // (unused slot, kept)
    __hip_bfloat16* xi_bf = (__hip_bfloat16*)(y1 + (size_t)M_ * D_);
    __hip_bfloat16* yg_bf = xi_bf + (size_t)M_ * DI_;
    __hip_bfloat16* a_bf  = yg_bf + (size_t)M_ * DI_;
    __hip_bfloat16* wpool = a_bf + (size_t)M_ * D_;
    __hip_bfloat16* f_in_wb  = wpool;
    __hip_bfloat16* f_xp_wb  = f_in_wb + 2 * DI_ * D_;
    __hip_bfloat16* f_out_wb = f_xp_wb + PROJ_ * DI_;
    __hip_bfloat16* b_in_wb  = f_out_wb + D_ * DI_;
    __hip_bfloat16* b_xp_wb  = b_in_wb + 2 * DI_ * D_;
    __hip_bfloat16* b_out_wb = b_xp_wb + PROJ_ * DI_;

    const dim3 blk(256);
    const dim3 g_in(M_ / 128, (2 * DI_) / 128);   // (128,8)
    const dim3 g_xp(M_ / 128, PROJ_ / 128);       // (128,6)
    const dim3 g_out64(M_ / 64, D_ / 64);         // (256,4) bwd out_proj
    const dim3 g_oln(M_ / 16);                    // 1024 blocks fwd out_proj+LN
    const dim3 g_chunk(B_ * H_, NC_ / 4);         // (32,32)
    const dim3 g_comb(NSEQ_ / 256);               // 128 blocks

    // ---- fused fp32 -> bf16 conversions ----
    f2b_all<<<dim3(4096), blk, 0, stream>>>(inputs, f_in_w, f_xp_w, f_out_w,
                                            b_in_w, b_xp_w, b_out_w,
                                            a_bf, f_in_wb, f_xp_wb, f_out_wb,
                                            b_in_wb, b_xp_wb, b_out_wb);

    // ---- forward pass ----
    gemm_mfma<1><<<g_in, blk, 0, stream>>>(a_bf, f_in_wb, f_in_b, D_,
                                           z_bf, xi_bf, nullptr);
    gemm_mfma<2><<<g_xp, blk, 0, stream>>>(xi_bf, f_xp_wb, f_xp_b, DI_,
                                           nullptr, proj_bf, f_dt_b);
    scan_chunk_state<<<g_chunk, blk, 0, stream>>>(xi_bf, proj_bf, f_A,
                                                  st_prod, st_hend);
    scan_combine<<<g_comb, blk, 0, stream>>>(st_prod, st_hend);
    scan_chunk_out<<<g_chunk, blk, 0, stream>>>(xi_bf, z_bf, proj_bf, f_A, f_D,
                                                st_prod, yg_bf);
    gemm_out_ln<<<g_oln, blk, 0, stream>>>(yg_bf, f_out_wb, f_out_b,
                                           norm_w, norm_b, a_bf);

    // ---- backward pass ----
    gemm_mfma<1><<<g_in, blk, 0, stream>>>(a_bf, b_in_wb, b_in_b, D_,
                                           z_bf, xi_bf, nullptr);
    gemm_mfma<2><<<g_xp, blk, 0, stream>>>(xi_bf, b_xp_wb, b_xp_b, DI_,
                                           nullptr, proj_bf, b_dt_b);
    scan_chunk_state<<<g_chunk, blk, 0, stream>>>(xi_bf, proj_bf, b_A,
                                                  st_prod, st_hend);
    scan_combine<<<g_comb, blk, 0, stream>>>(st_prod, st_hend);
    scan_chunk_out<<<g_chunk, blk, 0, stream>>>(xi_bf, z_bf, proj_bf, b_A, b_D,
                                                st_prod, yg_bf);
    gemm64_convout<<<g_out64, blk, 0, stream>>>(yg_bf, b_out_wb, b_out_b, DI_,
                                                out, conv_w, conv_b, inputs);
}